// Round 4
// baseline (1972.160 us; speedup 1.0000x reference)
//
#include <hip/hip_runtime.h>
#include <hip/hip_bf16.h>

typedef unsigned short u16;
typedef unsigned int u32;

__device__ __forceinline__ float bf2f(u16 u) { return __uint_as_float(((u32)u) << 16); }
__device__ __forceinline__ float bl(u32 u) { return __uint_as_float(u << 16); }
__device__ __forceinline__ float bh(u32 u) { return __uint_as_float(u & 0xffff0000u); }
__device__ __forceinline__ u16 f2bf(float f) {
    u32 u = __float_as_uint(f);
    u += 0x7fffu + ((u >> 16) & 1u);   // round-to-nearest-even
    return (u16)(u >> 16);
}
__device__ __forceinline__ void unp8(uint4 r, float* o) {
    o[0] = bl(r.x); o[1] = bh(r.x); o[2] = bl(r.y); o[3] = bh(r.y);
    o[4] = bl(r.z); o[5] = bh(r.z); o[6] = bl(r.w); o[7] = bh(r.w);
}
__device__ __forceinline__ float lrelu(float x) { return x > 0.f ? x : 0.2f * x; }
__device__ __forceinline__ int clampi(int v, int lo, int hi) {
    return v < lo ? lo : (v > hi ? hi : v);
}
// flag-aware external loads (cold paths only)
__device__ __forceinline__ float load1(const void* base, int idx, int f32) {
    return f32 ? ((const float*)base)[idx] : bf2f(((const u16*)base)[idx]);
}
__device__ __forceinline__ void load8(const void* base, int idx, int f32, float* o) {
    if (f32) {
        const float4* p = (const float4*)((const float*)base + idx);
        float4 a = p[0], b = p[1];
        o[0] = a.x; o[1] = a.y; o[2] = a.z; o[3] = a.w;
        o[4] = b.x; o[5] = b.y; o[6] = b.z; o[7] = b.w;
    } else {
        uint4 r = *(const uint4*)((const u16*)base + idx);
        unp8(r, o);
    }
}

// ---------------- dtype detector: sample first 512 u16 of x ------------------------------
__global__ void k_detect(const u32* __restrict__ xw, int* __restrict__ flag) {
    int lane = threadIdx.x & 63;
    int cnt = 0;
    #pragma unroll
    for (int j = 0; j < 4; j++) {
        u32 w = xw[lane * 4 + j];
        int e0 = (int)((w >> 7) & 0xffu);
        int e1 = (int)((w >> 23) & 0xffu);
        cnt += (e0 >= 0x60 && e0 <= 0x8f);
        cnt += (e1 >= 0x60 && e1 <= 0x8f);
    }
    #pragma unroll
    for (int off = 32; off > 0; off >>= 1) cnt += __shfl_xor(cnt, off);
    if (lane == 0) *flag = (cnt < 480) ? 1 : 0;
}

// ---------------- constants ------------------------------------------------------------
__global__ void k_consts(const void* We1, const void* ae1, const void* We2, const void* ae2,
                         const int* __restrict__ flag, float* __restrict__ consts) {
    int f = *flag;
    int t = threadIdx.x;
    if (t < 4) {
        float s = 0.f;
        for (int c = 0; c < 32; c++) s += load1(We1, t * 32 + c, f) * load1(ae1, t * 32 + c, f);
        consts[t] = s;
    } else if (t == 4) {
        float s = 0.f;
        for (int c = 0; c < 64; c++) s += load1(We2, c, f) * load1(ae2, c, f);
        consts[4] = s;
    }
}

// ---------------- GEMM: Y[nrows,NC] = X[nrows,128] @ W[128,NC] --------------------------
// Compile-time dtypes (FX: X is fp32, FW: W is fp32). Early-exits unless *flag == fexp.
// 4 waves/block; wave computes 4 rows; lane owns col c0=lane (and c1=lane+64 if NC=128).
// W in LDS [k][col] fp32 (lanes read consecutive cols: conflict-free). X rows staged
// 4x128 fp32 per wave, broadcast reads.
template <int NC, bool FX, bool FW>
__global__ __launch_bounds__(256, 2) void k_gemmT(
    const void* __restrict__ X, const void* __restrict__ Wg,
    const int* __restrict__ flag, int fexp, u16* __restrict__ Y, int nrows) {
    if (*flag != fexp) return;
    constexpr int K = 128;
    __shared__ float Ws[K * NC];
    __shared__ float Xs[4][4 * K];

    const int tid = threadIdx.x;
    const int wid = tid >> 6, lane = tid & 63;

    // stage W once (bf16 path only taken when flag==0)
    for (int i = tid * 4; i < K * NC; i += 256 * 4) {
        if (FW) {
            *(float4*)&Ws[i] = *(const float4*)((const float*)Wg + i);
        } else {
            ushort4 r = *(const ushort4*)((const u16*)Wg + i);
            Ws[i] = bf2f(r.x); Ws[i + 1] = bf2f(r.y);
            Ws[i + 2] = bf2f(r.z); Ws[i + 3] = bf2f(r.w);
        }
    }
    __syncthreads();

    const int c0 = lane;
    const int rld = lane >> 4;          // staging: row within group of 4
    const int cld = (lane & 15) * 8;    // staging: col within row

    for (int base = blockIdx.x * 16; base < nrows; base += gridDim.x * 16) {
        // stage this wave's 4 rows into Xs[wid]
        {
            int row = base + wid * 4 + rld;
            float v[8];
            if (row < nrows) {
                load8(X, row * K + cld, FX, v);
            } else {
                #pragma unroll
                for (int j = 0; j < 8; j++) v[j] = 0.f;
            }
            #pragma unroll
            for (int j = 0; j < 8; j++) Xs[wid][rld * K + cld + j] = v[j];
        }
        __syncthreads();

        float acc0[4] = {0.f, 0.f, 0.f, 0.f};
        float acc1[4] = {0.f, 0.f, 0.f, 0.f};
        for (int k = 0; k < K; k += 4) {
            float4 xr[4];
            #pragma unroll
            for (int r = 0; r < 4; r++) xr[r] = *(const float4*)&Xs[wid][r * K + k];
            #pragma unroll
            for (int kk = 0; kk < 4; kk++) {
                float w0 = Ws[(k + kk) * NC + c0];
                float w1 = (NC == 128) ? Ws[(k + kk) * NC + c0 + 64] : 0.f;
                #pragma unroll
                for (int r = 0; r < 4; r++) {
                    float xv = ((const float*)&xr[r])[kk];
                    acc0[r] += xv * w0;
                    if (NC == 128) acc1[r] += xv * w1;
                }
            }
        }

        #pragma unroll
        for (int r = 0; r < 4; r++) {
            int row = base + wid * 4 + r;
            if (row < nrows) {
                Y[row * NC + c0] = f2bf(acc0[r]);
                if (NC == 128) Y[row * NC + c0 + 64] = f2bf(acc1[r]);
            }
        }
        __syncthreads();
    }
}

// ---------------- attention coefficients (layer1: 4 heads x 32ch) -----------------------
__global__ void k_coef1(const u16* __restrict__ h, const void* as_, const void* ad_,
                        const int* __restrict__ flag, float* __restrict__ asrc,
                        float* __restrict__ adst, int n) {
    int f = *flag;
    int i = blockIdx.x * 256 + threadIdx.x;
    if (i >= n * 4) return;
    int node = i >> 2, hd = i & 3;
    const u16* hp = h + node * 128 + hd * 32;
    float s1 = 0.f, s2 = 0.f;
    #pragma unroll
    for (int c = 0; c < 32; c += 8) {
        uint4 hv = *(const uint4*)&hp[c];
        float hf[8], af[8], df[8];
        unp8(hv, hf);
        load8(as_, hd * 32 + c, f, af);
        load8(ad_, hd * 32 + c, f, df);
        #pragma unroll
        for (int j = 0; j < 8; j++) { s1 += hf[j] * af[j]; s2 += hf[j] * df[j]; }
    }
    asrc[i] = s1; adst[i] = s2;
}

// ---------------- attention coefficients (layer2: 1 head x 64ch) ------------------------
__global__ void k_coef2(const u16* __restrict__ h, const void* as_, const void* ad_,
                        const int* __restrict__ flag, float* __restrict__ asrc,
                        float* __restrict__ adst, int n) {
    int f = *flag;
    int i = blockIdx.x * 256 + threadIdx.x;
    if (i >= n) return;
    const u16* hp = h + i * 64;
    float s1 = 0.f, s2 = 0.f;
    #pragma unroll
    for (int c = 0; c < 64; c += 8) {
        uint4 hv = *(const uint4*)&hp[c];
        float hf[8], af[8], df[8];
        unp8(hv, hf);
        load8(as_, c, f, af);
        load8(ad_, c, f, df);
        #pragma unroll
        for (int j = 0; j < 8; j++) { s1 += hf[j] * af[j]; s2 += hf[j] * df[j]; }
    }
    asrc[i] = s1; adst[i] = s2;
}

// ---------------- CSR build -------------------------------------------------------------
__global__ void k_count(const int* __restrict__ dst, int* __restrict__ cnt, int E, int n) {
    int e = blockIdx.x * 256 + threadIdx.x;
    if (e < E) atomicAdd(&cnt[clampi(dst[e], 0, n - 1)], 1);
}
__global__ void k_scan1(const int* __restrict__ cnt, int* __restrict__ part,
                        int* __restrict__ bsum, int n) {
    __shared__ int buf[256];
    int i = blockIdx.x * 256 + threadIdx.x;
    int v = (i < n) ? cnt[i] : 0;
    buf[threadIdx.x] = v;
    __syncthreads();
    for (int off = 1; off < 256; off <<= 1) {
        int t = (threadIdx.x >= off) ? buf[threadIdx.x - off] : 0;
        __syncthreads();
        buf[threadIdx.x] += t;
        __syncthreads();
    }
    if (i < n) part[i] = buf[threadIdx.x];
    if (threadIdx.x == 255) bsum[blockIdx.x] = buf[255];
}
__global__ void k_scan2(int* __restrict__ bsum, int nb) {
    __shared__ int buf[256];
    int t = threadIdx.x;
    int v = (t < nb) ? bsum[t] : 0;
    buf[t] = v;
    __syncthreads();
    for (int off = 1; off < 256; off <<= 1) {
        int tt = (t >= off) ? buf[t - off] : 0;
        __syncthreads();
        buf[t] += tt;
        __syncthreads();
    }
    if (t < nb) bsum[t] = buf[t] - v;   // exclusive
}
__global__ void k_scan3(int* __restrict__ roff, const int* __restrict__ bsum, int n) {
    int i = blockIdx.x * 256 + threadIdx.x;
    if (i > n) return;
    if (i == 0) { roff[0] = 0; return; }
    roff[i] += bsum[(i - 1) >> 8];
}
__global__ void k_copy(const int* __restrict__ roff, int* __restrict__ rpos, int n) {
    int i = blockIdx.x * 256 + threadIdx.x;
    if (i < n) rpos[i] = roff[i];
}
__global__ void k_scatter(const int* __restrict__ dst, int* __restrict__ rpos,
                          int* __restrict__ eids, int E, int n) {
    int e = blockIdx.x * 256 + threadIdx.x;
    if (e < E) {
        int p = atomicAdd(&rpos[clampi(dst[e], 0, n - 1)], 1);
        if (p >= 0 && p < E) eids[p] = e;
    }
}

// ---------------- fused per-dst softmax + aggregation, layer 1 (4 heads x 32) -----------
__global__ __launch_bounds__(256) void k_gat1(
    const u16* __restrict__ h, const float* __restrict__ asrc, const float* __restrict__ adst,
    const void* eattr, const int* __restrict__ srcs,
    const int* __restrict__ roff, const int* __restrict__ eids,
    const int* __restrict__ flag, const float* __restrict__ consts, const void* bias,
    u16* __restrict__ out, int n, int E) {
    int f = *flag;
    int gtid = blockIdx.x * 256 + threadIdx.x;
    int wv = gtid >> 6, lane = gtid & 63;
    int nw = (gridDim.x * 256) >> 6;
    const float c0 = consts[0], c1 = consts[1], c2 = consts[2], c3 = consts[3];
    const int hsel = lane >> 5;
    const float biasA = load1(bias, lane, f);
    const float biasB = load1(bias, 64 + lane, f);

    for (int d = wv; d < n; d += nw) {
        int s0 = clampi(roff[d], 0, E);
        int s1 = clampi(roff[d + 1], s0, E);
        float4 adv = *(const float4*)&adst[d * 4];
        float ad0 = adv.x, ad1 = adv.y, ad2 = adv.z, ad3 = adv.w;

        float m0 = -1e30f, m1 = -1e30f, m2 = -1e30f, m3 = -1e30f;
        for (int idx = s0 + lane; idx < s1; idx += 64) {
            int e = clampi(eids[idx], 0, E - 1);
            int s = clampi(srcs[e], 0, n - 1);
            float ea = load1(eattr, e, f);
            float4 av = *(const float4*)&asrc[s * 4];
            m0 = fmaxf(m0, lrelu(av.x + ad0 + ea * c0));
            m1 = fmaxf(m1, lrelu(av.y + ad1 + ea * c1));
            m2 = fmaxf(m2, lrelu(av.z + ad2 + ea * c2));
            m3 = fmaxf(m3, lrelu(av.w + ad3 + ea * c3));
        }
        #pragma unroll
        for (int off = 32; off > 0; off >>= 1) {
            m0 = fmaxf(m0, __shfl_xor(m0, off));
            m1 = fmaxf(m1, __shfl_xor(m1, off));
            m2 = fmaxf(m2, __shfl_xor(m2, off));
            m3 = fmaxf(m3, __shfl_xor(m3, off));
        }
        float d0 = 0.f, d1 = 0.f, d2 = 0.f, d3 = 0.f;
        for (int idx = s0 + lane; idx < s1; idx += 64) {
            int e = clampi(eids[idx], 0, E - 1);
            int s = clampi(srcs[e], 0, n - 1);
            float ea = load1(eattr, e, f);
            float4 av = *(const float4*)&asrc[s * 4];
            d0 += expf(lrelu(av.x + ad0 + ea * c0) - m0);
            d1 += expf(lrelu(av.y + ad1 + ea * c1) - m1);
            d2 += expf(lrelu(av.z + ad2 + ea * c2) - m2);
            d3 += expf(lrelu(av.w + ad3 + ea * c3) - m3);
        }
        #pragma unroll
        for (int off = 32; off > 0; off >>= 1) {
            d0 += __shfl_xor(d0, off); d1 += __shfl_xor(d1, off);
            d2 += __shfl_xor(d2, off); d3 += __shfl_xor(d3, off);
        }
        float i0 = 1.f / (d0 + 1e-16f), i1 = 1.f / (d1 + 1e-16f);
        float i2 = 1.f / (d2 + 1e-16f), i3 = 1.f / (d3 + 1e-16f);

        float mA = hsel ? m1 : m0, mB = hsel ? m3 : m2;
        float iA = hsel ? i1 : i0, iB = hsel ? i3 : i2;
        float cA = hsel ? c1 : c0, cB = hsel ? c3 : c2;
        float aA = hsel ? ad1 : ad0, aB = hsel ? ad3 : ad2;

        float accA = 0.f, accB = 0.f;
        for (int idx = s0; idx < s1; idx++) {
            int e = clampi(eids[idx], 0, E - 1);
            int s = clampi(srcs[e], 0, n - 1);
            float ea = load1(eattr, e, f);
            float4 av = *(const float4*)&asrc[s * 4];
            float alA = lrelu((hsel ? av.y : av.x) + aA + ea * cA);
            float alB = lrelu((hsel ? av.w : av.z) + aB + ea * cB);
            float wA = expf(alA - mA) * iA;
            float wB = expf(alB - mB) * iB;
            accA += wA * bf2f(h[s * 128 + lane]);
            accB += wB * bf2f(h[s * 128 + 64 + lane]);
        }
        out[d * 128 + lane]      = f2bf(fmaxf(accA + biasA, 0.f));
        out[d * 128 + 64 + lane] = f2bf(fmaxf(accB + biasB, 0.f));
    }
}

// ---------------- fused per-dst softmax + aggregation, layer 2 (1 head x 64) ------------
__global__ __launch_bounds__(256) void k_gat2(
    const u16* __restrict__ h, const float* __restrict__ asrc, const float* __restrict__ adst,
    const void* eattr, const int* __restrict__ srcs,
    const int* __restrict__ roff, const int* __restrict__ eids,
    const int* __restrict__ flag, const float* __restrict__ consts, const void* bias,
    u16* __restrict__ out, int n, int E) {
    int f = *flag;
    int gtid = blockIdx.x * 256 + threadIdx.x;
    int wv = gtid >> 6, lane = gtid & 63;
    int nw = (gridDim.x * 256) >> 6;
    const float C = consts[4];
    const float biasL = load1(bias, lane, f);

    for (int d = wv; d < n; d += nw) {
        int s0 = clampi(roff[d], 0, E);
        int s1 = clampi(roff[d + 1], s0, E);
        float ad = adst[d];
        float m = -1e30f;
        for (int idx = s0 + lane; idx < s1; idx += 64) {
            int e = clampi(eids[idx], 0, E - 1);
            int s = clampi(srcs[e], 0, n - 1);
            float ea = load1(eattr, e, f);
            m = fmaxf(m, lrelu(asrc[s] + ad + ea * C));
        }
        #pragma unroll
        for (int off = 32; off > 0; off >>= 1) m = fmaxf(m, __shfl_xor(m, off));
        float den = 0.f;
        for (int idx = s0 + lane; idx < s1; idx += 64) {
            int e = clampi(eids[idx], 0, E - 1);
            int s = clampi(srcs[e], 0, n - 1);
            float ea = load1(eattr, e, f);
            den += expf(lrelu(asrc[s] + ad + ea * C) - m);
        }
        #pragma unroll
        for (int off = 32; off > 0; off >>= 1) den += __shfl_xor(den, off);
        float inv = 1.f / (den + 1e-16f);

        float acc = 0.f;
        for (int idx = s0; idx < s1; idx++) {
            int e = clampi(eids[idx], 0, E - 1);
            int s = clampi(srcs[e], 0, n - 1);
            float ea = load1(eattr, e, f);
            float al = lrelu(asrc[s] + ad + ea * C);
            float w = expf(al - m) * inv;
            acc += w * bf2f(h[s * 64 + lane]);
        }
        out[d * 64 + lane] = f2bf(acc + biasL);
    }
}

// ---------------- pooling ---------------------------------------------------------------
__global__ void k_pool(const u16* __restrict__ agg2, const int* __restrict__ batch,
                       float* __restrict__ pool, float* __restrict__ cnt, int n, int G) {
    int t = blockIdx.x * 256 + threadIdx.x;
    int nb8 = (n + 7) / 8;
    if (t >= nb8 * 64) return;
    int base = (t >> 6) * 8;
    int c = t & 63;
    int end = min(base + 8, n);
    float acc = 0.f, cacc = 0.f;
    int curg = clampi(batch[base], 0, G - 1);
    for (int j = base; j < end; j++) {
        int g = clampi(batch[j], 0, G - 1);
        if (g != curg) {
            atomicAdd(&pool[curg * 64 + c], acc);
            if (c == 0) atomicAdd(&cnt[curg], cacc);
            acc = 0.f; cacc = 0.f; curg = g;
        }
        acc += bf2f(agg2[j * 64 + c]);
        cacc += 1.f;
    }
    atomicAdd(&pool[curg * 64 + c], acc);
    if (c == 0) atomicAdd(&cnt[curg], cacc);
}

__global__ void k_head(const float* __restrict__ pool, const float* __restrict__ cnt,
                       const void* Wp, const void* bp, const int* __restrict__ flag,
                       void* out, int G) {
    int f = *flag;
    int g = threadIdx.x;
    if (g >= G) return;
    float s = 0.f;
    for (int c = 0; c < 64; c++) s += pool[g * 64 + c] * load1(Wp, c, f);
    float cv = cnt[g];
    if (!(cv > 0.f)) cv = 1.f;
    float r = s / cv + load1(bp, 0, f);
    if (f) ((float*)out)[g] = r;
    else   ((u16*)out)[g] = f2bf(r);
}

// ---------------- launch ----------------------------------------------------------------
extern "C" void kernel_launch(void* const* d_in, const int* in_sizes, int n_in,
                              void* d_out, int out_size, void* d_ws, size_t ws_size,
                              hipStream_t stream) {
    const void* x    = d_in[0];
    const int* ei    = (const int*)d_in[1];
    const void* eattr = d_in[2];
    const int* batch = (const int*)d_in[3];
    const void* W1   = d_in[4];
    const void* as1  = d_in[5];
    const void* ad1  = d_in[6];
    const void* We1  = d_in[7];
    const void* ae1  = d_in[8];
    const void* b1   = d_in[9];
    const void* W2   = d_in[10];
    const void* as2  = d_in[11];
    const void* ad2  = d_in[12];
    const void* We2  = d_in[13];
    const void* ae2  = d_in[14];
    const void* b2   = d_in[15];
    const void* Wp   = d_in[16];
    const void* bp   = d_in[17];

    const int N = in_sizes[3];
    const int E = in_sizes[2];
    const int G = out_size;
    const int* src = ei;
    const int* dst = ei + E;

    char* p = (char*)d_ws;
    auto alloc = [&](size_t bytes) -> char* {
        char* r = p;
        p += (bytes + 255) & ~(size_t)255;
        return r;
    };
    int* flag    = (int*)alloc(32);
    float* consts = (float*)alloc(32);
    int* roff    = (int*)alloc((size_t)(N + 1) * 4);
    int* rpos    = (int*)alloc((size_t)N * 4);
    int* bsum    = (int*)alloc(256 * 4);
    int* eids    = (int*)alloc((size_t)E * 4);
    float* pool  = (float*)alloc((size_t)(G * 64 + G) * 4);
    float* cnt   = pool + (size_t)G * 64;
    float* asrc1 = (float*)alloc((size_t)N * 4 * 4);
    float* adst1 = (float*)alloc((size_t)N * 4 * 4);
    float* asrc2 = asrc1;             // alias: asrc1 dead after k_gat1
    float* adst2 = adst1;
    u16* agg1    = (u16*)alloc((size_t)N * 128 * 2);
    u16* h1      = (u16*)alloc((size_t)N * 128 * 2);
    u16* h2      = h1;                // alias: h1 dead after k_gat1
    u16* agg2    = h1 + (size_t)N * 64;

    hipMemsetAsync(rpos, 0, (size_t)N * 4, stream);
    hipMemsetAsync(pool, 0, (size_t)(G * 64 + G) * 4, stream);

    k_detect<<<1, 64, 0, stream>>>((const u32*)x, flag);
    k_consts<<<1, 64, 0, stream>>>(We1, ae1, We2, ae2, flag, consts);
    // layer-1 GEMM: X and W are external (same dtype); dispatch both, one no-ops
    k_gemmT<128, true,  true ><<<512, 256, 0, stream>>>(x, W1, flag, 1, h1, N);
    k_gemmT<128, false, false><<<512, 256, 0, stream>>>(x, W1, flag, 0, h1, N);
    k_coef1<<<(N * 4 + 255) / 256, 256, 0, stream>>>(h1, as1, ad1, flag, asrc1, adst1, N);

    int NB = (N + 255) / 256;
    k_count<<<(E + 255) / 256, 256, 0, stream>>>(dst, rpos, E, N);
    k_scan1<<<NB, 256, 0, stream>>>(rpos, roff + 1, bsum, N);
    k_scan2<<<1, 256, 0, stream>>>(bsum, NB);
    k_scan3<<<(N + 256) / 256, 256, 0, stream>>>(roff, bsum, N);
    k_copy<<<NB, 256, 0, stream>>>(roff, rpos, N);
    k_scatter<<<(E + 255) / 256, 256, 0, stream>>>(dst, rpos, eids, E, N);

    k_gat1<<<(N * 64 + 255) / 256, 256, 0, stream>>>(h1, asrc1, adst1, eattr, src, roff,
                                                     eids, flag, consts, b1, agg1, N, E);
    // layer-2 GEMM: X = agg1 (always bf16), W external
    k_gemmT<64, false, true ><<<512, 256, 0, stream>>>(agg1, W2, flag, 1, h2, N);
    k_gemmT<64, false, false><<<512, 256, 0, stream>>>(agg1, W2, flag, 0, h2, N);
    k_coef2<<<(N + 255) / 256, 256, 0, stream>>>(h2, as2, ad2, flag, asrc2, adst2, N);
    k_gat2<<<(N * 64 + 255) / 256, 256, 0, stream>>>(h2, asrc2, adst2, eattr, src, roff,
                                                     eids, flag, consts, b2, agg2, N, E);
    k_pool<<<(((N + 7) / 8) * 64 + 255) / 256, 256, 0, stream>>>(agg2, batch, pool, cnt, N, G);
    k_head<<<1, 64, 0, stream>>>(pool, cnt, Wp, bp, flag, d_out, G);
}

// Round 5
// 728.357 us; speedup vs baseline: 2.7077x; 2.7077x over previous
//
#include <hip/hip_runtime.h>
#include <hip/hip_bf16.h>

typedef unsigned short u16;
typedef unsigned int u32;

__device__ __forceinline__ float bf2f(u16 u) { return __uint_as_float(((u32)u) << 16); }
__device__ __forceinline__ float bl(u32 u) { return __uint_as_float(u << 16); }
__device__ __forceinline__ float bh(u32 u) { return __uint_as_float(u & 0xffff0000u); }
__device__ __forceinline__ u16 f2bf(float f) {
    u32 u = __float_as_uint(f);
    u += 0x7fffu + ((u >> 16) & 1u);   // round-to-nearest-even
    return (u16)(u >> 16);
}
__device__ __forceinline__ void unp8(uint4 r, float* o) {
    o[0] = bl(r.x); o[1] = bh(r.x); o[2] = bl(r.y); o[3] = bh(r.y);
    o[4] = bl(r.z); o[5] = bh(r.z); o[6] = bl(r.w); o[7] = bh(r.w);
}
__device__ __forceinline__ float lrelu(float x) { return x > 0.f ? x : 0.2f * x; }
__device__ __forceinline__ int clampi(int v, int lo, int hi) {
    return v < lo ? lo : (v > hi ? hi : v);
}
// flag-aware external loads (cold paths only)
__device__ __forceinline__ float load1(const void* base, int idx, int f32) {
    return f32 ? ((const float*)base)[idx] : bf2f(((const u16*)base)[idx]);
}
__device__ __forceinline__ void load8(const void* base, int idx, int f32, float* o) {
    if (f32) {
        const float4* p = (const float4*)((const float*)base + idx);
        float4 a = p[0], b = p[1];
        o[0] = a.x; o[1] = a.y; o[2] = a.z; o[3] = a.w;
        o[4] = b.x; o[5] = b.y; o[6] = b.z; o[7] = b.w;
    } else {
        uint4 r = *(const uint4*)((const u16*)base + idx);
        unp8(r, o);
    }
}

// ---------------- dtype detector: sample first 512 u16 of x ------------------------------
__global__ void k_detect(const u32* __restrict__ xw, int* __restrict__ flag) {
    int lane = threadIdx.x & 63;
    int cnt = 0;
    #pragma unroll
    for (int j = 0; j < 4; j++) {
        u32 w = xw[lane * 4 + j];
        int e0 = (int)((w >> 7) & 0xffu);
        int e1 = (int)((w >> 23) & 0xffu);
        cnt += (e0 >= 0x60 && e0 <= 0x8f);
        cnt += (e1 >= 0x60 && e1 <= 0x8f);
    }
    #pragma unroll
    for (int off = 32; off > 0; off >>= 1) cnt += __shfl_xor(cnt, off);
    if (lane == 0) *flag = (cnt < 480) ? 1 : 0;
}

// ---------------- constants ------------------------------------------------------------
__global__ void k_consts(const void* We1, const void* ae1, const void* We2, const void* ae2,
                         const int* __restrict__ flag, float* __restrict__ consts) {
    int f = *flag;
    int t = threadIdx.x;
    if (t < 4) {
        float s = 0.f;
        for (int c = 0; c < 32; c++) s += load1(We1, t * 32 + c, f) * load1(ae1, t * 32 + c, f);
        consts[t] = s;
    } else if (t == 4) {
        float s = 0.f;
        for (int c = 0; c < 64; c++) s += load1(We2, c, f) * load1(ae2, c, f);
        consts[4] = s;
    }
}

// ---------------- GEMM: Y[nrows,NC] = X[nrows,128] @ W[128,NC] --------------------------
// Compile-time dtypes. Early-exits unless *flag == fexp. No local-array address-taking:
// all hot-loop temporaries are named scalars / float4s; only LDS and global pointers are
// dereferenced through addresses. W in LDS [k][col] fp32 (lane-consecutive cols: 2-way,
// free). 16 rows of X staged per block iteration; wave wid computes rows wid*4..wid*4+3.
template <int NC, bool FX, bool FW>
__global__ __launch_bounds__(256) void k_gemmT(
    const void* __restrict__ X, const void* __restrict__ Wg,
    const int* __restrict__ flag, int fexp, u16* __restrict__ Y, int nrows) {
    if (*flag != fexp) return;
    constexpr int K = 128;
    __shared__ float Ws[K * NC];
    __shared__ float Xs[16 * K];

    const int tid = threadIdx.x;
    const int wid = tid >> 6, lane = tid & 63;

    // stage W once
    for (int i = tid * 4; i < K * NC; i += 256 * 4) {
        if (FW) {
            *(float4*)&Ws[i] = *(const float4*)((const float*)Wg + i);
        } else {
            ushort4 r = *(const ushort4*)((const u16*)Wg + i);
            Ws[i] = bf2f(r.x); Ws[i + 1] = bf2f(r.y);
            Ws[i + 2] = bf2f(r.z); Ws[i + 3] = bf2f(r.w);
        }
    }

    const int sr = tid >> 4;           // staging row 0..15
    const int sc = (tid & 15) * 8;     // staging col 0..120

    for (int base = blockIdx.x * 16; base < nrows; base += gridDim.x * 16) {
        __syncthreads();
        {
            int row = base + sr;
            float v0, v1, v2, v3, v4, v5, v6, v7;
            if (row < nrows) {
                if (FX) {
                    const float* xp = (const float*)X + (size_t)row * K + sc;
                    float4 a = *(const float4*)xp;
                    float4 b = *(const float4*)(xp + 4);
                    v0 = a.x; v1 = a.y; v2 = a.z; v3 = a.w;
                    v4 = b.x; v5 = b.y; v6 = b.z; v7 = b.w;
                } else {
                    uint4 r = *(const uint4*)((const u16*)X + (size_t)row * K + sc);
                    v0 = bl(r.x); v1 = bh(r.x); v2 = bl(r.y); v3 = bh(r.y);
                    v4 = bl(r.z); v5 = bh(r.z); v6 = bl(r.w); v7 = bh(r.w);
                }
            } else {
                v0 = v1 = v2 = v3 = v4 = v5 = v6 = v7 = 0.f;
            }
            float* xs = &Xs[sr * K + sc];
            xs[0] = v0; xs[1] = v1; xs[2] = v2; xs[3] = v3;
            xs[4] = v4; xs[5] = v5; xs[6] = v6; xs[7] = v7;
        }
        __syncthreads();

        float acc0[4] = {0.f, 0.f, 0.f, 0.f};
        float acc1[4] = {0.f, 0.f, 0.f, 0.f};
        for (int k = 0; k < K; k += 4) {
            float wa0 = Ws[(k + 0) * NC + lane];
            float wa1 = Ws[(k + 1) * NC + lane];
            float wa2 = Ws[(k + 2) * NC + lane];
            float wa3 = Ws[(k + 3) * NC + lane];
            float wb0 = 0.f, wb1 = 0.f, wb2 = 0.f, wb3 = 0.f;
            if constexpr (NC == 128) {
                wb0 = Ws[(k + 0) * NC + lane + 64];
                wb1 = Ws[(k + 1) * NC + lane + 64];
                wb2 = Ws[(k + 2) * NC + lane + 64];
                wb3 = Ws[(k + 3) * NC + lane + 64];
            }
            #pragma unroll
            for (int r = 0; r < 4; r++) {
                float4 xv = *(const float4*)&Xs[(wid * 4 + r) * K + k];
                acc0[r] += xv.x * wa0 + xv.y * wa1 + xv.z * wa2 + xv.w * wa3;
                if constexpr (NC == 128)
                    acc1[r] += xv.x * wb0 + xv.y * wb1 + xv.z * wb2 + xv.w * wb3;
            }
        }

        #pragma unroll
        for (int r = 0; r < 4; r++) {
            int row = base + wid * 4 + r;
            if (row < nrows) {
                Y[(size_t)row * NC + lane] = f2bf(acc0[r]);
                if constexpr (NC == 128)
                    Y[(size_t)row * NC + lane + 64] = f2bf(acc1[r]);
            }
        }
    }
}

// ---------------- attention coefficients (layer1: 4 heads x 32ch) -----------------------
__global__ void k_coef1(const u16* __restrict__ h, const void* as_, const void* ad_,
                        const int* __restrict__ flag, float* __restrict__ asrc,
                        float* __restrict__ adst, int n) {
    int f = *flag;
    int i = blockIdx.x * 256 + threadIdx.x;
    if (i >= n * 4) return;
    int node = i >> 2, hd = i & 3;
    const u16* hp = h + node * 128 + hd * 32;
    float s1 = 0.f, s2 = 0.f;
    #pragma unroll
    for (int c = 0; c < 32; c += 8) {
        uint4 hv = *(const uint4*)&hp[c];
        float hf[8], af[8], df[8];
        unp8(hv, hf);
        load8(as_, hd * 32 + c, f, af);
        load8(ad_, hd * 32 + c, f, df);
        #pragma unroll
        for (int j = 0; j < 8; j++) { s1 += hf[j] * af[j]; s2 += hf[j] * df[j]; }
    }
    asrc[i] = s1; adst[i] = s2;
}

// ---------------- attention coefficients (layer2: 1 head x 64ch) ------------------------
__global__ void k_coef2(const u16* __restrict__ h, const void* as_, const void* ad_,
                        const int* __restrict__ flag, float* __restrict__ asrc,
                        float* __restrict__ adst, int n) {
    int f = *flag;
    int i = blockIdx.x * 256 + threadIdx.x;
    if (i >= n) return;
    const u16* hp = h + i * 64;
    float s1 = 0.f, s2 = 0.f;
    #pragma unroll
    for (int c = 0; c < 64; c += 8) {
        uint4 hv = *(const uint4*)&hp[c];
        float hf[8], af[8], df[8];
        unp8(hv, hf);
        load8(as_, c, f, af);
        load8(ad_, c, f, df);
        #pragma unroll
        for (int j = 0; j < 8; j++) { s1 += hf[j] * af[j]; s2 += hf[j] * df[j]; }
    }
    asrc[i] = s1; adst[i] = s2;
}

// ---------------- CSR build -------------------------------------------------------------
__global__ void k_count(const int* __restrict__ dst, int* __restrict__ cnt, int E, int n) {
    int e = blockIdx.x * 256 + threadIdx.x;
    if (e < E) atomicAdd(&cnt[clampi(dst[e], 0, n - 1)], 1);
}
__global__ void k_scan1(const int* __restrict__ cnt, int* __restrict__ part,
                        int* __restrict__ bsum, int n) {
    __shared__ int buf[256];
    int i = blockIdx.x * 256 + threadIdx.x;
    int v = (i < n) ? cnt[i] : 0;
    buf[threadIdx.x] = v;
    __syncthreads();
    for (int off = 1; off < 256; off <<= 1) {
        int t = (threadIdx.x >= off) ? buf[threadIdx.x - off] : 0;
        __syncthreads();
        buf[threadIdx.x] += t;
        __syncthreads();
    }
    if (i < n) part[i] = buf[threadIdx.x];
    if (threadIdx.x == 255) bsum[blockIdx.x] = buf[255];
}
__global__ void k_scan2(int* __restrict__ bsum, int nb) {
    __shared__ int buf[256];
    int t = threadIdx.x;
    int v = (t < nb) ? bsum[t] : 0;
    buf[t] = v;
    __syncthreads();
    for (int off = 1; off < 256; off <<= 1) {
        int tt = (t >= off) ? buf[t - off] : 0;
        __syncthreads();
        buf[t] += tt;
        __syncthreads();
    }
    if (t < nb) bsum[t] = buf[t] - v;   // exclusive
}
__global__ void k_scan3(int* __restrict__ roff, const int* __restrict__ bsum, int n) {
    int i = blockIdx.x * 256 + threadIdx.x;
    if (i > n) return;
    if (i == 0) { roff[0] = 0; return; }
    roff[i] += bsum[(i - 1) >> 8];
}
__global__ void k_copy(const int* __restrict__ roff, int* __restrict__ rpos, int n) {
    int i = blockIdx.x * 256 + threadIdx.x;
    if (i < n) rpos[i] = roff[i];
}
__global__ void k_scatter(const int* __restrict__ dst, int* __restrict__ rpos,
                          int* __restrict__ eids, int E, int n) {
    int e = blockIdx.x * 256 + threadIdx.x;
    if (e < E) {
        int p = atomicAdd(&rpos[clampi(dst[e], 0, n - 1)], 1);
        if (p >= 0 && p < E) eids[p] = e;
    }
}

// ---------------- fused per-dst softmax + aggregation, layer 1 (4 heads x 32) -----------
__global__ __launch_bounds__(256) void k_gat1(
    const u16* __restrict__ h, const float* __restrict__ asrc, const float* __restrict__ adst,
    const void* eattr, const int* __restrict__ srcs,
    const int* __restrict__ roff, const int* __restrict__ eids,
    const int* __restrict__ flag, const float* __restrict__ consts, const void* bias,
    u16* __restrict__ out, int n, int E) {
    int f = *flag;
    int gtid = blockIdx.x * 256 + threadIdx.x;
    int wv = gtid >> 6, lane = gtid & 63;
    int nw = (gridDim.x * 256) >> 6;
    const float c0 = consts[0], c1 = consts[1], c2 = consts[2], c3 = consts[3];
    const int hsel = lane >> 5;
    const float biasA = load1(bias, lane, f);
    const float biasB = load1(bias, 64 + lane, f);

    for (int d = wv; d < n; d += nw) {
        int s0 = clampi(roff[d], 0, E);
        int s1 = clampi(roff[d + 1], s0, E);
        float4 adv = *(const float4*)&adst[d * 4];
        float ad0 = adv.x, ad1 = adv.y, ad2 = adv.z, ad3 = adv.w;

        float m0 = -1e30f, m1 = -1e30f, m2 = -1e30f, m3 = -1e30f;
        for (int idx = s0 + lane; idx < s1; idx += 64) {
            int e = clampi(eids[idx], 0, E - 1);
            int s = clampi(srcs[e], 0, n - 1);
            float ea = load1(eattr, e, f);
            float4 av = *(const float4*)&asrc[s * 4];
            m0 = fmaxf(m0, lrelu(av.x + ad0 + ea * c0));
            m1 = fmaxf(m1, lrelu(av.y + ad1 + ea * c1));
            m2 = fmaxf(m2, lrelu(av.z + ad2 + ea * c2));
            m3 = fmaxf(m3, lrelu(av.w + ad3 + ea * c3));
        }
        #pragma unroll
        for (int off = 32; off > 0; off >>= 1) {
            m0 = fmaxf(m0, __shfl_xor(m0, off));
            m1 = fmaxf(m1, __shfl_xor(m1, off));
            m2 = fmaxf(m2, __shfl_xor(m2, off));
            m3 = fmaxf(m3, __shfl_xor(m3, off));
        }
        float d0 = 0.f, d1 = 0.f, d2 = 0.f, d3 = 0.f;
        for (int idx = s0 + lane; idx < s1; idx += 64) {
            int e = clampi(eids[idx], 0, E - 1);
            int s = clampi(srcs[e], 0, n - 1);
            float ea = load1(eattr, e, f);
            float4 av = *(const float4*)&asrc[s * 4];
            d0 += expf(lrelu(av.x + ad0 + ea * c0) - m0);
            d1 += expf(lrelu(av.y + ad1 + ea * c1) - m1);
            d2 += expf(lrelu(av.z + ad2 + ea * c2) - m2);
            d3 += expf(lrelu(av.w + ad3 + ea * c3) - m3);
        }
        #pragma unroll
        for (int off = 32; off > 0; off >>= 1) {
            d0 += __shfl_xor(d0, off); d1 += __shfl_xor(d1, off);
            d2 += __shfl_xor(d2, off); d3 += __shfl_xor(d3, off);
        }
        float i0 = 1.f / (d0 + 1e-16f), i1 = 1.f / (d1 + 1e-16f);
        float i2 = 1.f / (d2 + 1e-16f), i3 = 1.f / (d3 + 1e-16f);

        float mA = hsel ? m1 : m0, mB = hsel ? m3 : m2;
        float iA = hsel ? i1 : i0, iB = hsel ? i3 : i2;
        float cA = hsel ? c1 : c0, cB = hsel ? c3 : c2;
        float aA = hsel ? ad1 : ad0, aB = hsel ? ad3 : ad2;

        float accA = 0.f, accB = 0.f;
        for (int idx = s0; idx < s1; idx++) {
            int e = clampi(eids[idx], 0, E - 1);
            int s = clampi(srcs[e], 0, n - 1);
            float ea = load1(eattr, e, f);
            float4 av = *(const float4*)&asrc[s * 4];
            float alA = lrelu((hsel ? av.y : av.x) + aA + ea * cA);
            float alB = lrelu((hsel ? av.w : av.z) + aB + ea * cB);
            float wA = expf(alA - mA) * iA;
            float wB = expf(alB - mB) * iB;
            accA += wA * bf2f(h[s * 128 + lane]);
            accB += wB * bf2f(h[s * 128 + 64 + lane]);
        }
        out[d * 128 + lane]      = f2bf(fmaxf(accA + biasA, 0.f));
        out[d * 128 + 64 + lane] = f2bf(fmaxf(accB + biasB, 0.f));
    }
}

// ---------------- fused per-dst softmax + aggregation, layer 2 (1 head x 64) ------------
__global__ __launch_bounds__(256) void k_gat2(
    const u16* __restrict__ h, const float* __restrict__ asrc, const float* __restrict__ adst,
    const void* eattr, const int* __restrict__ srcs,
    const int* __restrict__ roff, const int* __restrict__ eids,
    const int* __restrict__ flag, const float* __restrict__ consts, const void* bias,
    u16* __restrict__ out, int n, int E) {
    int f = *flag;
    int gtid = blockIdx.x * 256 + threadIdx.x;
    int wv = gtid >> 6, lane = gtid & 63;
    int nw = (gridDim.x * 256) >> 6;
    const float C = consts[4];
    const float biasL = load1(bias, lane, f);

    for (int d = wv; d < n; d += nw) {
        int s0 = clampi(roff[d], 0, E);
        int s1 = clampi(roff[d + 1], s0, E);
        float ad = adst[d];
        float m = -1e30f;
        for (int idx = s0 + lane; idx < s1; idx += 64) {
            int e = clampi(eids[idx], 0, E - 1);
            int s = clampi(srcs[e], 0, n - 1);
            float ea = load1(eattr, e, f);
            m = fmaxf(m, lrelu(asrc[s] + ad + ea * C));
        }
        #pragma unroll
        for (int off = 32; off > 0; off >>= 1) m = fmaxf(m, __shfl_xor(m, off));
        float den = 0.f;
        for (int idx = s0 + lane; idx < s1; idx += 64) {
            int e = clampi(eids[idx], 0, E - 1);
            int s = clampi(srcs[e], 0, n - 1);
            float ea = load1(eattr, e, f);
            den += expf(lrelu(asrc[s] + ad + ea * C) - m);
        }
        #pragma unroll
        for (int off = 32; off > 0; off >>= 1) den += __shfl_xor(den, off);
        float inv = 1.f / (den + 1e-16f);

        float acc = 0.f;
        for (int idx = s0; idx < s1; idx++) {
            int e = clampi(eids[idx], 0, E - 1);
            int s = clampi(srcs[e], 0, n - 1);
            float ea = load1(eattr, e, f);
            float al = lrelu(asrc[s] + ad + ea * C);
            float w = expf(al - m) * inv;
            acc += w * bf2f(h[s * 64 + lane]);
        }
        out[d * 64 + lane] = f2bf(acc + biasL);
    }
}

// ---------------- pooling ---------------------------------------------------------------
__global__ void k_pool(const u16* __restrict__ agg2, const int* __restrict__ batch,
                       float* __restrict__ pool, float* __restrict__ cnt, int n, int G) {
    int t = blockIdx.x * 256 + threadIdx.x;
    int nb8 = (n + 7) / 8;
    if (t >= nb8 * 64) return;
    int base = (t >> 6) * 8;
    int c = t & 63;
    int end = min(base + 8, n);
    float acc = 0.f, cacc = 0.f;
    int curg = clampi(batch[base], 0, G - 1);
    for (int j = base; j < end; j++) {
        int g = clampi(batch[j], 0, G - 1);
        if (g != curg) {
            atomicAdd(&pool[curg * 64 + c], acc);
            if (c == 0) atomicAdd(&cnt[curg], cacc);
            acc = 0.f; cacc = 0.f; curg = g;
        }
        acc += bf2f(agg2[j * 64 + c]);
        cacc += 1.f;
    }
    atomicAdd(&pool[curg * 64 + c], acc);
    if (c == 0) atomicAdd(&cnt[curg], cacc);
}

__global__ void k_head(const float* __restrict__ pool, const float* __restrict__ cnt,
                       const void* Wp, const void* bp, const int* __restrict__ flag,
                       void* out, int G) {
    int f = *flag;
    int g = threadIdx.x;
    if (g >= G) return;
    float s = 0.f;
    for (int c = 0; c < 64; c++) s += pool[g * 64 + c] * load1(Wp, c, f);
    float cv = cnt[g];
    if (!(cv > 0.f)) cv = 1.f;
    float r = s / cv + load1(bp, 0, f);
    if (f) ((float*)out)[g] = r;
    else   ((u16*)out)[g] = f2bf(r);
}

// ---------------- launch ----------------------------------------------------------------
extern "C" void kernel_launch(void* const* d_in, const int* in_sizes, int n_in,
                              void* d_out, int out_size, void* d_ws, size_t ws_size,
                              hipStream_t stream) {
    const void* x    = d_in[0];
    const int* ei    = (const int*)d_in[1];
    const void* eattr = d_in[2];
    const int* batch = (const int*)d_in[3];
    const void* W1   = d_in[4];
    const void* as1  = d_in[5];
    const void* ad1  = d_in[6];
    const void* We1  = d_in[7];
    const void* ae1  = d_in[8];
    const void* b1   = d_in[9];
    const void* W2   = d_in[10];
    const void* as2  = d_in[11];
    const void* ad2  = d_in[12];
    const void* We2  = d_in[13];
    const void* ae2  = d_in[14];
    const void* b2   = d_in[15];
    const void* Wp   = d_in[16];
    const void* bp   = d_in[17];

    const int N = in_sizes[3];
    const int E = in_sizes[2];
    const int G = out_size;
    const int* src = ei;
    const int* dst = ei + E;

    char* p = (char*)d_ws;
    auto alloc = [&](size_t bytes) -> char* {
        char* r = p;
        p += (bytes + 255) & ~(size_t)255;
        return r;
    };
    int* flag    = (int*)alloc(32);
    float* consts = (float*)alloc(32);
    int* roff    = (int*)alloc((size_t)(N + 1) * 4);
    int* rpos    = (int*)alloc((size_t)N * 4);
    int* bsum    = (int*)alloc(256 * 4);
    int* eids    = (int*)alloc((size_t)E * 4);
    float* pool  = (float*)alloc((size_t)(G * 64 + G) * 4);
    float* cnt   = pool + (size_t)G * 64;
    float* asrc1 = (float*)alloc((size_t)N * 4 * 4);
    float* adst1 = (float*)alloc((size_t)N * 4 * 4);
    float* asrc2 = asrc1;             // alias: asrc1 dead after k_gat1
    float* adst2 = adst1;
    u16* agg1    = (u16*)alloc((size_t)N * 128 * 2);
    u16* h1      = (u16*)alloc((size_t)N * 128 * 2);
    u16* h2      = h1;                // alias: h1 dead after k_gat1
    u16* agg2    = h1 + (size_t)N * 64;

    hipMemsetAsync(rpos, 0, (size_t)N * 4, stream);
    hipMemsetAsync(pool, 0, (size_t)(G * 64 + G) * 4, stream);

    k_detect<<<1, 64, 0, stream>>>((const u32*)x, flag);
    k_consts<<<1, 64, 0, stream>>>(We1, ae1, We2, ae2, flag, consts);
    // layer-1 GEMM: X and W are external (same dtype); dispatch both, one no-ops
    k_gemmT<128, true,  true ><<<512, 256, 0, stream>>>(x, W1, flag, 1, h1, N);
    k_gemmT<128, false, false><<<512, 256, 0, stream>>>(x, W1, flag, 0, h1, N);
    k_coef1<<<(N * 4 + 255) / 256, 256, 0, stream>>>(h1, as1, ad1, flag, asrc1, adst1, N);

    int NB = (N + 255) / 256;
    k_count<<<(E + 255) / 256, 256, 0, stream>>>(dst, rpos, E, N);
    k_scan1<<<NB, 256, 0, stream>>>(rpos, roff + 1, bsum, N);
    k_scan2<<<1, 256, 0, stream>>>(bsum, NB);
    k_scan3<<<(N + 256) / 256, 256, 0, stream>>>(roff, bsum, N);
    k_copy<<<NB, 256, 0, stream>>>(roff, rpos, N);
    k_scatter<<<(E + 255) / 256, 256, 0, stream>>>(dst, rpos, eids, E, N);

    k_gat1<<<(N * 64 + 255) / 256, 256, 0, stream>>>(h1, asrc1, adst1, eattr, src, roff,
                                                     eids, flag, consts, b1, agg1, N, E);
    // layer-2 GEMM: X = agg1 (always bf16), W external
    k_gemmT<64, false, true ><<<512, 256, 0, stream>>>(agg1, W2, flag, 1, h2, N);
    k_gemmT<64, false, false><<<512, 256, 0, stream>>>(agg1, W2, flag, 0, h2, N);
    k_coef2<<<(N + 255) / 256, 256, 0, stream>>>(h2, as2, ad2, flag, asrc2, adst2, N);
    k_gat2<<<(N * 64 + 255) / 256, 256, 0, stream>>>(h2, asrc2, adst2, eattr, src, roff,
                                                     eids, flag, consts, b2, agg2, N, E);
    k_pool<<<(((N + 7) / 8) * 64 + 255) / 256, 256, 0, stream>>>(agg2, batch, pool, cnt, N, G);
    k_head<<<1, 64, 0, stream>>>(pool, cnt, Wp, bp, flag, d_out, G);
}

// Round 6
// 534.054 us; speedup vs baseline: 3.6928x; 1.3638x over previous
//
#include <hip/hip_runtime.h>
#include <hip/hip_bf16.h>

typedef unsigned short u16;
typedef unsigned int u32;

__device__ __forceinline__ float bf2f(u16 u) { return __uint_as_float(((u32)u) << 16); }
__device__ __forceinline__ float bl(u32 u) { return __uint_as_float(u << 16); }
__device__ __forceinline__ float bh(u32 u) { return __uint_as_float(u & 0xffff0000u); }
__device__ __forceinline__ u16 f2bf(float f) {
    u32 u = __float_as_uint(f);
    u += 0x7fffu + ((u >> 16) & 1u);   // round-to-nearest-even
    return (u16)(u >> 16);
}
__device__ __forceinline__ float lrelu(float x) { return x > 0.f ? x : 0.2f * x; }
__device__ __forceinline__ int clampi(int v, int lo, int hi) {
    return v < lo ? lo : (v > hi ? hi : v);
}
__device__ __forceinline__ float load1(const void* base, int idx, int f32) {
    return f32 ? ((const float*)base)[idx] : bf2f(((const u16*)base)[idx]);
}

// ---------------- dtype detector ---------------------------------------------------------
__global__ void k_detect(const u32* __restrict__ xw, int* __restrict__ flag) {
    int lane = threadIdx.x & 63;
    int cnt = 0;
    #pragma unroll
    for (int j = 0; j < 4; j++) {
        u32 w = xw[lane * 4 + j];
        int e0 = (int)((w >> 7) & 0xffu);
        int e1 = (int)((w >> 23) & 0xffu);
        cnt += (e0 >= 0x60 && e0 <= 0x8f);
        cnt += (e1 >= 0x60 && e1 <= 0x8f);
    }
    #pragma unroll
    for (int off = 32; off > 0; off >>= 1) cnt += __shfl_xor(cnt, off);
    if (lane == 0) *flag = (cnt < 480) ? 1 : 0;
}

// ---------------- constants + fp32 expansion of attention vectors -----------------------
// consts layout (floats): [0..3]=C1 per head, [4]=C2, [8..135]=as1f, [136..263]=ad1f,
// [264..327]=as2f, [328..391]=ad2f
__global__ void k_consts(const void* We1, const void* ae1, const void* We2, const void* ae2,
                         const void* as1, const void* ad1, const void* as2, const void* ad2,
                         const int* __restrict__ flag, float* __restrict__ consts) {
    int f = *flag;
    int t = threadIdx.x;
    if (t < 4) {
        float s = 0.f;
        for (int c = 0; c < 32; c++) s += load1(We1, t * 32 + c, f) * load1(ae1, t * 32 + c, f);
        consts[t] = s;
    } else if (t == 4) {
        float s = 0.f;
        for (int c = 0; c < 64; c++) s += load1(We2, c, f) * load1(ae2, c, f);
        consts[4] = s;
    }
    if (t < 128) {
        consts[8 + t] = load1(as1, t, f);
        consts[136 + t] = load1(ad1, t, f);
    }
    if (t < 64) {
        consts[264 + t] = load1(as2, t, f);
        consts[328 + t] = load1(ad2, t, f);
    }
}

// ---------------- GEMM: Y[nrows,NC] = X[nrows,128] @ W[128,NC] --------------------------
// One kernel per layer; dtype branch is wave-uniform on *flag (fXovr forces X dtype).
// 32-row tiles, 8 rows/wave, lane -> col lane (+64 if NC=128). K-loop unroll capped.
// NC==128: output PAIRED layout (u32 word = (ch c | ch c+64<<16) at word row*64+c).
// NC==64:  X (agg1) is PAIRED -> W rows permuted during staging; natural u16 output.
template <int NC>
__global__ __launch_bounds__(256, 4) void k_gemm5(
    const void* __restrict__ X, const void* __restrict__ Wg,
    const int* __restrict__ flag, int fXovr, u16* __restrict__ Y, int nrows) {
    constexpr int K = 128;
    constexpr int ROWS = 32;
    __shared__ float Ws[K * NC];
    __shared__ float Xs[ROWS * K];

    const int f = *flag;
    const bool fX = (fXovr < 0) ? (f != 0) : (fXovr != 0);
    const bool fW = (f != 0);
    const int tid = threadIdx.x, wid = tid >> 6, lane = tid & 63;

    // stage W once (permute rows if NC==64 because X rows are channel-paired)
    for (int i = tid * 4; i < K * NC; i += 256 * 4) {
        int j = i / NC;
        int col = i & (NC - 1);
        int srow = (NC == 64) ? ((j & 1) * 64 + (j >> 1)) : j;
        int g = srow * NC + col;
        if (fW) {
            float4 v = *(const float4*)((const float*)Wg + g);
            Ws[i] = v.x; Ws[i + 1] = v.y; Ws[i + 2] = v.z; Ws[i + 3] = v.w;
        } else {
            ushort4 r = *(const ushort4*)((const u16*)Wg + g);
            Ws[i] = bf2f(r.x); Ws[i + 1] = bf2f(r.y);
            Ws[i + 2] = bf2f(r.z); Ws[i + 3] = bf2f(r.w);
        }
    }

    const int sr = tid >> 3;           // staging row 0..31
    const int sc = (tid & 7) * 16;     // staging col 0,16,..112

    for (int base = blockIdx.x * ROWS; base < nrows; base += gridDim.x * ROWS) {
        __syncthreads();
        {
            int row = base + sr;
            float* xs = &Xs[sr * K + sc];
            if (row < nrows) {
                if (fX) {
                    const float* xp = (const float*)X + (size_t)row * K + sc;
                    float4 a = *(const float4*)xp;
                    float4 b = *(const float4*)(xp + 4);
                    float4 c = *(const float4*)(xp + 8);
                    float4 d = *(const float4*)(xp + 12);
                    xs[0] = a.x; xs[1] = a.y; xs[2] = a.z; xs[3] = a.w;
                    xs[4] = b.x; xs[5] = b.y; xs[6] = b.z; xs[7] = b.w;
                    xs[8] = c.x; xs[9] = c.y; xs[10] = c.z; xs[11] = c.w;
                    xs[12] = d.x; xs[13] = d.y; xs[14] = d.z; xs[15] = d.w;
                } else {
                    const u16* xp = (const u16*)X + (size_t)row * K + sc;
                    uint4 a = *(const uint4*)xp;
                    uint4 b = *(const uint4*)(xp + 8);
                    xs[0] = bl(a.x); xs[1] = bh(a.x); xs[2] = bl(a.y); xs[3] = bh(a.y);
                    xs[4] = bl(a.z); xs[5] = bh(a.z); xs[6] = bl(a.w); xs[7] = bh(a.w);
                    xs[8] = bl(b.x); xs[9] = bh(b.x); xs[10] = bl(b.y); xs[11] = bh(b.y);
                    xs[12] = bl(b.z); xs[13] = bh(b.z); xs[14] = bl(b.w); xs[15] = bh(b.w);
                }
            } else {
                #pragma unroll
                for (int j = 0; j < 16; j++) xs[j] = 0.f;
            }
        }
        __syncthreads();

        float acc0[8] = {0.f, 0.f, 0.f, 0.f, 0.f, 0.f, 0.f, 0.f};
        float acc1[8] = {0.f, 0.f, 0.f, 0.f, 0.f, 0.f, 0.f, 0.f};
        #pragma unroll 2
        for (int k = 0; k < K; k += 4) {
            float wa0 = Ws[(k + 0) * NC + lane];
            float wa1 = Ws[(k + 1) * NC + lane];
            float wa2 = Ws[(k + 2) * NC + lane];
            float wa3 = Ws[(k + 3) * NC + lane];
            float wb0 = 0.f, wb1 = 0.f, wb2 = 0.f, wb3 = 0.f;
            if constexpr (NC == 128) {
                wb0 = Ws[(k + 0) * NC + lane + 64];
                wb1 = Ws[(k + 1) * NC + lane + 64];
                wb2 = Ws[(k + 2) * NC + lane + 64];
                wb3 = Ws[(k + 3) * NC + lane + 64];
            }
            #pragma unroll
            for (int rr = 0; rr < 8; rr++) {
                float4 xv = *(const float4*)&Xs[(wid * 8 + rr) * K + k];
                acc0[rr] += xv.x * wa0 + xv.y * wa1 + xv.z * wa2 + xv.w * wa3;
                if constexpr (NC == 128)
                    acc1[rr] += xv.x * wb0 + xv.y * wb1 + xv.z * wb2 + xv.w * wb3;
            }
        }

        #pragma unroll
        for (int rr = 0; rr < 8; rr++) {
            int row = base + wid * 8 + rr;
            if (row < nrows) {
                if constexpr (NC == 128) {
                    u32 w = (u32)f2bf(acc0[rr]) | ((u32)f2bf(acc1[rr]) << 16);
                    ((u32*)Y)[(size_t)row * 64 + lane] = w;
                } else {
                    Y[(size_t)row * 64 + lane] = f2bf(acc0[rr]);
                }
            }
        }
    }
}

// ---------------- coef1: paired h1 -> asrc1/adst1 [N][4] --------------------------------
__global__ void k_coef1(const u32* __restrict__ hp, const float* __restrict__ consts,
                        float* __restrict__ asrc, float* __restrict__ adst, int n) {
    int i = blockIdx.x * 256 + threadIdx.x;
    if (i >= n * 2) return;
    int node = i >> 1, g = i & 1;
    const u32* w = hp + (size_t)node * 64 + g * 32;
    const float* asA = consts + 8 + g * 32;
    const float* adA = consts + 136 + g * 32;
    const float* asB = consts + 8 + (g + 2) * 32;
    const float* adB = consts + 136 + (g + 2) * 32;
    float sA1 = 0.f, sA2 = 0.f, sB1 = 0.f, sB2 = 0.f;
    #pragma unroll
    for (int c = 0; c < 32; c += 4) {
        uint4 q = *(const uint4*)&w[c];
        float l0 = bl(q.x), h0 = bh(q.x), l1 = bl(q.y), h1 = bh(q.y);
        float l2 = bl(q.z), h2 = bh(q.z), l3 = bl(q.w), h3 = bh(q.w);
        sA1 += l0 * asA[c] + l1 * asA[c + 1] + l2 * asA[c + 2] + l3 * asA[c + 3];
        sA2 += l0 * adA[c] + l1 * adA[c + 1] + l2 * adA[c + 2] + l3 * adA[c + 3];
        sB1 += h0 * asB[c] + h1 * asB[c + 1] + h2 * asB[c + 2] + h3 * asB[c + 3];
        sB2 += h0 * adB[c] + h1 * adB[c + 1] + h2 * adB[c + 2] + h3 * adB[c + 3];
    }
    asrc[node * 4 + g] = sA1;     adst[node * 4 + g] = sA2;
    asrc[node * 4 + g + 2] = sB1; adst[node * 4 + g + 2] = sB2;
}

// ---------------- coef2: natural h2 -> asrc2/adst2 [N] ----------------------------------
__global__ void k_coef2(const u32* __restrict__ hp, const float* __restrict__ consts,
                        float* __restrict__ asrc, float* __restrict__ adst, int n) {
    int i = blockIdx.x * 256 + threadIdx.x;
    if (i >= n) return;
    const u32* w = hp + (size_t)i * 32;
    const float* as_ = consts + 264;
    const float* ad_ = consts + 328;
    float s1 = 0.f, s2 = 0.f;
    #pragma unroll
    for (int c = 0; c < 32; c += 4) {
        uint4 q = *(const uint4*)&w[c];
        float l0 = bl(q.x), h0 = bh(q.x), l1 = bl(q.y), h1 = bh(q.y);
        float l2 = bl(q.z), h2 = bh(q.z), l3 = bl(q.w), h3 = bh(q.w);
        s1 += l0 * as_[2*c] + h0 * as_[2*c+1] + l1 * as_[2*c+2] + h1 * as_[2*c+3]
            + l2 * as_[2*c+4] + h2 * as_[2*c+5] + l3 * as_[2*c+6] + h3 * as_[2*c+7];
        s2 += l0 * ad_[2*c] + h0 * ad_[2*c+1] + l1 * ad_[2*c+2] + h1 * ad_[2*c+3]
            + l2 * ad_[2*c+4] + h2 * ad_[2*c+5] + l3 * ad_[2*c+6] + h3 * ad_[2*c+7];
    }
    asrc[i] = s1; adst[i] = s2;
}

// ---------------- CSR build -------------------------------------------------------------
__global__ void k_count(const int* __restrict__ dst, int* __restrict__ cnt, int E, int n) {
    int e = blockIdx.x * 256 + threadIdx.x;
    if (e < E) atomicAdd(&cnt[clampi(dst[e], 0, n - 1)], 1);
}
__global__ void k_scan1(const int* __restrict__ cnt, int* __restrict__ part,
                        int* __restrict__ bsum, int n) {
    __shared__ int buf[256];
    int i = blockIdx.x * 256 + threadIdx.x;
    int v = (i < n) ? cnt[i] : 0;
    buf[threadIdx.x] = v;
    __syncthreads();
    for (int off = 1; off < 256; off <<= 1) {
        int t = (threadIdx.x >= off) ? buf[threadIdx.x - off] : 0;
        __syncthreads();
        buf[threadIdx.x] += t;
        __syncthreads();
    }
    if (i < n) part[i] = buf[threadIdx.x];
    if (threadIdx.x == 255) bsum[blockIdx.x] = buf[255];
}
__global__ void k_scan2(int* __restrict__ bsum, int nb) {
    __shared__ int buf[256];
    int t = threadIdx.x;
    int v = (t < nb) ? bsum[t] : 0;
    buf[t] = v;
    __syncthreads();
    for (int off = 1; off < 256; off <<= 1) {
        int tt = (t >= off) ? buf[t - off] : 0;
        __syncthreads();
        buf[t] += tt;
        __syncthreads();
    }
    if (t < nb) bsum[t] = buf[t] - v;   // exclusive
}
__global__ void k_scan3(int* __restrict__ roff, const int* __restrict__ bsum, int n) {
    int i = blockIdx.x * 256 + threadIdx.x;
    if (i > n) return;
    if (i == 0) { roff[0] = 0; return; }
    roff[i] += bsum[(i - 1) >> 8];
}
__global__ void k_copy(const int* __restrict__ roff, int* __restrict__ rpos, int n) {
    int i = blockIdx.x * 256 + threadIdx.x;
    if (i < n) rpos[i] = roff[i];
}
__global__ void k_scatter(const int* __restrict__ dst, int* __restrict__ rpos,
                          int* __restrict__ eids, int E, int n) {
    int e = blockIdx.x * 256 + threadIdx.x;
    if (e < E) {
        int p = atomicAdd(&rpos[clampi(dst[e], 0, n - 1)], 1);
        if (p >= 0 && p < E) eids[p] = e;
    }
}

// ---------------- gat1, CACHED variant --------------------------------------------------
__global__ __launch_bounds__(256) void k_gat1c(
    const u32* __restrict__ hp, const float* __restrict__ asrc, const float* __restrict__ adst,
    const void* eattr, const int* __restrict__ srcs,
    const int* __restrict__ roff, const int* __restrict__ eids,
    const int* __restrict__ flag, const float* __restrict__ consts, const void* bias,
    float* __restrict__ al, int* __restrict__ ssrc, float* __restrict__ eas,
    u32* __restrict__ out, int n, int E) {
    int f = *flag;
    int gtid = blockIdx.x * 256 + threadIdx.x;
    int wv = gtid >> 6, lane = gtid & 63;
    int nw = (gridDim.x * 256) >> 6;
    const float c0 = consts[0], c1 = consts[1], c2 = consts[2], c3 = consts[3];
    const int hsel = lane >> 5;
    const float biasA = load1(bias, lane, f);
    const float biasB = load1(bias, 64 + lane, f);

    for (int d = wv; d < n; d += nw) {
        int s0 = clampi(roff[d], 0, E);
        int s1 = clampi(roff[d + 1], s0, E);
        float4 adv = *(const float4*)&adst[d * 4];

        // pass 1: gather once, cache alpha/src/ea in CSR order, track max
        float m0 = -1e30f, m1 = -1e30f, m2 = -1e30f, m3 = -1e30f;
        for (int idx = s0 + lane; idx < s1; idx += 64) {
            int e = clampi(eids[idx], 0, E - 1);
            int s = clampi(srcs[e], 0, n - 1);
            float ea = load1(eattr, e, f);
            float4 av = *(const float4*)&asrc[s * 4];
            float a0 = lrelu(av.x + adv.x + ea * c0);
            float a1 = lrelu(av.y + adv.y + ea * c1);
            float a2 = lrelu(av.z + adv.z + ea * c2);
            float a3 = lrelu(av.w + adv.w + ea * c3);
            *(float4*)&al[(size_t)idx * 4] = make_float4(a0, a1, a2, a3);
            ssrc[idx] = s;
            eas[idx] = ea;
            m0 = fmaxf(m0, a0); m1 = fmaxf(m1, a1);
            m2 = fmaxf(m2, a2); m3 = fmaxf(m3, a3);
        }
        #pragma unroll
        for (int off = 32; off > 0; off >>= 1) {
            m0 = fmaxf(m0, __shfl_xor(m0, off));
            m1 = fmaxf(m1, __shfl_xor(m1, off));
            m2 = fmaxf(m2, __shfl_xor(m2, off));
            m3 = fmaxf(m3, __shfl_xor(m3, off));
        }
        // pass 2: coalesced exp + denom; store exp in place
        float d0 = 0.f, d1 = 0.f, d2 = 0.f, d3 = 0.f;
        for (int idx = s0 + lane; idx < s1; idx += 64) {
            float4 a = *(const float4*)&al[(size_t)idx * 4];
            float e0 = expf(a.x - m0), e1 = expf(a.y - m1);
            float e2 = expf(a.z - m2), e3 = expf(a.w - m3);
            d0 += e0; d1 += e1; d2 += e2; d3 += e3;
            *(float4*)&al[(size_t)idx * 4] = make_float4(e0, e1, e2, e3);
        }
        #pragma unroll
        for (int off = 32; off > 0; off >>= 1) {
            d0 += __shfl_xor(d0, off); d1 += __shfl_xor(d1, off);
            d2 += __shfl_xor(d2, off); d3 += __shfl_xor(d3, off);
        }
        float i0 = 1.f / (d0 + 1e-16f), i1 = 1.f / (d1 + 1e-16f);
        float i2 = 1.f / (d2 + 1e-16f), i3 = 1.f / (d3 + 1e-16f);
        float iA = hsel ? i1 : i0, iB = hsel ? i3 : i2;

        // pass 3: broadcast reads + one u32 gather + 2 FMA per edge
        float accA = 0.f, accB = 0.f;
        for (int idx = s0; idx < s1; idx++) {
            int s = ssrc[idx];
            float4 ex = *(const float4*)&al[(size_t)idx * 4];
            float wA = (hsel ? ex.y : ex.x) * iA;
            float wB = (hsel ? ex.w : ex.z) * iB;
            u32 hw = hp[(size_t)s * 64 + lane];
            accA += wA * bl(hw);
            accB += wB * bh(hw);
        }
        float rA = fmaxf(accA + biasA, 0.f);   // fused ReLU
        float rB = fmaxf(accB + biasB, 0.f);
        out[(size_t)d * 64 + lane] = (u32)f2bf(rA) | ((u32)f2bf(rB) << 16);
    }
}

// ---------------- gat2, CACHED variant --------------------------------------------------
__global__ __launch_bounds__(256) void k_gat2c(
    const u16* __restrict__ h, const float* __restrict__ asrc, const float* __restrict__ adst,
    const int* __restrict__ roff, const int* __restrict__ flag,
    const float* __restrict__ consts, const void* bias,
    float* __restrict__ al, const int* __restrict__ ssrc, const float* __restrict__ eas,
    u16* __restrict__ out, int n, int E) {
    int f = *flag;
    int gtid = blockIdx.x * 256 + threadIdx.x;
    int wv = gtid >> 6, lane = gtid & 63;
    int nw = (gridDim.x * 256) >> 6;
    const float C = consts[4];
    const float biasL = load1(bias, lane, f);

    for (int d = wv; d < n; d += nw) {
        int s0 = clampi(roff[d], 0, E);
        int s1 = clampi(roff[d + 1], s0, E);
        float ad = adst[d];
        float m = -1e30f;
        for (int idx = s0 + lane; idx < s1; idx += 64) {
            int s = ssrc[idx];
            float a = lrelu(asrc[s] + ad + eas[idx] * C);
            al[idx] = a;
            m = fmaxf(m, a);
        }
        #pragma unroll
        for (int off = 32; off > 0; off >>= 1) m = fmaxf(m, __shfl_xor(m, off));
        float den = 0.f;
        for (int idx = s0 + lane; idx < s1; idx += 64) {
            float e = expf(al[idx] - m);
            den += e;
            al[idx] = e;
        }
        #pragma unroll
        for (int off = 32; off > 0; off >>= 1) den += __shfl_xor(den, off);
        float inv = 1.f / (den + 1e-16f);

        float acc = 0.f;
        for (int idx = s0; idx < s1; idx++) {
            int s = ssrc[idx];
            float w = al[idx] * inv;
            acc += w * bf2f(h[(size_t)s * 64 + lane]);
        }
        out[(size_t)d * 64 + lane] = f2bf(acc + biasL);
    }
}

// ---------------- gat1/gat2 FALLBACK (recompute) variants -------------------------------
__global__ __launch_bounds__(256) void k_gat1f(
    const u32* __restrict__ hp, const float* __restrict__ asrc, const float* __restrict__ adst,
    const void* eattr, const int* __restrict__ srcs,
    const int* __restrict__ roff, const int* __restrict__ eids,
    const int* __restrict__ flag, const float* __restrict__ consts, const void* bias,
    u32* __restrict__ out, int n, int E) {
    int f = *flag;
    int gtid = blockIdx.x * 256 + threadIdx.x;
    int wv = gtid >> 6, lane = gtid & 63;
    int nw = (gridDim.x * 256) >> 6;
    const float c0 = consts[0], c1 = consts[1], c2 = consts[2], c3 = consts[3];
    const int hsel = lane >> 5;
    const float biasA = load1(bias, lane, f);
    const float biasB = load1(bias, 64 + lane, f);

    for (int d = wv; d < n; d += nw) {
        int s0 = clampi(roff[d], 0, E);
        int s1 = clampi(roff[d + 1], s0, E);
        float4 adv = *(const float4*)&adst[d * 4];
        float m0 = -1e30f, m1 = -1e30f, m2 = -1e30f, m3 = -1e30f;
        for (int idx = s0 + lane; idx < s1; idx += 64) {
            int e = clampi(eids[idx], 0, E - 1);
            int s = clampi(srcs[e], 0, n - 1);
            float ea = load1(eattr, e, f);
            float4 av = *(const float4*)&asrc[s * 4];
            m0 = fmaxf(m0, lrelu(av.x + adv.x + ea * c0));
            m1 = fmaxf(m1, lrelu(av.y + adv.y + ea * c1));
            m2 = fmaxf(m2, lrelu(av.z + adv.z + ea * c2));
            m3 = fmaxf(m3, lrelu(av.w + adv.w + ea * c3));
        }
        #pragma unroll
        for (int off = 32; off > 0; off >>= 1) {
            m0 = fmaxf(m0, __shfl_xor(m0, off));
            m1 = fmaxf(m1, __shfl_xor(m1, off));
            m2 = fmaxf(m2, __shfl_xor(m2, off));
            m3 = fmaxf(m3, __shfl_xor(m3, off));
        }
        float d0 = 0.f, d1 = 0.f, d2 = 0.f, d3 = 0.f;
        for (int idx = s0 + lane; idx < s1; idx += 64) {
            int e = clampi(eids[idx], 0, E - 1);
            int s = clampi(srcs[e], 0, n - 1);
            float ea = load1(eattr, e, f);
            float4 av = *(const float4*)&asrc[s * 4];
            d0 += expf(lrelu(av.x + adv.x + ea * c0) - m0);
            d1 += expf(lrelu(av.y + adv.y + ea * c1) - m1);
            d2 += expf(lrelu(av.z + adv.z + ea * c2) - m2);
            d3 += expf(lrelu(av.w + adv.w + ea * c3) - m3);
        }
        #pragma unroll
        for (int off = 32; off > 0; off >>= 1) {
            d0 += __shfl_xor(d0, off); d1 += __shfl_xor(d1, off);
            d2 += __shfl_xor(d2, off); d3 += __shfl_xor(d3, off);
        }
        float i0 = 1.f / (d0 + 1e-16f), i1 = 1.f / (d1 + 1e-16f);
        float i2 = 1.f / (d2 + 1e-16f), i3 = 1.f / (d3 + 1e-16f);
        float mA = hsel ? m1 : m0, mB = hsel ? m3 : m2;
        float iA = hsel ? i1 : i0, iB = hsel ? i3 : i2;
        float cA = hsel ? c1 : c0, cB = hsel ? c3 : c2;
        float aA = hsel ? adv.y : adv.x, aB = hsel ? adv.w : adv.z;

        float accA = 0.f, accB = 0.f;
        for (int idx = s0; idx < s1; idx++) {
            int e = clampi(eids[idx], 0, E - 1);
            int s = clampi(srcs[e], 0, n - 1);
            float ea = load1(eattr, e, f);
            float4 av = *(const float4*)&asrc[s * 4];
            float alA = lrelu((hsel ? av.y : av.x) + aA + ea * cA);
            float alB = lrelu((hsel ? av.w : av.z) + aB + ea * cB);
            float wA = expf(alA - mA) * iA;
            float wB = expf(alB - mB) * iB;
            u32 hw = hp[(size_t)s * 64 + lane];
            accA += wA * bl(hw);
            accB += wB * bh(hw);
        }
        float rA = fmaxf(accA + biasA, 0.f);
        float rB = fmaxf(accB + biasB, 0.f);
        out[(size_t)d * 64 + lane] = (u32)f2bf(rA) | ((u32)f2bf(rB) << 16);
    }
}

__global__ __launch_bounds__(256) void k_gat2f(
    const u16* __restrict__ h, const float* __restrict__ asrc, const float* __restrict__ adst,
    const void* eattr, const int* __restrict__ srcs,
    const int* __restrict__ roff, const int* __restrict__ eids,
    const int* __restrict__ flag, const float* __restrict__ consts, const void* bias,
    u16* __restrict__ out, int n, int E) {
    int f = *flag;
    int gtid = blockIdx.x * 256 + threadIdx.x;
    int wv = gtid >> 6, lane = gtid & 63;
    int nw = (gridDim.x * 256) >> 6;
    const float C = consts[4];
    const float biasL = load1(bias, lane, f);

    for (int d = wv; d < n; d += nw) {
        int s0 = clampi(roff[d], 0, E);
        int s1 = clampi(roff[d + 1], s0, E);
        float ad = adst[d];
        float m = -1e30f;
        for (int idx = s0 + lane; idx < s1; idx += 64) {
            int e = clampi(eids[idx], 0, E - 1);
            int s = clampi(srcs[e], 0, n - 1);
            m = fmaxf(m, lrelu(asrc[s] + ad + load1(eattr, e, f) * C));
        }
        #pragma unroll
        for (int off = 32; off > 0; off >>= 1) m = fmaxf(m, __shfl_xor(m, off));
        float den = 0.f;
        for (int idx = s0 + lane; idx < s1; idx += 64) {
            int e = clampi(eids[idx], 0, E - 1);
            int s = clampi(srcs[e], 0, n - 1);
            den += expf(lrelu(asrc[s] + ad + load1(eattr, e, f) * C) - m);
        }
        #pragma unroll
        for (int off = 32; off > 0; off >>= 1) den += __shfl_xor(den, off);
        float inv = 1.f / (den + 1e-16f);

        float acc = 0.f;
        for (int idx = s0; idx < s1; idx++) {
            int e = clampi(eids[idx], 0, E - 1);
            int s = clampi(srcs[e], 0, n - 1);
            float a = lrelu(asrc[s] + ad + load1(eattr, e, f) * C);
            acc += expf(a - m) * inv * bf2f(h[(size_t)s * 64 + lane]);
        }
        out[(size_t)d * 64 + lane] = f2bf(acc + biasL);
    }
}

// ---------------- pooling ---------------------------------------------------------------
__global__ void k_pool(const u16* __restrict__ agg2, const int* __restrict__ batch,
                       float* __restrict__ pool, float* __restrict__ cnt, int n, int G) {
    int t = blockIdx.x * 256 + threadIdx.x;
    int nb8 = (n + 7) / 8;
    if (t >= nb8 * 64) return;
    int base = (t >> 6) * 8;
    int c = t & 63;
    int end = min(base + 8, n);
    float acc = 0.f, cacc = 0.f;
    int curg = clampi(batch[base], 0, G - 1);
    for (int j = base; j < end; j++) {
        int g = clampi(batch[j], 0, G - 1);
        if (g != curg) {
            atomicAdd(&pool[curg * 64 + c], acc);
            if (c == 0) atomicAdd(&cnt[curg], cacc);
            acc = 0.f; cacc = 0.f; curg = g;
        }
        acc += bf2f(agg2[(size_t)j * 64 + c]);
        cacc += 1.f;
    }
    atomicAdd(&pool[curg * 64 + c], acc);
    if (c == 0) atomicAdd(&cnt[curg], cacc);
}

__global__ void k_head(const float* __restrict__ pool, const float* __restrict__ cnt,
                       const void* Wp, const void* bp, const int* __restrict__ flag,
                       void* out, int G) {
    int f = *flag;
    int g = threadIdx.x;
    if (g >= G) return;
    float s = 0.f;
    for (int c = 0; c < 64; c++) s += pool[g * 64 + c] * load1(Wp, c, f);
    float cv = cnt[g];
    if (!(cv > 0.f)) cv = 1.f;
    float r = s / cv + load1(bp, 0, f);
    if (f) ((float*)out)[g] = r;
    else   ((u16*)out)[g] = f2bf(r);
}

// ---------------- launch ----------------------------------------------------------------
extern "C" void kernel_launch(void* const* d_in, const int* in_sizes, int n_in,
                              void* d_out, int out_size, void* d_ws, size_t ws_size,
                              hipStream_t stream) {
    const void* x    = d_in[0];
    const int* ei    = (const int*)d_in[1];
    const void* eattr = d_in[2];
    const int* batch = (const int*)d_in[3];
    const void* W1   = d_in[4];
    const void* as1  = d_in[5];
    const void* ad1  = d_in[6];
    const void* We1  = d_in[7];
    const void* ae1  = d_in[8];
    const void* b1   = d_in[9];
    const void* W2   = d_in[10];
    const void* as2  = d_in[11];
    const void* ad2  = d_in[12];
    const void* We2  = d_in[13];
    const void* ae2  = d_in[14];
    const void* b2   = d_in[15];
    const void* Wp   = d_in[16];
    const void* bp   = d_in[17];

    const int N = in_sizes[3];
    const int E = in_sizes[2];
    const int G = out_size;
    const int* src = ei;
    const int* dst = ei + E;

    char* p = (char*)d_ws;
    auto alloc = [&](size_t bytes) -> char* {
        char* r = p;
        p += (bytes + 255) & ~(size_t)255;
        return r;
    };
    int* flag    = (int*)alloc(32);
    float* consts = (float*)alloc(2048);
    int* roff    = (int*)alloc((size_t)(N + 1) * 4);
    int* rpos    = (int*)alloc((size_t)N * 4);
    int* bsum    = (int*)alloc(256 * 4);
    int* eids    = (int*)alloc((size_t)E * 4);
    float* pool  = (float*)alloc((size_t)(G * 64 + G) * 4);
    float* cnt   = pool + (size_t)G * 64;
    float* asrc1 = (float*)alloc((size_t)N * 4 * 4);
    float* adst1 = (float*)alloc((size_t)N * 4 * 4);
    float* asrc2 = asrc1;             // alias: dead after gat1
    float* adst2 = adst1;
    u16* agg1    = (u16*)alloc((size_t)N * 128 * 2);
    u16* h1      = (u16*)alloc((size_t)N * 128 * 2);
    u16* h2      = h1;                // alias: h1 dead after gat1
    u16* agg2    = h1 + (size_t)N * 64;
    size_t base_need = (size_t)(p - (char*)d_ws);
    // cached-path buffers (allocated last; only used if they fit)
    int*   ssrc = (int*)alloc((size_t)E * 4);
    float* eas  = (float*)alloc((size_t)E * 4);
    float* al   = (float*)alloc((size_t)E * 16);
    size_t full_need = (size_t)(p - (char*)d_ws);
    const bool cached = (ws_size >= full_need);
    (void)base_need;

    hipMemsetAsync(rpos, 0, (size_t)N * 4, stream);
    hipMemsetAsync(pool, 0, (size_t)(G * 64 + G) * 4, stream);

    k_detect<<<1, 64, 0, stream>>>((const u32*)x, flag);
    k_consts<<<1, 256, 0, stream>>>(We1, ae1, We2, ae2, as1, ad1, as2, ad2, flag, consts);
    k_gemm5<128><<<512, 256, 0, stream>>>(x, W1, flag, -1, h1, N);
    k_coef1<<<(N * 2 + 255) / 256, 256, 0, stream>>>((const u32*)h1, consts, asrc1, adst1, N);

    int NB = (N + 255) / 256;
    k_count<<<(E + 255) / 256, 256, 0, stream>>>(dst, rpos, E, N);
    k_scan1<<<NB, 256, 0, stream>>>(rpos, roff + 1, bsum, N);
    k_scan2<<<1, 256, 0, stream>>>(bsum, NB);
    k_scan3<<<(N + 256) / 256, 256, 0, stream>>>(roff, bsum, N);
    k_copy<<<NB, 256, 0, stream>>>(roff, rpos, N);
    k_scatter<<<(E + 255) / 256, 256, 0, stream>>>(dst, rpos, eids, E, N);

    int gatBlocks = (N * 64 + 255) / 256;
    if (cached) {
        k_gat1c<<<gatBlocks, 256, 0, stream>>>((const u32*)h1, asrc1, adst1, eattr, src,
                                               roff, eids, flag, consts, b1,
                                               al, ssrc, eas, (u32*)agg1, N, E);
    } else {
        k_gat1f<<<gatBlocks, 256, 0, stream>>>((const u32*)h1, asrc1, adst1, eattr, src,
                                               roff, eids, flag, consts, b1,
                                               (u32*)agg1, N, E);
    }
    k_gemm5<64><<<512, 256, 0, stream>>>(agg1, W2, flag, 0, h2, N);
    k_coef2<<<(N + 255) / 256, 256, 0, stream>>>((const u32*)h2, consts, asrc2, adst2, N);
    if (cached) {
        k_gat2c<<<gatBlocks, 256, 0, stream>>>(h2, asrc2, adst2, roff, flag, consts, b2,
                                               al, ssrc, eas, agg2, N, E);
    } else {
        k_gat2f<<<gatBlocks, 256, 0, stream>>>(h2, asrc2, adst2, eattr, src, roff, eids,
                                               flag, consts, b2, agg2, N, E);
    }
    k_pool<<<(((N + 7) / 8) * 64 + 255) / 256, 256, 0, stream>>>(agg2, batch, pool, cnt, N, G);
    k_head<<<1, 64, 0, stream>>>(pool, cnt, Wp, bp, flag, d_out, G);
}

// Round 7
// 525.178 us; speedup vs baseline: 3.7552x; 1.0169x over previous
//
#include <hip/hip_runtime.h>
#include <hip/hip_bf16.h>

typedef unsigned short u16;
typedef unsigned int u32;

__device__ __forceinline__ float bf2f(u16 u) { return __uint_as_float(((u32)u) << 16); }
__device__ __forceinline__ float bl(u32 u) { return __uint_as_float(u << 16); }
__device__ __forceinline__ float bh(u32 u) { return __uint_as_float(u & 0xffff0000u); }
__device__ __forceinline__ u16 f2bf(float f) {
    u32 u = __float_as_uint(f);
    u += 0x7fffu + ((u >> 16) & 1u);   // round-to-nearest-even
    return (u16)(u >> 16);
}
__device__ __forceinline__ float lrelu(float x) { return x > 0.f ? x : 0.2f * x; }
__device__ __forceinline__ int clampi(int v, int lo, int hi) {
    return v < lo ? lo : (v > hi ? hi : v);
}
__device__ __forceinline__ float load1(const void* base, int idx, int f32) {
    return f32 ? ((const float*)base)[idx] : bf2f(((const u16*)base)[idx]);
}

// ---------------- dtype detector ---------------------------------------------------------
__global__ void k_detect(const u32* __restrict__ xw, int* __restrict__ flag) {
    int lane = threadIdx.x & 63;
    int cnt = 0;
    #pragma unroll
    for (int j = 0; j < 4; j++) {
        u32 w = xw[lane * 4 + j];
        int e0 = (int)((w >> 7) & 0xffu);
        int e1 = (int)((w >> 23) & 0xffu);
        cnt += (e0 >= 0x60 && e0 <= 0x8f);
        cnt += (e1 >= 0x60 && e1 <= 0x8f);
    }
    #pragma unroll
    for (int off = 32; off > 0; off >>= 1) cnt += __shfl_xor(cnt, off);
    if (lane == 0) *flag = (cnt < 480) ? 1 : 0;
}

// ---------------- constants + fp32 expansion of attention vectors -----------------------
// consts layout (floats): [0..3]=C1 per head, [4]=C2, [8..135]=as1f, [136..263]=ad1f,
// [264..327]=as2f, [328..391]=ad2f
__global__ void k_consts(const void* We1, const void* ae1, const void* We2, const void* ae2,
                         const void* as1, const void* ad1, const void* as2, const void* ad2,
                         const int* __restrict__ flag, float* __restrict__ consts) {
    int f = *flag;
    int t = threadIdx.x;
    if (t < 4) {
        float s = 0.f;
        for (int c = 0; c < 32; c++) s += load1(We1, t * 32 + c, f) * load1(ae1, t * 32 + c, f);
        consts[t] = s;
    } else if (t == 4) {
        float s = 0.f;
        for (int c = 0; c < 64; c++) s += load1(We2, c, f) * load1(ae2, c, f);
        consts[4] = s;
    }
    if (t < 128) {
        consts[8 + t] = load1(as1, t, f);
        consts[136 + t] = load1(ad1, t, f);
    }
    if (t < 64) {
        consts[264 + t] = load1(as2, t, f);
        consts[328 + t] = load1(ad2, t, f);
    }
}

// ---------------- GEMM: Y[nrows,NC] = X[nrows,128] @ W[128,NC] --------------------------
// NC==128: output PAIRED layout (u32 word = (ch c | ch c+64<<16) at word row*64+c).
// NC==64:  X (agg1) is PAIRED -> W rows permuted during staging; natural u16 output.
template <int NC>
__global__ __launch_bounds__(256, 4) void k_gemm5(
    const void* __restrict__ X, const void* __restrict__ Wg,
    const int* __restrict__ flag, int fXovr, u16* __restrict__ Y, int nrows) {
    constexpr int K = 128;
    constexpr int ROWS = 32;
    __shared__ float Ws[K * NC];
    __shared__ float Xs[ROWS * K];

    const int f = *flag;
    const bool fX = (fXovr < 0) ? (f != 0) : (fXovr != 0);
    const bool fW = (f != 0);
    const int tid = threadIdx.x, wid = tid >> 6, lane = tid & 63;

    for (int i = tid * 4; i < K * NC; i += 256 * 4) {
        int j = i / NC;
        int col = i & (NC - 1);
        int srow = (NC == 64) ? ((j & 1) * 64 + (j >> 1)) : j;
        int g = srow * NC + col;
        if (fW) {
            float4 v = *(const float4*)((const float*)Wg + g);
            Ws[i] = v.x; Ws[i + 1] = v.y; Ws[i + 2] = v.z; Ws[i + 3] = v.w;
        } else {
            ushort4 r = *(const ushort4*)((const u16*)Wg + g);
            Ws[i] = bf2f(r.x); Ws[i + 1] = bf2f(r.y);
            Ws[i + 2] = bf2f(r.z); Ws[i + 3] = bf2f(r.w);
        }
    }

    const int sr = tid >> 3;           // staging row 0..31
    const int sc = (tid & 7) * 16;     // staging col 0,16,..112

    for (int base = blockIdx.x * ROWS; base < nrows; base += gridDim.x * ROWS) {
        __syncthreads();
        {
            int row = base + sr;
            float* xs = &Xs[sr * K + sc];
            if (row < nrows) {
                if (fX) {
                    const float* xp = (const float*)X + (size_t)row * K + sc;
                    float4 a = *(const float4*)xp;
                    float4 b = *(const float4*)(xp + 4);
                    float4 c = *(const float4*)(xp + 8);
                    float4 d = *(const float4*)(xp + 12);
                    xs[0] = a.x; xs[1] = a.y; xs[2] = a.z; xs[3] = a.w;
                    xs[4] = b.x; xs[5] = b.y; xs[6] = b.z; xs[7] = b.w;
                    xs[8] = c.x; xs[9] = c.y; xs[10] = c.z; xs[11] = c.w;
                    xs[12] = d.x; xs[13] = d.y; xs[14] = d.z; xs[15] = d.w;
                } else {
                    const u16* xp = (const u16*)X + (size_t)row * K + sc;
                    uint4 a = *(const uint4*)xp;
                    uint4 b = *(const uint4*)(xp + 8);
                    xs[0] = bl(a.x); xs[1] = bh(a.x); xs[2] = bl(a.y); xs[3] = bh(a.y);
                    xs[4] = bl(a.z); xs[5] = bh(a.z); xs[6] = bl(a.w); xs[7] = bh(a.w);
                    xs[8] = bl(b.x); xs[9] = bh(b.x); xs[10] = bl(b.y); xs[11] = bh(b.y);
                    xs[12] = bl(b.z); xs[13] = bh(b.z); xs[14] = bl(b.w); xs[15] = bh(b.w);
                }
            } else {
                #pragma unroll
                for (int j = 0; j < 16; j++) xs[j] = 0.f;
            }
        }
        __syncthreads();

        float acc0[8] = {0.f, 0.f, 0.f, 0.f, 0.f, 0.f, 0.f, 0.f};
        float acc1[8] = {0.f, 0.f, 0.f, 0.f, 0.f, 0.f, 0.f, 0.f};
        #pragma unroll 2
        for (int k = 0; k < K; k += 4) {
            float wa0 = Ws[(k + 0) * NC + lane];
            float wa1 = Ws[(k + 1) * NC + lane];
            float wa2 = Ws[(k + 2) * NC + lane];
            float wa3 = Ws[(k + 3) * NC + lane];
            float wb0 = 0.f, wb1 = 0.f, wb2 = 0.f, wb3 = 0.f;
            if constexpr (NC == 128) {
                wb0 = Ws[(k + 0) * NC + lane + 64];
                wb1 = Ws[(k + 1) * NC + lane + 64];
                wb2 = Ws[(k + 2) * NC + lane + 64];
                wb3 = Ws[(k + 3) * NC + lane + 64];
            }
            #pragma unroll
            for (int rr = 0; rr < 8; rr++) {
                float4 xv = *(const float4*)&Xs[(wid * 8 + rr) * K + k];
                acc0[rr] += xv.x * wa0 + xv.y * wa1 + xv.z * wa2 + xv.w * wa3;
                if constexpr (NC == 128)
                    acc1[rr] += xv.x * wb0 + xv.y * wb1 + xv.z * wb2 + xv.w * wb3;
            }
        }

        #pragma unroll
        for (int rr = 0; rr < 8; rr++) {
            int row = base + wid * 8 + rr;
            if (row < nrows) {
                if constexpr (NC == 128) {
                    u32 w = (u32)f2bf(acc0[rr]) | ((u32)f2bf(acc1[rr]) << 16);
                    ((u32*)Y)[(size_t)row * 64 + lane] = w;
                } else {
                    Y[(size_t)row * 64 + lane] = f2bf(acc0[rr]);
                }
            }
        }
    }
}

// ---------------- coef1: paired h1 -> asrc1/adst1 [N][4] --------------------------------
__global__ void k_coef1(const u32* __restrict__ hp, const float* __restrict__ consts,
                        float* __restrict__ asrc, float* __restrict__ adst, int n) {
    int i = blockIdx.x * 256 + threadIdx.x;
    if (i >= n * 2) return;
    int node = i >> 1, g = i & 1;
    const u32* w = hp + (size_t)node * 64 + g * 32;
    const float* asA = consts + 8 + g * 32;
    const float* adA = consts + 136 + g * 32;
    const float* asB = consts + 8 + (g + 2) * 32;
    const float* adB = consts + 136 + (g + 2) * 32;
    float sA1 = 0.f, sA2 = 0.f, sB1 = 0.f, sB2 = 0.f;
    #pragma unroll
    for (int c = 0; c < 32; c += 4) {
        uint4 q = *(const uint4*)&w[c];
        float l0 = bl(q.x), h0 = bh(q.x), l1 = bl(q.y), h1 = bh(q.y);
        float l2 = bl(q.z), h2 = bh(q.z), l3 = bl(q.w), h3 = bh(q.w);
        sA1 += l0 * asA[c] + l1 * asA[c + 1] + l2 * asA[c + 2] + l3 * asA[c + 3];
        sA2 += l0 * adA[c] + l1 * adA[c + 1] + l2 * adA[c + 2] + l3 * adA[c + 3];
        sB1 += h0 * asB[c] + h1 * asB[c + 1] + h2 * asB[c + 2] + h3 * asB[c + 3];
        sB2 += h0 * adB[c] + h1 * adB[c + 1] + h2 * adB[c + 2] + h3 * adB[c + 3];
    }
    asrc[node * 4 + g] = sA1;     adst[node * 4 + g] = sA2;
    asrc[node * 4 + g + 2] = sB1; adst[node * 4 + g + 2] = sB2;
}

// ---------------- coef2: natural h2 -> asrc2/adst2 [N] ----------------------------------
__global__ void k_coef2(const u32* __restrict__ hp, const float* __restrict__ consts,
                        float* __restrict__ asrc, float* __restrict__ adst, int n) {
    int i = blockIdx.x * 256 + threadIdx.x;
    if (i >= n) return;
    const u32* w = hp + (size_t)i * 32;
    const float* as_ = consts + 264;
    const float* ad_ = consts + 328;
    float s1 = 0.f, s2 = 0.f;
    #pragma unroll
    for (int c = 0; c < 32; c += 4) {
        uint4 q = *(const uint4*)&w[c];
        float l0 = bl(q.x), h0 = bh(q.x), l1 = bl(q.y), h1 = bh(q.y);
        float l2 = bl(q.z), h2 = bh(q.z), l3 = bl(q.w), h3 = bh(q.w);
        s1 += l0 * as_[2*c] + h0 * as_[2*c+1] + l1 * as_[2*c+2] + h1 * as_[2*c+3]
            + l2 * as_[2*c+4] + h2 * as_[2*c+5] + l3 * as_[2*c+6] + h3 * as_[2*c+7];
        s2 += l0 * ad_[2*c] + h0 * ad_[2*c+1] + l1 * ad_[2*c+2] + h1 * ad_[2*c+3]
            + l2 * ad_[2*c+4] + h2 * ad_[2*c+5] + l3 * ad_[2*c+6] + h3 * ad_[2*c+7];
    }
    asrc[i] = s1; adst[i] = s2;
}

// ---------------- CSR build -------------------------------------------------------------
__global__ void k_count(const int* __restrict__ dst, int* __restrict__ cnt, int E, int n) {
    int e = blockIdx.x * 256 + threadIdx.x;
    if (e < E) atomicAdd(&cnt[clampi(dst[e], 0, n - 1)], 1);
}
__global__ void k_scan1(const int* __restrict__ cnt, int* __restrict__ part,
                        int* __restrict__ bsum, int n) {
    __shared__ int buf[256];
    int i = blockIdx.x * 256 + threadIdx.x;
    int v = (i < n) ? cnt[i] : 0;
    buf[threadIdx.x] = v;
    __syncthreads();
    for (int off = 1; off < 256; off <<= 1) {
        int t = (threadIdx.x >= off) ? buf[threadIdx.x - off] : 0;
        __syncthreads();
        buf[threadIdx.x] += t;
        __syncthreads();
    }
    if (i < n) part[i] = buf[threadIdx.x];
    if (threadIdx.x == 255) bsum[blockIdx.x] = buf[255];
}
__global__ void k_scan2(int* __restrict__ bsum, int nb) {
    __shared__ int buf[256];
    int t = threadIdx.x;
    int v = (t < nb) ? bsum[t] : 0;
    buf[t] = v;
    __syncthreads();
    for (int off = 1; off < 256; off <<= 1) {
        int tt = (t >= off) ? buf[t - off] : 0;
        __syncthreads();
        buf[t] += tt;
        __syncthreads();
    }
    if (t < nb) bsum[t] = buf[t] - v;   // exclusive
}
// finalize roff AND seed rpos with the same value (fused old k_scan3+k_copy)
__global__ void k_scan3(int* __restrict__ roff, const int* __restrict__ bsum,
                        int* __restrict__ rpos, int n) {
    int i = blockIdx.x * 256 + threadIdx.x;
    if (i > n) return;
    int v;
    if (i == 0) { v = 0; roff[0] = 0; }
    else { v = roff[i] + bsum[(i - 1) >> 8]; roff[i] = v; }
    if (i < n) rpos[i] = v;
}
// payload scatter: edata[p] = {src, ea} — removes the eids->srcs->eattr gather chain
__global__ void k_scatter(const int* __restrict__ dst, const int* __restrict__ src,
                          const void* eattr, const int* __restrict__ flag,
                          int* __restrict__ rpos, int2* __restrict__ edata, int E, int n) {
    int f = *flag;
    int e = blockIdx.x * 256 + threadIdx.x;
    if (e < E) {
        int d = clampi(dst[e], 0, n - 1);
        int s = clampi(src[e], 0, n - 1);
        float ea = load1(eattr, e, f);
        int p = atomicAdd(&rpos[d], 1);
        if (p >= 0 && p < E) {
            int2 v; v.x = s; v.y = __float_as_int(ea);
            edata[p] = v;
        }
    }
}

// ---------------- gat1, CACHED variant --------------------------------------------------
__global__ __launch_bounds__(256) void k_gat1c(
    const u32* __restrict__ hp, const float* __restrict__ asrc, const float* __restrict__ adst,
    const int2* __restrict__ edata, const int* __restrict__ roff,
    const int* __restrict__ flag, const float* __restrict__ consts, const void* bias,
    float* __restrict__ al, u32* __restrict__ out, int n, int E) {
    int f = *flag;
    int gtid = blockIdx.x * 256 + threadIdx.x;
    int wv = gtid >> 6, lane = gtid & 63;
    int nw = (gridDim.x * 256) >> 6;
    const float c0 = consts[0], c1 = consts[1], c2 = consts[2], c3 = consts[3];
    const int hsel = lane >> 5;
    const float biasA = load1(bias, lane, f);
    const float biasB = load1(bias, 64 + lane, f);

    for (int d = wv; d < n; d += nw) {
        int s0 = clampi(roff[d], 0, E);
        int s1 = clampi(roff[d + 1], s0, E);
        float4 adv = *(const float4*)&adst[d * 4];

        // pass 1: coalesced edata read + ONE asrc gather; cache alpha, track max
        float m0 = -1e30f, m1 = -1e30f, m2 = -1e30f, m3 = -1e30f;
        for (int idx = s0 + lane; idx < s1; idx += 64) {
            int2 ed = edata[idx];
            int s = ed.x;
            float ea = __int_as_float(ed.y);
            float4 av = *(const float4*)&asrc[(size_t)s * 4];
            float a0 = lrelu(av.x + adv.x + ea * c0);
            float a1 = lrelu(av.y + adv.y + ea * c1);
            float a2 = lrelu(av.z + adv.z + ea * c2);
            float a3 = lrelu(av.w + adv.w + ea * c3);
            *(float4*)&al[(size_t)idx * 4] = make_float4(a0, a1, a2, a3);
            m0 = fmaxf(m0, a0); m1 = fmaxf(m1, a1);
            m2 = fmaxf(m2, a2); m3 = fmaxf(m3, a3);
        }
        #pragma unroll
        for (int off = 32; off > 0; off >>= 1) {
            m0 = fmaxf(m0, __shfl_xor(m0, off));
            m1 = fmaxf(m1, __shfl_xor(m1, off));
            m2 = fmaxf(m2, __shfl_xor(m2, off));
            m3 = fmaxf(m3, __shfl_xor(m3, off));
        }
        // pass 2: coalesced exp + denom; store exp in place
        float d0 = 0.f, d1 = 0.f, d2 = 0.f, d3 = 0.f;
        for (int idx = s0 + lane; idx < s1; idx += 64) {
            float4 a = *(const float4*)&al[(size_t)idx * 4];
            float e0 = expf(a.x - m0), e1 = expf(a.y - m1);
            float e2 = expf(a.z - m2), e3 = expf(a.w - m3);
            d0 += e0; d1 += e1; d2 += e2; d3 += e3;
            *(float4*)&al[(size_t)idx * 4] = make_float4(e0, e1, e2, e3);
        }
        #pragma unroll
        for (int off = 32; off > 0; off >>= 1) {
            d0 += __shfl_xor(d0, off); d1 += __shfl_xor(d1, off);
            d2 += __shfl_xor(d2, off); d3 += __shfl_xor(d3, off);
        }
        float i0 = 1.f / (d0 + 1e-16f), i1 = 1.f / (d1 + 1e-16f);
        float i2 = 1.f / (d2 + 1e-16f), i3 = 1.f / (d3 + 1e-16f);
        float iA = hsel ? i1 : i0, iB = hsel ? i3 : i2;

        // pass 3: broadcast reads + one u32 gather + 2 FMA per edge
        float accA = 0.f, accB = 0.f;
        for (int idx = s0; idx < s1; idx++) {
            int s = edata[idx].x;
            float4 ex = *(const float4*)&al[(size_t)idx * 4];
            float wA = (hsel ? ex.y : ex.x) * iA;
            float wB = (hsel ? ex.w : ex.z) * iB;
            u32 hw = hp[(size_t)s * 64 + lane];
            accA += wA * bl(hw);
            accB += wB * bh(hw);
        }
        float rA = fmaxf(accA + biasA, 0.f);   // fused ReLU
        float rB = fmaxf(accB + biasB, 0.f);
        out[(size_t)d * 64 + lane] = (u32)f2bf(rA) | ((u32)f2bf(rB) << 16);
    }
}

// ---------------- gat2, CACHED variant --------------------------------------------------
__global__ __launch_bounds__(256) void k_gat2c(
    const u16* __restrict__ h, const float* __restrict__ asrc, const float* __restrict__ adst,
    const int2* __restrict__ edata, const int* __restrict__ roff,
    const int* __restrict__ flag, const float* __restrict__ consts, const void* bias,
    float* __restrict__ al, u16* __restrict__ out, int n, int E) {
    int f = *flag;
    int gtid = blockIdx.x * 256 + threadIdx.x;
    int wv = gtid >> 6, lane = gtid & 63;
    int nw = (gridDim.x * 256) >> 6;
    const float C = consts[4];
    const float biasL = load1(bias, lane, f);

    for (int d = wv; d < n; d += nw) {
        int s0 = clampi(roff[d], 0, E);
        int s1 = clampi(roff[d + 1], s0, E);
        float ad = adst[d];
        float m = -1e30f;
        for (int idx = s0 + lane; idx < s1; idx += 64) {
            int2 ed = edata[idx];
            float a = lrelu(asrc[ed.x] + ad + __int_as_float(ed.y) * C);
            al[idx] = a;
            m = fmaxf(m, a);
        }
        #pragma unroll
        for (int off = 32; off > 0; off >>= 1) m = fmaxf(m, __shfl_xor(m, off));
        float den = 0.f;
        for (int idx = s0 + lane; idx < s1; idx += 64) {
            float e = expf(al[idx] - m);
            den += e;
            al[idx] = e;
        }
        #pragma unroll
        for (int off = 32; off > 0; off >>= 1) den += __shfl_xor(den, off);
        float inv = 1.f / (den + 1e-16f);

        float acc = 0.f;
        for (int idx = s0; idx < s1; idx++) {
            int s = edata[idx].x;
            float w = al[idx] * inv;
            acc += w * bf2f(h[(size_t)s * 64 + lane]);
        }
        out[(size_t)d * 64 + lane] = f2bf(acc + biasL);
    }
}

// ---------------- gat1/gat2 FALLBACK (recompute, no al cache) ---------------------------
__global__ __launch_bounds__(256) void k_gat1f(
    const u32* __restrict__ hp, const float* __restrict__ asrc, const float* __restrict__ adst,
    const int2* __restrict__ edata, const int* __restrict__ roff,
    const int* __restrict__ flag, const float* __restrict__ consts, const void* bias,
    u32* __restrict__ out, int n, int E) {
    int f = *flag;
    int gtid = blockIdx.x * 256 + threadIdx.x;
    int wv = gtid >> 6, lane = gtid & 63;
    int nw = (gridDim.x * 256) >> 6;
    const float c0 = consts[0], c1 = consts[1], c2 = consts[2], c3 = consts[3];
    const int hsel = lane >> 5;
    const float biasA = load1(bias, lane, f);
    const float biasB = load1(bias, 64 + lane, f);

    for (int d = wv; d < n; d += nw) {
        int s0 = clampi(roff[d], 0, E);
        int s1 = clampi(roff[d + 1], s0, E);
        float4 adv = *(const float4*)&adst[d * 4];
        float m0 = -1e30f, m1 = -1e30f, m2 = -1e30f, m3 = -1e30f;
        for (int idx = s0 + lane; idx < s1; idx += 64) {
            int2 ed = edata[idx];
            float ea = __int_as_float(ed.y);
            float4 av = *(const float4*)&asrc[(size_t)ed.x * 4];
            m0 = fmaxf(m0, lrelu(av.x + adv.x + ea * c0));
            m1 = fmaxf(m1, lrelu(av.y + adv.y + ea * c1));
            m2 = fmaxf(m2, lrelu(av.z + adv.z + ea * c2));
            m3 = fmaxf(m3, lrelu(av.w + adv.w + ea * c3));
        }
        #pragma unroll
        for (int off = 32; off > 0; off >>= 1) {
            m0 = fmaxf(m0, __shfl_xor(m0, off));
            m1 = fmaxf(m1, __shfl_xor(m1, off));
            m2 = fmaxf(m2, __shfl_xor(m2, off));
            m3 = fmaxf(m3, __shfl_xor(m3, off));
        }
        float d0 = 0.f, d1 = 0.f, d2 = 0.f, d3 = 0.f;
        for (int idx = s0 + lane; idx < s1; idx += 64) {
            int2 ed = edata[idx];
            float ea = __int_as_float(ed.y);
            float4 av = *(const float4*)&asrc[(size_t)ed.x * 4];
            d0 += expf(lrelu(av.x + adv.x + ea * c0) - m0);
            d1 += expf(lrelu(av.y + adv.y + ea * c1) - m1);
            d2 += expf(lrelu(av.z + adv.z + ea * c2) - m2);
            d3 += expf(lrelu(av.w + adv.w + ea * c3) - m3);
        }
        #pragma unroll
        for (int off = 32; off > 0; off >>= 1) {
            d0 += __shfl_xor(d0, off); d1 += __shfl_xor(d1, off);
            d2 += __shfl_xor(d2, off); d3 += __shfl_xor(d3, off);
        }
        float i0 = 1.f / (d0 + 1e-16f), i1 = 1.f / (d1 + 1e-16f);
        float i2 = 1.f / (d2 + 1e-16f), i3 = 1.f / (d3 + 1e-16f);
        float mA = hsel ? m1 : m0, mB = hsel ? m3 : m2;
        float iA = hsel ? i1 : i0, iB = hsel ? i3 : i2;
        float cA = hsel ? c1 : c0, cB = hsel ? c3 : c2;
        float aA = hsel ? adv.y : adv.x, aB = hsel ? adv.w : adv.z;

        float accA = 0.f, accB = 0.f;
        for (int idx = s0; idx < s1; idx++) {
            int2 ed = edata[idx];
            float ea = __int_as_float(ed.y);
            float4 av = *(const float4*)&asrc[(size_t)ed.x * 4];
            float alA = lrelu((hsel ? av.y : av.x) + aA + ea * cA);
            float alB = lrelu((hsel ? av.w : av.z) + aB + ea * cB);
            float wA = expf(alA - mA) * iA;
            float wB = expf(alB - mB) * iB;
            u32 hw = hp[(size_t)ed.x * 64 + lane];
            accA += wA * bl(hw);
            accB += wB * bh(hw);
        }
        float rA = fmaxf(accA + biasA, 0.f);
        float rB = fmaxf(accB + biasB, 0.f);
        out[(size_t)d * 64 + lane] = (u32)f2bf(rA) | ((u32)f2bf(rB) << 16);
    }
}

__global__ __launch_bounds__(256) void k_gat2f(
    const u16* __restrict__ h, const float* __restrict__ asrc, const float* __restrict__ adst,
    const int2* __restrict__ edata, const int* __restrict__ roff,
    const int* __restrict__ flag, const float* __restrict__ consts, const void* bias,
    u16* __restrict__ out, int n, int E) {
    int f = *flag;
    int gtid = blockIdx.x * 256 + threadIdx.x;
    int wv = gtid >> 6, lane = gtid & 63;
    int nw = (gridDim.x * 256) >> 6;
    const float C = consts[4];
    const float biasL = load1(bias, lane, f);

    for (int d = wv; d < n; d += nw) {
        int s0 = clampi(roff[d], 0, E);
        int s1 = clampi(roff[d + 1], s0, E);
        float ad = adst[d];
        float m = -1e30f;
        for (int idx = s0 + lane; idx < s1; idx += 64) {
            int2 ed = edata[idx];
            m = fmaxf(m, lrelu(asrc[ed.x] + ad + __int_as_float(ed.y) * C));
        }
        #pragma unroll
        for (int off = 32; off > 0; off >>= 1) m = fmaxf(m, __shfl_xor(m, off));
        float den = 0.f;
        for (int idx = s0 + lane; idx < s1; idx += 64) {
            int2 ed = edata[idx];
            den += expf(lrelu(asrc[ed.x] + ad + __int_as_float(ed.y) * C) - m);
        }
        #pragma unroll
        for (int off = 32; off > 0; off >>= 1) den += __shfl_xor(den, off);
        float inv = 1.f / (den + 1e-16f);

        float acc = 0.f;
        for (int idx = s0; idx < s1; idx++) {
            int2 ed = edata[idx];
            float a = lrelu(asrc[ed.x] + ad + __int_as_float(ed.y) * C);
            acc += expf(a - m) * inv * bf2f(h[(size_t)ed.x * 64 + lane]);
        }
        out[(size_t)d * 64 + lane] = f2bf(acc + biasL);
    }
}

// ---------------- pooling ---------------------------------------------------------------
__global__ void k_pool(const u16* __restrict__ agg2, const int* __restrict__ batch,
                       float* __restrict__ pool, float* __restrict__ cnt, int n, int G) {
    int t = blockIdx.x * 256 + threadIdx.x;
    int nb8 = (n + 7) / 8;
    if (t >= nb8 * 64) return;
    int base = (t >> 6) * 8;
    int c = t & 63;
    int end = min(base + 8, n);
    float acc = 0.f, cacc = 0.f;
    int curg = clampi(batch[base], 0, G - 1);
    for (int j = base; j < end; j++) {
        int g = clampi(batch[j], 0, G - 1);
        if (g != curg) {
            atomicAdd(&pool[curg * 64 + c], acc);
            if (c == 0) atomicAdd(&cnt[curg], cacc);
            acc = 0.f; cacc = 0.f; curg = g;
        }
        acc += bf2f(agg2[(size_t)j * 64 + c]);
        cacc += 1.f;
    }
    atomicAdd(&pool[curg * 64 + c], acc);
    if (c == 0) atomicAdd(&cnt[curg], cacc);
}

__global__ void k_head(const float* __restrict__ pool, const float* __restrict__ cnt,
                       const void* Wp, const void* bp, const int* __restrict__ flag,
                       void* out, int G) {
    int f = *flag;
    int g = threadIdx.x;
    if (g >= G) return;
    float s = 0.f;
    for (int c = 0; c < 64; c++) s += pool[g * 64 + c] * load1(Wp, c, f);
    float cv = cnt[g];
    if (!(cv > 0.f)) cv = 1.f;
    float r = s / cv + load1(bp, 0, f);
    if (f) ((float*)out)[g] = r;
    else   ((u16*)out)[g] = f2bf(r);
}

// ---------------- launch ----------------------------------------------------------------
extern "C" void kernel_launch(void* const* d_in, const int* in_sizes, int n_in,
                              void* d_out, int out_size, void* d_ws, size_t ws_size,
                              hipStream_t stream) {
    const void* x    = d_in[0];
    const int* ei    = (const int*)d_in[1];
    const void* eattr = d_in[2];
    const int* batch = (const int*)d_in[3];
    const void* W1   = d_in[4];
    const void* as1  = d_in[5];
    const void* ad1  = d_in[6];
    const void* We1  = d_in[7];
    const void* ae1  = d_in[8];
    const void* b1   = d_in[9];
    const void* W2   = d_in[10];
    const void* as2  = d_in[11];
    const void* ad2  = d_in[12];
    const void* We2  = d_in[13];
    const void* ae2  = d_in[14];
    const void* b2   = d_in[15];
    const void* Wp   = d_in[16];
    const void* bp   = d_in[17];

    const int N = in_sizes[3];
    const int E = in_sizes[2];
    const int G = out_size;
    const int* src = ei;
    const int* dst = ei + E;

    char* p = (char*)d_ws;
    auto alloc = [&](size_t bytes) -> char* {
        char* r = p;
        p += (bytes + 255) & ~(size_t)255;
        return r;
    };
    int* flag    = (int*)alloc(32);
    float* consts = (float*)alloc(2048);
    int* roff    = (int*)alloc((size_t)(N + 1) * 4);
    int* rpos    = (int*)alloc((size_t)N * 4);
    int* bsum    = (int*)alloc(256 * 4);
    int2* edata  = (int2*)alloc((size_t)E * 8);
    float* pool  = (float*)alloc((size_t)(G * 64 + G) * 4);
    float* cnt   = pool + (size_t)G * 64;
    float* asrc1 = (float*)alloc((size_t)N * 4 * 4);
    float* adst1 = (float*)alloc((size_t)N * 4 * 4);
    float* asrc2 = asrc1;             // alias: dead after gat1
    float* adst2 = adst1;
    u16* agg1    = (u16*)alloc((size_t)N * 128 * 2);
    u16* h1      = (u16*)alloc((size_t)N * 128 * 2);
    u16* h2      = h1;                // alias: h1 dead after gat1
    u16* agg2    = h1 + (size_t)N * 64;
    // cached-path buffer (allocated last; only used if it fits)
    float* al    = (float*)alloc((size_t)E * 16);
    size_t full_need = (size_t)(p - (char*)d_ws);
    const bool cached = (ws_size >= full_need);

    hipMemsetAsync(rpos, 0, (size_t)N * 4, stream);
    hipMemsetAsync(pool, 0, (size_t)(G * 64 + G) * 4, stream);

    k_detect<<<1, 64, 0, stream>>>((const u32*)x, flag);
    k_consts<<<1, 256, 0, stream>>>(We1, ae1, We2, ae2, as1, ad1, as2, ad2, flag, consts);
    k_gemm5<128><<<512, 256, 0, stream>>>(x, W1, flag, -1, h1, N);
    k_coef1<<<(N * 2 + 255) / 256, 256, 0, stream>>>((const u32*)h1, consts, asrc1, adst1, N);

    int NB = (N + 255) / 256;
    k_count<<<(E + 255) / 256, 256, 0, stream>>>(dst, rpos, E, N);
    k_scan1<<<NB, 256, 0, stream>>>(rpos, roff + 1, bsum, N);
    k_scan2<<<1, 256, 0, stream>>>(bsum, NB);
    k_scan3<<<(N + 256) / 256, 256, 0, stream>>>(roff, bsum, rpos, N);
    k_scatter<<<(E + 255) / 256, 256, 0, stream>>>(dst, src, eattr, flag, rpos, edata, E, N);

    int gatBlocks = (N * 64 + 255) / 256;
    if (cached) {
        k_gat1c<<<gatBlocks, 256, 0, stream>>>((const u32*)h1, asrc1, adst1, edata, roff,
                                               flag, consts, b1, al, (u32*)agg1, N, E);
    } else {
        k_gat1f<<<gatBlocks, 256, 0, stream>>>((const u32*)h1, asrc1, adst1, edata, roff,
                                               flag, consts, b1, (u32*)agg1, N, E);
    }
    k_gemm5<64><<<512, 256, 0, stream>>>(agg1, W2, flag, 0, h2, N);
    k_coef2<<<(N + 255) / 256, 256, 0, stream>>>((const u32*)h2, consts, asrc2, adst2, N);
    if (cached) {
        k_gat2c<<<gatBlocks, 256, 0, stream>>>(h2, asrc2, adst2, edata, roff, flag,
                                               consts, b2, al, agg2, N, E);
    } else {
        k_gat2f<<<gatBlocks, 256, 0, stream>>>(h2, asrc2, adst2, edata, roff, flag,
                                               consts, b2, agg2, N, E);
    }
    k_pool<<<(((N + 7) / 8) * 64 + 255) / 256, 256, 0, stream>>>(agg2, batch, pool, cnt, N, G);
    k_head<<<1, 64, 0, stream>>>(pool, cnt, Wp, bp, flag, d_out, G);
}

// Round 8
// 431.033 us; speedup vs baseline: 4.5754x; 1.2184x over previous
//
#include <hip/hip_runtime.h>
#include <hip/hip_bf16.h>

typedef unsigned short u16;
typedef unsigned int u32;

__device__ __forceinline__ float bf2f(u16 u) { return __uint_as_float(((u32)u) << 16); }
__device__ __forceinline__ float bl(u32 u) { return __uint_as_float(u << 16); }
__device__ __forceinline__ float bh(u32 u) { return __uint_as_float(u & 0xffff0000u); }
__device__ __forceinline__ u16 f2bf(float f) {
    u32 u = __float_as_uint(f);
    u += 0x7fffu + ((u >> 16) & 1u);   // round-to-nearest-even
    return (u16)(u >> 16);
}
__device__ __forceinline__ float lrelu(float x) { return x > 0.f ? x : 0.2f * x; }
__device__ __forceinline__ int clampi(int v, int lo, int hi) {
    return v < lo ? lo : (v > hi ? hi : v);
}
__device__ __forceinline__ float load1(const void* base, int idx, int f32) {
    return f32 ? ((const float*)base)[idx] : bf2f(((const u16*)base)[idx]);
}

// ---------------- dtype detector ---------------------------------------------------------
__global__ void k_detect(const u32* __restrict__ xw, int* __restrict__ flag) {
    int lane = threadIdx.x & 63;
    int cnt = 0;
    #pragma unroll
    for (int j = 0; j < 4; j++) {
        u32 w = xw[lane * 4 + j];
        int e0 = (int)((w >> 7) & 0xffu);
        int e1 = (int)((w >> 23) & 0xffu);
        cnt += (e0 >= 0x60 && e0 <= 0x8f);
        cnt += (e1 >= 0x60 && e1 <= 0x8f);
    }
    #pragma unroll
    for (int off = 32; off > 0; off >>= 1) cnt += __shfl_xor(cnt, off);
    if (lane == 0) *flag = (cnt < 480) ? 1 : 0;
}

// ---------------- constants + fp32 expansion of attention vectors -----------------------
// consts layout (floats): [0..3]=C1 per head, [4]=C2, [8..135]=as1f, [136..263]=ad1f,
// [264..327]=as2f, [328..391]=ad2f
__global__ void k_consts(const void* We1, const void* ae1, const void* We2, const void* ae2,
                         const void* as1, const void* ad1, const void* as2, const void* ad2,
                         const int* __restrict__ flag, float* __restrict__ consts) {
    int f = *flag;
    int t = threadIdx.x;
    if (t < 4) {
        float s = 0.f;
        for (int c = 0; c < 32; c++) s += load1(We1, t * 32 + c, f) * load1(ae1, t * 32 + c, f);
        consts[t] = s;
    } else if (t == 4) {
        float s = 0.f;
        for (int c = 0; c < 64; c++) s += load1(We2, c, f) * load1(ae2, c, f);
        consts[4] = s;
    }
    if (t < 128) {
        consts[8 + t] = load1(as1, t, f);
        consts[136 + t] = load1(ad1, t, f);
    }
    if (t < 64) {
        consts[264 + t] = load1(as2, t, f);
        consts[328 + t] = load1(ad2, t, f);
    }
}

// ---------------- GEMM: Y[nrows,NC] = X[nrows,128] @ W[128,NC] --------------------------
// NC==128: output PAIRED layout (u32 word = (ch c | ch c+64<<16) at word row*64+c).
// NC==64:  X (agg1) is PAIRED -> W rows permuted during staging; natural u16 output.
template <int NC>
__global__ __launch_bounds__(256, 4) void k_gemm5(
    const void* __restrict__ X, const void* __restrict__ Wg,
    const int* __restrict__ flag, int fXovr, u16* __restrict__ Y, int nrows) {
    constexpr int K = 128;
    constexpr int ROWS = 32;
    __shared__ float Ws[K * NC];
    __shared__ float Xs[ROWS * K];

    const int f = *flag;
    const bool fX = (fXovr < 0) ? (f != 0) : (fXovr != 0);
    const bool fW = (f != 0);
    const int tid = threadIdx.x, wid = tid >> 6, lane = tid & 63;

    for (int i = tid * 4; i < K * NC; i += 256 * 4) {
        int j = i / NC;
        int col = i & (NC - 1);
        int srow = (NC == 64) ? ((j & 1) * 64 + (j >> 1)) : j;
        int g = srow * NC + col;
        if (fW) {
            float4 v = *(const float4*)((const float*)Wg + g);
            Ws[i] = v.x; Ws[i + 1] = v.y; Ws[i + 2] = v.z; Ws[i + 3] = v.w;
        } else {
            ushort4 r = *(const ushort4*)((const u16*)Wg + g);
            Ws[i] = bf2f(r.x); Ws[i + 1] = bf2f(r.y);
            Ws[i + 2] = bf2f(r.z); Ws[i + 3] = bf2f(r.w);
        }
    }

    const int sr = tid >> 3;           // staging row 0..31
    const int sc = (tid & 7) * 16;     // staging col 0,16,..112

    for (int base = blockIdx.x * ROWS; base < nrows; base += gridDim.x * ROWS) {
        __syncthreads();
        {
            int row = base + sr;
            float* xs = &Xs[sr * K + sc];
            if (row < nrows) {
                if (fX) {
                    const float* xp = (const float*)X + (size_t)row * K + sc;
                    float4 a = *(const float4*)xp;
                    float4 b = *(const float4*)(xp + 4);
                    float4 c = *(const float4*)(xp + 8);
                    float4 d = *(const float4*)(xp + 12);
                    xs[0] = a.x; xs[1] = a.y; xs[2] = a.z; xs[3] = a.w;
                    xs[4] = b.x; xs[5] = b.y; xs[6] = b.z; xs[7] = b.w;
                    xs[8] = c.x; xs[9] = c.y; xs[10] = c.z; xs[11] = c.w;
                    xs[12] = d.x; xs[13] = d.y; xs[14] = d.z; xs[15] = d.w;
                } else {
                    const u16* xp = (const u16*)X + (size_t)row * K + sc;
                    uint4 a = *(const uint4*)xp;
                    uint4 b = *(const uint4*)(xp + 8);
                    xs[0] = bl(a.x); xs[1] = bh(a.x); xs[2] = bl(a.y); xs[3] = bh(a.y);
                    xs[4] = bl(a.z); xs[5] = bh(a.z); xs[6] = bl(a.w); xs[7] = bh(a.w);
                    xs[8] = bl(b.x); xs[9] = bh(b.x); xs[10] = bl(b.y); xs[11] = bh(b.y);
                    xs[12] = bl(b.z); xs[13] = bh(b.z); xs[14] = bl(b.w); xs[15] = bh(b.w);
                }
            } else {
                #pragma unroll
                for (int j = 0; j < 16; j++) xs[j] = 0.f;
            }
        }
        __syncthreads();

        float acc0[8] = {0.f, 0.f, 0.f, 0.f, 0.f, 0.f, 0.f, 0.f};
        float acc1[8] = {0.f, 0.f, 0.f, 0.f, 0.f, 0.f, 0.f, 0.f};
        #pragma unroll 2
        for (int k = 0; k < K; k += 4) {
            float wa0 = Ws[(k + 0) * NC + lane];
            float wa1 = Ws[(k + 1) * NC + lane];
            float wa2 = Ws[(k + 2) * NC + lane];
            float wa3 = Ws[(k + 3) * NC + lane];
            float wb0 = 0.f, wb1 = 0.f, wb2 = 0.f, wb3 = 0.f;
            if constexpr (NC == 128) {
                wb0 = Ws[(k + 0) * NC + lane + 64];
                wb1 = Ws[(k + 1) * NC + lane + 64];
                wb2 = Ws[(k + 2) * NC + lane + 64];
                wb3 = Ws[(k + 3) * NC + lane + 64];
            }
            #pragma unroll
            for (int rr = 0; rr < 8; rr++) {
                float4 xv = *(const float4*)&Xs[(wid * 8 + rr) * K + k];
                acc0[rr] += xv.x * wa0 + xv.y * wa1 + xv.z * wa2 + xv.w * wa3;
                if constexpr (NC == 128)
                    acc1[rr] += xv.x * wb0 + xv.y * wb1 + xv.z * wb2 + xv.w * wb3;
            }
        }

        #pragma unroll
        for (int rr = 0; rr < 8; rr++) {
            int row = base + wid * 8 + rr;
            if (row < nrows) {
                if constexpr (NC == 128) {
                    u32 w = (u32)f2bf(acc0[rr]) | ((u32)f2bf(acc1[rr]) << 16);
                    ((u32*)Y)[(size_t)row * 64 + lane] = w;
                } else {
                    Y[(size_t)row * 64 + lane] = f2bf(acc0[rr]);
                }
            }
        }
    }
}

// ---------------- coef1: paired h1 -> asrc1/adst1 [N][4] --------------------------------
__global__ void k_coef1(const u32* __restrict__ hp, const float* __restrict__ consts,
                        float* __restrict__ asrc, float* __restrict__ adst, int n) {
    int i = blockIdx.x * 256 + threadIdx.x;
    if (i >= n * 2) return;
    int node = i >> 1, g = i & 1;
    const u32* w = hp + (size_t)node * 64 + g * 32;
    const float* asA = consts + 8 + g * 32;
    const float* adA = consts + 136 + g * 32;
    const float* asB = consts + 8 + (g + 2) * 32;
    const float* adB = consts + 136 + (g + 2) * 32;
    float sA1 = 0.f, sA2 = 0.f, sB1 = 0.f, sB2 = 0.f;
    #pragma unroll
    for (int c = 0; c < 32; c += 4) {
        uint4 q = *(const uint4*)&w[c];
        float l0 = bl(q.x), h0 = bh(q.x), l1 = bl(q.y), h1 = bh(q.y);
        float l2 = bl(q.z), h2 = bh(q.z), l3 = bl(q.w), h3 = bh(q.w);
        sA1 += l0 * asA[c] + l1 * asA[c + 1] + l2 * asA[c + 2] + l3 * asA[c + 3];
        sA2 += l0 * adA[c] + l1 * adA[c + 1] + l2 * adA[c + 2] + l3 * adA[c + 3];
        sB1 += h0 * asB[c] + h1 * asB[c + 1] + h2 * asB[c + 2] + h3 * asB[c + 3];
        sB2 += h0 * adB[c] + h1 * adB[c + 1] + h2 * adB[c + 2] + h3 * adB[c + 3];
    }
    asrc[node * 4 + g] = sA1;     adst[node * 4 + g] = sA2;
    asrc[node * 4 + g + 2] = sB1; adst[node * 4 + g + 2] = sB2;
}

// ---------------- coef2: natural h2 -> asrc2/adst2 [N] ----------------------------------
__global__ void k_coef2(const u32* __restrict__ hp, const float* __restrict__ consts,
                        float* __restrict__ asrc, float* __restrict__ adst, int n) {
    int i = blockIdx.x * 256 + threadIdx.x;
    if (i >= n) return;
    const u32* w = hp + (size_t)i * 32;
    const float* as_ = consts + 264;
    const float* ad_ = consts + 328;
    float s1 = 0.f, s2 = 0.f;
    #pragma unroll
    for (int c = 0; c < 32; c += 4) {
        uint4 q = *(const uint4*)&w[c];
        float l0 = bl(q.x), h0 = bh(q.x), l1 = bl(q.y), h1 = bh(q.y);
        float l2 = bl(q.z), h2 = bh(q.z), l3 = bl(q.w), h3 = bh(q.w);
        s1 += l0 * as_[2*c] + h0 * as_[2*c+1] + l1 * as_[2*c+2] + h1 * as_[2*c+3]
            + l2 * as_[2*c+4] + h2 * as_[2*c+5] + l3 * as_[2*c+6] + h3 * as_[2*c+7];
        s2 += l0 * ad_[2*c] + h0 * ad_[2*c+1] + l1 * ad_[2*c+2] + h1 * ad_[2*c+3]
            + l2 * ad_[2*c+4] + h2 * ad_[2*c+5] + l3 * ad_[2*c+6] + h3 * ad_[2*c+7];
    }
    asrc[i] = s1; adst[i] = s2;
}

// ---------------- CSR build -------------------------------------------------------------
__global__ void k_count(const int* __restrict__ dst, int* __restrict__ cnt, int E, int n) {
    int e = blockIdx.x * 256 + threadIdx.x;
    if (e < E) atomicAdd(&cnt[clampi(dst[e], 0, n - 1)], 1);
}
__global__ void k_scan1(const int* __restrict__ cnt, int* __restrict__ part,
                        int* __restrict__ bsum, int n) {
    __shared__ int buf[256];
    int i = blockIdx.x * 256 + threadIdx.x;
    int v = (i < n) ? cnt[i] : 0;
    buf[threadIdx.x] = v;
    __syncthreads();
    for (int off = 1; off < 256; off <<= 1) {
        int t = (threadIdx.x >= off) ? buf[threadIdx.x - off] : 0;
        __syncthreads();
        buf[threadIdx.x] += t;
        __syncthreads();
    }
    if (i < n) part[i] = buf[threadIdx.x];
    if (threadIdx.x == 255) bsum[blockIdx.x] = buf[255];
}
__global__ void k_scan2(int* __restrict__ bsum, int nb) {
    __shared__ int buf[256];
    int t = threadIdx.x;
    int v = (t < nb) ? bsum[t] : 0;
    buf[t] = v;
    __syncthreads();
    for (int off = 1; off < 256; off <<= 1) {
        int tt = (t >= off) ? buf[t - off] : 0;
        __syncthreads();
        buf[t] += tt;
        __syncthreads();
    }
    if (t < nb) bsum[t] = buf[t] - v;   // exclusive
}
// finalize roff AND seed rpos with the same value
__global__ void k_scan3(int* __restrict__ roff, const int* __restrict__ bsum,
                        int* __restrict__ rpos, int n) {
    int i = blockIdx.x * 256 + threadIdx.x;
    if (i > n) return;
    int v;
    if (i == 0) { v = 0; roff[0] = 0; }
    else { v = roff[i] + bsum[(i - 1) >> 8]; roff[i] = v; }
    if (i < n) rpos[i] = v;
}
// payload scatter: edata[p] = {src, ea}
__global__ void k_scatter(const int* __restrict__ dst, const int* __restrict__ src,
                          const void* eattr, const int* __restrict__ flag,
                          int* __restrict__ rpos, int2* __restrict__ edata, int E, int n) {
    int f = *flag;
    int e = blockIdx.x * 256 + threadIdx.x;
    if (e < E) {
        int d = clampi(dst[e], 0, n - 1);
        int s = clampi(src[e], 0, n - 1);
        float ea = load1(eattr, e, f);
        int p = atomicAdd(&rpos[d], 1);
        if (p >= 0 && p < E) {
            int2 v; v.x = s; v.y = __float_as_int(ea);
            edata[p] = v;
        }
    }
}

// ---------------- gat1, CACHED: fused passes for deg<=64, LDS weights, 4x MLP -----------
__global__ __launch_bounds__(256) void k_gat1c(
    const u32* __restrict__ hp, const float* __restrict__ asrc, const float* __restrict__ adst,
    const int2* __restrict__ edata, const int* __restrict__ roff,
    const int* __restrict__ flag, const float* __restrict__ consts, const void* bias,
    float* __restrict__ al, u32* __restrict__ out, int n, int E) {
    __shared__ float4 wls[4][64];
    int f = *flag;
    int gtid = blockIdx.x * 256 + threadIdx.x;
    int wv = gtid >> 6, lane = gtid & 63;
    int wid = (threadIdx.x >> 6);
    int nw = (gridDim.x * 256) >> 6;
    const float c0 = consts[0], c1 = consts[1], c2 = consts[2], c3 = consts[3];
    const int hsel = lane >> 5;
    const float biasA = load1(bias, lane, f);
    const float biasB = load1(bias, 64 + lane, f);

    for (int d = wv; d < n; d += nw) {
        int s0 = clampi(roff[d], 0, E);
        int s1 = clampi(roff[d + 1], s0, E);
        int deg = s1 - s0;
        float4 adv = *(const float4*)&adst[d * 4];
        float accA = 0.f, accB = 0.f;

        if (deg <= 64) {
            // fused: alpha/exp in registers, weights to LDS, no global al traffic
            bool v = lane < deg;
            int s = 0; float ea = 0.f;
            float a0 = -1e30f, a1 = -1e30f, a2 = -1e30f, a3 = -1e30f;
            if (v) {
                int2 ed = edata[s0 + lane];
                s = ed.x; ea = __int_as_float(ed.y);
                float4 av = *(const float4*)&asrc[(size_t)s * 4];
                a0 = lrelu(av.x + adv.x + ea * c0);
                a1 = lrelu(av.y + adv.y + ea * c1);
                a2 = lrelu(av.z + adv.z + ea * c2);
                a3 = lrelu(av.w + adv.w + ea * c3);
            }
            float m0 = a0, m1 = a1, m2 = a2, m3 = a3;
            #pragma unroll
            for (int off = 32; off > 0; off >>= 1) {
                m0 = fmaxf(m0, __shfl_xor(m0, off));
                m1 = fmaxf(m1, __shfl_xor(m1, off));
                m2 = fmaxf(m2, __shfl_xor(m2, off));
                m3 = fmaxf(m3, __shfl_xor(m3, off));
            }
            float e0 = v ? expf(a0 - m0) : 0.f;
            float e1 = v ? expf(a1 - m1) : 0.f;
            float e2 = v ? expf(a2 - m2) : 0.f;
            float e3 = v ? expf(a3 - m3) : 0.f;
            float d0 = e0, d1 = e1, d2 = e2, d3 = e3;
            #pragma unroll
            for (int off = 32; off > 0; off >>= 1) {
                d0 += __shfl_xor(d0, off); d1 += __shfl_xor(d1, off);
                d2 += __shfl_xor(d2, off); d3 += __shfl_xor(d3, off);
            }
            float i0 = 1.f / (d0 + 1e-16f), i1 = 1.f / (d1 + 1e-16f);
            float i2 = 1.f / (d2 + 1e-16f), i3 = 1.f / (d3 + 1e-16f);
            if (v) wls[wid][lane] = make_float4(e0 * i0, e1 * i1, e2 * i2, e3 * i3);

            int j = 0;
            for (; j + 4 <= deg; j += 4) {
                int sa = __shfl(s, j), sb = __shfl(s, j + 1);
                int sc_ = __shfl(s, j + 2), sd = __shfl(s, j + 3);
                u32 ha = hp[(size_t)sa * 64 + lane];
                u32 hb = hp[(size_t)sb * 64 + lane];
                u32 hc = hp[(size_t)sc_ * 64 + lane];
                u32 hd = hp[(size_t)sd * 64 + lane];
                float4 wa = wls[wid][j], wb = wls[wid][j + 1];
                float4 wc = wls[wid][j + 2], wd = wls[wid][j + 3];
                accA += (hsel ? wa.y : wa.x) * bl(ha); accB += (hsel ? wa.w : wa.z) * bh(ha);
                accA += (hsel ? wb.y : wb.x) * bl(hb); accB += (hsel ? wb.w : wb.z) * bh(hb);
                accA += (hsel ? wc.y : wc.x) * bl(hc); accB += (hsel ? wc.w : wc.z) * bh(hc);
                accA += (hsel ? wd.y : wd.x) * bl(hd); accB += (hsel ? wd.w : wd.z) * bh(hd);
            }
            for (; j < deg; j++) {
                int sj = __shfl(s, j);
                u32 hw = hp[(size_t)sj * 64 + lane];
                float4 w = wls[wid][j];
                accA += (hsel ? w.y : w.x) * bl(hw);
                accB += (hsel ? w.w : w.z) * bh(hw);
            }
        } else {
            // general path (rare): 3 passes through global al
            float m0 = -1e30f, m1 = -1e30f, m2 = -1e30f, m3 = -1e30f;
            for (int idx = s0 + lane; idx < s1; idx += 64) {
                int2 ed = edata[idx];
                int s = ed.x;
                float ea = __int_as_float(ed.y);
                float4 av = *(const float4*)&asrc[(size_t)s * 4];
                float a0 = lrelu(av.x + adv.x + ea * c0);
                float a1 = lrelu(av.y + adv.y + ea * c1);
                float a2 = lrelu(av.z + adv.z + ea * c2);
                float a3 = lrelu(av.w + adv.w + ea * c3);
                *(float4*)&al[(size_t)idx * 4] = make_float4(a0, a1, a2, a3);
                m0 = fmaxf(m0, a0); m1 = fmaxf(m1, a1);
                m2 = fmaxf(m2, a2); m3 = fmaxf(m3, a3);
            }
            #pragma unroll
            for (int off = 32; off > 0; off >>= 1) {
                m0 = fmaxf(m0, __shfl_xor(m0, off));
                m1 = fmaxf(m1, __shfl_xor(m1, off));
                m2 = fmaxf(m2, __shfl_xor(m2, off));
                m3 = fmaxf(m3, __shfl_xor(m3, off));
            }
            float d0 = 0.f, d1 = 0.f, d2 = 0.f, d3 = 0.f;
            for (int idx = s0 + lane; idx < s1; idx += 64) {
                float4 a = *(const float4*)&al[(size_t)idx * 4];
                float e0 = expf(a.x - m0), e1 = expf(a.y - m1);
                float e2 = expf(a.z - m2), e3 = expf(a.w - m3);
                d0 += e0; d1 += e1; d2 += e2; d3 += e3;
                *(float4*)&al[(size_t)idx * 4] = make_float4(e0, e1, e2, e3);
            }
            #pragma unroll
            for (int off = 32; off > 0; off >>= 1) {
                d0 += __shfl_xor(d0, off); d1 += __shfl_xor(d1, off);
                d2 += __shfl_xor(d2, off); d3 += __shfl_xor(d3, off);
            }
            float i0 = 1.f / (d0 + 1e-16f), i1 = 1.f / (d1 + 1e-16f);
            float i2 = 1.f / (d2 + 1e-16f), i3 = 1.f / (d3 + 1e-16f);
            float iA = hsel ? i1 : i0, iB = hsel ? i3 : i2;
            for (int idx = s0; idx < s1; idx++) {
                int s = edata[idx].x;
                float4 ex = *(const float4*)&al[(size_t)idx * 4];
                float wA = (hsel ? ex.y : ex.x) * iA;
                float wB = (hsel ? ex.w : ex.z) * iB;
                u32 hw = hp[(size_t)s * 64 + lane];
                accA += wA * bl(hw);
                accB += wB * bh(hw);
            }
        }
        float rA = fmaxf(accA + biasA, 0.f);   // fused ReLU
        float rB = fmaxf(accB + biasB, 0.f);
        out[(size_t)d * 64 + lane] = (u32)f2bf(rA) | ((u32)f2bf(rB) << 16);
    }
}

// ---------------- gat2, CACHED: fused passes for deg<=64, LDS weights, 4x MLP -----------
__global__ __launch_bounds__(256) void k_gat2c(
    const u16* __restrict__ h, const float* __restrict__ asrc, const float* __restrict__ adst,
    const int2* __restrict__ edata, const int* __restrict__ roff,
    const int* __restrict__ flag, const float* __restrict__ consts, const void* bias,
    float* __restrict__ al, u16* __restrict__ out, int n, int E) {
    __shared__ float wls[4][64];
    int f = *flag;
    int gtid = blockIdx.x * 256 + threadIdx.x;
    int wv = gtid >> 6, lane = gtid & 63;
    int wid = (threadIdx.x >> 6);
    int nw = (gridDim.x * 256) >> 6;
    const float C = consts[4];
    const float biasL = load1(bias, lane, f);

    for (int d = wv; d < n; d += nw) {
        int s0 = clampi(roff[d], 0, E);
        int s1 = clampi(roff[d + 1], s0, E);
        int deg = s1 - s0;
        float ad = adst[d];
        float acc = 0.f;

        if (deg <= 64) {
            bool v = lane < deg;
            int s = 0;
            float a = -1e30f;
            if (v) {
                int2 ed = edata[s0 + lane];
                s = ed.x;
                a = lrelu(asrc[s] + ad + __int_as_float(ed.y) * C);
            }
            float m = a;
            #pragma unroll
            for (int off = 32; off > 0; off >>= 1) m = fmaxf(m, __shfl_xor(m, off));
            float e = v ? expf(a - m) : 0.f;
            float den = e;
            #pragma unroll
            for (int off = 32; off > 0; off >>= 1) den += __shfl_xor(den, off);
            float inv = 1.f / (den + 1e-16f);
            if (v) wls[wid][lane] = e * inv;

            int j = 0;
            for (; j + 4 <= deg; j += 4) {
                int sa = __shfl(s, j), sb = __shfl(s, j + 1);
                int sc_ = __shfl(s, j + 2), sd = __shfl(s, j + 3);
                float ha = bf2f(h[(size_t)sa * 64 + lane]);
                float hb = bf2f(h[(size_t)sb * 64 + lane]);
                float hc = bf2f(h[(size_t)sc_ * 64 + lane]);
                float hd = bf2f(h[(size_t)sd * 64 + lane]);
                acc += wls[wid][j] * ha + wls[wid][j + 1] * hb
                     + wls[wid][j + 2] * hc + wls[wid][j + 3] * hd;
            }
            for (; j < deg; j++) {
                int sj = __shfl(s, j);
                acc += wls[wid][j] * bf2f(h[(size_t)sj * 64 + lane]);
            }
        } else {
            float m = -1e30f;
            for (int idx = s0 + lane; idx < s1; idx += 64) {
                int2 ed = edata[idx];
                float a = lrelu(asrc[ed.x] + ad + __int_as_float(ed.y) * C);
                al[idx] = a;
                m = fmaxf(m, a);
            }
            #pragma unroll
            for (int off = 32; off > 0; off >>= 1) m = fmaxf(m, __shfl_xor(m, off));
            float den = 0.f;
            for (int idx = s0 + lane; idx < s1; idx += 64) {
                float e = expf(al[idx] - m);
                den += e;
                al[idx] = e;
            }
            #pragma unroll
            for (int off = 32; off > 0; off >>= 1) den += __shfl_xor(den, off);
            float inv = 1.f / (den + 1e-16f);
            for (int idx = s0; idx < s1; idx++) {
                int s = edata[idx].x;
                acc += al[idx] * inv * bf2f(h[(size_t)s * 64 + lane]);
            }
        }
        out[(size_t)d * 64 + lane] = f2bf(acc + biasL);
    }
}

// ---------------- gat1/gat2 FALLBACK (recompute, no al cache) ---------------------------
__global__ __launch_bounds__(256) void k_gat1f(
    const u32* __restrict__ hp, const float* __restrict__ asrc, const float* __restrict__ adst,
    const int2* __restrict__ edata, const int* __restrict__ roff,
    const int* __restrict__ flag, const float* __restrict__ consts, const void* bias,
    u32* __restrict__ out, int n, int E) {
    int f = *flag;
    int gtid = blockIdx.x * 256 + threadIdx.x;
    int wv = gtid >> 6, lane = gtid & 63;
    int nw = (gridDim.x * 256) >> 6;
    const float c0 = consts[0], c1 = consts[1], c2 = consts[2], c3 = consts[3];
    const int hsel = lane >> 5;
    const float biasA = load1(bias, lane, f);
    const float biasB = load1(bias, 64 + lane, f);

    for (int d = wv; d < n; d += nw) {
        int s0 = clampi(roff[d], 0, E);
        int s1 = clampi(roff[d + 1], s0, E);
        float4 adv = *(const float4*)&adst[d * 4];
        float m0 = -1e30f, m1 = -1e30f, m2 = -1e30f, m3 = -1e30f;
        for (int idx = s0 + lane; idx < s1; idx += 64) {
            int2 ed = edata[idx];
            float ea = __int_as_float(ed.y);
            float4 av = *(const float4*)&asrc[(size_t)ed.x * 4];
            m0 = fmaxf(m0, lrelu(av.x + adv.x + ea * c0));
            m1 = fmaxf(m1, lrelu(av.y + adv.y + ea * c1));
            m2 = fmaxf(m2, lrelu(av.z + adv.z + ea * c2));
            m3 = fmaxf(m3, lrelu(av.w + adv.w + ea * c3));
        }
        #pragma unroll
        for (int off = 32; off > 0; off >>= 1) {
            m0 = fmaxf(m0, __shfl_xor(m0, off));
            m1 = fmaxf(m1, __shfl_xor(m1, off));
            m2 = fmaxf(m2, __shfl_xor(m2, off));
            m3 = fmaxf(m3, __shfl_xor(m3, off));
        }
        float d0 = 0.f, d1 = 0.f, d2 = 0.f, d3 = 0.f;
        for (int idx = s0 + lane; idx < s1; idx += 64) {
            int2 ed = edata[idx];
            float ea = __int_as_float(ed.y);
            float4 av = *(const float4*)&asrc[(size_t)ed.x * 4];
            d0 += expf(lrelu(av.x + adv.x + ea * c0) - m0);
            d1 += expf(lrelu(av.y + adv.y + ea * c1) - m1);
            d2 += expf(lrelu(av.z + adv.z + ea * c2) - m2);
            d3 += expf(lrelu(av.w + adv.w + ea * c3) - m3);
        }
        #pragma unroll
        for (int off = 32; off > 0; off >>= 1) {
            d0 += __shfl_xor(d0, off); d1 += __shfl_xor(d1, off);
            d2 += __shfl_xor(d2, off); d3 += __shfl_xor(d3, off);
        }
        float i0 = 1.f / (d0 + 1e-16f), i1 = 1.f / (d1 + 1e-16f);
        float i2 = 1.f / (d2 + 1e-16f), i3 = 1.f / (d3 + 1e-16f);
        float mA = hsel ? m1 : m0, mB = hsel ? m3 : m2;
        float iA = hsel ? i1 : i0, iB = hsel ? i3 : i2;
        float cA = hsel ? c1 : c0, cB = hsel ? c3 : c2;
        float aA = hsel ? adv.y : adv.x, aB = hsel ? adv.w : adv.z;

        float accA = 0.f, accB = 0.f;
        for (int idx = s0; idx < s1; idx++) {
            int2 ed = edata[idx];
            float ea = __int_as_float(ed.y);
            float4 av = *(const float4*)&asrc[(size_t)ed.x * 4];
            float alA = lrelu((hsel ? av.y : av.x) + aA + ea * cA);
            float alB = lrelu((hsel ? av.w : av.z) + aB + ea * cB);
            float wA = expf(alA - mA) * iA;
            float wB = expf(alB - mB) * iB;
            u32 hw = hp[(size_t)ed.x * 64 + lane];
            accA += wA * bl(hw);
            accB += wB * bh(hw);
        }
        float rA = fmaxf(accA + biasA, 0.f);
        float rB = fmaxf(accB + biasB, 0.f);
        out[(size_t)d * 64 + lane] = (u32)f2bf(rA) | ((u32)f2bf(rB) << 16);
    }
}

__global__ __launch_bounds__(256) void k_gat2f(
    const u16* __restrict__ h, const float* __restrict__ asrc, const float* __restrict__ adst,
    const int2* __restrict__ edata, const int* __restrict__ roff,
    const int* __restrict__ flag, const float* __restrict__ consts, const void* bias,
    u16* __restrict__ out, int n, int E) {
    int f = *flag;
    int gtid = blockIdx.x * 256 + threadIdx.x;
    int wv = gtid >> 6, lane = gtid & 63;
    int nw = (gridDim.x * 256) >> 6;
    const float C = consts[4];
    const float biasL = load1(bias, lane, f);

    for (int d = wv; d < n; d += nw) {
        int s0 = clampi(roff[d], 0, E);
        int s1 = clampi(roff[d + 1], s0, E);
        float ad = adst[d];
        float m = -1e30f;
        for (int idx = s0 + lane; idx < s1; idx += 64) {
            int2 ed = edata[idx];
            m = fmaxf(m, lrelu(asrc[ed.x] + ad + __int_as_float(ed.y) * C));
        }
        #pragma unroll
        for (int off = 32; off > 0; off >>= 1) m = fmaxf(m, __shfl_xor(m, off));
        float den = 0.f;
        for (int idx = s0 + lane; idx < s1; idx += 64) {
            int2 ed = edata[idx];
            den += expf(lrelu(asrc[ed.x] + ad + __int_as_float(ed.y) * C) - m);
        }
        #pragma unroll
        for (int off = 32; off > 0; off >>= 1) den += __shfl_xor(den, off);
        float inv = 1.f / (den + 1e-16f);

        float acc = 0.f;
        for (int idx = s0; idx < s1; idx++) {
            int2 ed = edata[idx];
            float a = lrelu(asrc[ed.x] + ad + __int_as_float(ed.y) * C);
            acc += expf(a - m) * inv * bf2f(h[(size_t)ed.x * 64 + lane]);
        }
        out[(size_t)d * 64 + lane] = f2bf(acc + biasL);
    }
}

// ---------------- pooling ---------------------------------------------------------------
__global__ void k_pool(const u16* __restrict__ agg2, const int* __restrict__ batch,
                       float* __restrict__ pool, float* __restrict__ cnt, int n, int G) {
    int t = blockIdx.x * 256 + threadIdx.x;
    int nb8 = (n + 7) / 8;
    if (t >= nb8 * 64) return;
    int base = (t >> 6) * 8;
    int c = t & 63;
    int end = min(base + 8, n);
    float acc = 0.f, cacc = 0.f;
    int curg = clampi(batch[base], 0, G - 1);
    for (int j = base; j < end; j++) {
        int g = clampi(batch[j], 0, G - 1);
        if (g != curg) {
            atomicAdd(&pool[curg * 64 + c], acc);
            if (c == 0) atomicAdd(&cnt[curg], cacc);
            acc = 0.f; cacc = 0.f; curg = g;
        }
        acc += bf2f(agg2[(size_t)j * 64 + c]);
        cacc += 1.f;
    }
    atomicAdd(&pool[curg * 64 + c], acc);
    if (c == 0) atomicAdd(&cnt[curg], cacc);
}

__global__ void k_head(const float* __restrict__ pool, const float* __restrict__ cnt,
                       const void* Wp, const void* bp, const int* __restrict__ flag,
                       void* out, int G) {
    int f = *flag;
    int g = threadIdx.x;
    if (g >= G) return;
    float s = 0.f;
    for (int c = 0; c < 64; c++) s += pool[g * 64 + c] * load1(Wp, c, f);
    float cv = cnt[g];
    if (!(cv > 0.f)) cv = 1.f;
    float r = s / cv + load1(bp, 0, f);
    if (f) ((float*)out)[g] = r;
    else   ((u16*)out)[g] = f2bf(r);
}

// ---------------- launch ----------------------------------------------------------------
extern "C" void kernel_launch(void* const* d_in, const int* in_sizes, int n_in,
                              void* d_out, int out_size, void* d_ws, size_t ws_size,
                              hipStream_t stream) {
    const void* x    = d_in[0];
    const int* ei    = (const int*)d_in[1];
    const void* eattr = d_in[2];
    const int* batch = (const int*)d_in[3];
    const void* W1   = d_in[4];
    const void* as1  = d_in[5];
    const void* ad1  = d_in[6];
    const void* We1  = d_in[7];
    const void* ae1  = d_in[8];
    const void* b1   = d_in[9];
    const void* W2   = d_in[10];
    const void* as2  = d_in[11];
    const void* ad2  = d_in[12];
    const void* We2  = d_in[13];
    const void* ae2  = d_in[14];
    const void* b2   = d_in[15];
    const void* Wp   = d_in[16];
    const void* bp   = d_in[17];

    const int N = in_sizes[3];
    const int E = in_sizes[2];
    const int G = out_size;
    const int* src = ei;
    const int* dst = ei + E;

    char* p = (char*)d_ws;
    auto alloc = [&](size_t bytes) -> char* {
        char* r = p;
        p += (bytes + 255) & ~(size_t)255;
        return r;
    };
    int* flag    = (int*)alloc(32);
    float* consts = (float*)alloc(2048);
    int* roff    = (int*)alloc((size_t)(N + 1) * 4);
    int* rpos    = (int*)alloc((size_t)N * 4);
    int* bsum    = (int*)alloc(256 * 4);
    int2* edata  = (int2*)alloc((size_t)E * 8);
    float* pool  = (float*)alloc((size_t)(G * 64 + G) * 4);
    float* cnt   = pool + (size_t)G * 64;
    float* asrc1 = (float*)alloc((size_t)N * 4 * 4);
    float* adst1 = (float*)alloc((size_t)N * 4 * 4);
    float* asrc2 = asrc1;             // alias: dead after gat1
    float* adst2 = adst1;
    u16* agg1    = (u16*)alloc((size_t)N * 128 * 2);
    u16* h1      = (u16*)alloc((size_t)N * 128 * 2);
    u16* h2      = h1;                // alias: h1 dead after gat1
    u16* agg2    = h1 + (size_t)N * 64;
    // cached-path buffer (used only for deg>64 dsts)
    float* al    = (float*)alloc((size_t)E * 16);
    size_t full_need = (size_t)(p - (char*)d_ws);
    const bool cached = (ws_size >= full_need);

    hipMemsetAsync(rpos, 0, (size_t)N * 4, stream);
    hipMemsetAsync(pool, 0, (size_t)(G * 64 + G) * 4, stream);

    k_detect<<<1, 64, 0, stream>>>((const u32*)x, flag);
    k_consts<<<1, 256, 0, stream>>>(We1, ae1, We2, ae2, as1, ad1, as2, ad2, flag, consts);
    k_gemm5<128><<<512, 256, 0, stream>>>(x, W1, flag, -1, h1, N);
    k_coef1<<<(N * 2 + 255) / 256, 256, 0, stream>>>((const u32*)h1, consts, asrc1, adst1, N);

    int NB = (N + 255) / 256;
    k_count<<<(E + 255) / 256, 256, 0, stream>>>(dst, rpos, E, N);
    k_scan1<<<NB, 256, 0, stream>>>(rpos, roff + 1, bsum, N);
    k_scan2<<<1, 256, 0, stream>>>(bsum, NB);
    k_scan3<<<(N + 256) / 256, 256, 0, stream>>>(roff, bsum, rpos, N);
    k_scatter<<<(E + 255) / 256, 256, 0, stream>>>(dst, src, eattr, flag, rpos, edata, E, N);

    int gatBlocks = (N * 64 + 255) / 256;
    if (cached) {
        k_gat1c<<<gatBlocks, 256, 0, stream>>>((const u32*)h1, asrc1, adst1, edata, roff,
                                               flag, consts, b1, al, (u32*)agg1, N, E);
    } else {
        k_gat1f<<<gatBlocks, 256, 0, stream>>>((const u32*)h1, asrc1, adst1, edata, roff,
                                               flag, consts, b1, (u32*)agg1, N, E);
    }
    k_gemm5<64><<<512, 256, 0, stream>>>(agg1, W2, flag, 0, h2, N);
    k_coef2<<<(N + 255) / 256, 256, 0, stream>>>((const u32*)h2, consts, asrc2, adst2, N);
    if (cached) {
        k_gat2c<<<gatBlocks, 256, 0, stream>>>(h2, asrc2, adst2, edata, roff, flag,
                                               consts, b2, al, agg2, N, E);
    } else {
        k_gat2f<<<gatBlocks, 256, 0, stream>>>(h2, asrc2, adst2, edata, roff, flag,
                                               consts, b2, agg2, N, E);
    }
    k_pool<<<(((N + 7) / 8) * 64 + 255) / 256, 256, 0, stream>>>(agg2, batch, pool, cnt, N, G);
    k_head<<<1, 64, 0, stream>>>(pool, cnt, Wp, bp, flag, d_out, G);
}

// Round 10
// 427.470 us; speedup vs baseline: 4.6136x; 1.0083x over previous
//
#include <hip/hip_runtime.h>
#include <hip/hip_bf16.h>

typedef unsigned short u16;
typedef unsigned int u32;

#define MAXB 2048

__device__ __forceinline__ float bf2f(u16 u) { return __uint_as_float(((u32)u) << 16); }
__device__ __forceinline__ float bl(u32 u) { return __uint_as_float(u << 16); }
__device__ __forceinline__ float bh(u32 u) { return __uint_as_float(u & 0xffff0000u); }
__device__ __forceinline__ u16 f2bf(float f) {
    u32 u = __float_as_uint(f);
    u += 0x7fffu + ((u >> 16) & 1u);   // round-to-nearest-even
    return (u16)(u >> 16);
}
__device__ __forceinline__ float lrelu(float x) { return x > 0.f ? x : 0.2f * x; }
__device__ __forceinline__ int clampi(int v, int lo, int hi) {
    return v < lo ? lo : (v > hi ? hi : v);
}
__device__ __forceinline__ float load1(const void* base, int idx, int f32) {
    return f32 ? ((const float*)base)[idx] : bf2f(((const u16*)base)[idx]);
}

// ---------------- dtype detector ---------------------------------------------------------
__global__ void k_detect(const u32* __restrict__ xw, int* __restrict__ flag) {
    int lane = threadIdx.x & 63;
    int cnt = 0;
    #pragma unroll
    for (int j = 0; j < 4; j++) {
        u32 w = xw[lane * 4 + j];
        int e0 = (int)((w >> 7) & 0xffu);
        int e1 = (int)((w >> 23) & 0xffu);
        cnt += (e0 >= 0x60 && e0 <= 0x8f);
        cnt += (e1 >= 0x60 && e1 <= 0x8f);
    }
    #pragma unroll
    for (int off = 32; off > 0; off >>= 1) cnt += __shfl_xor(cnt, off);
    if (lane == 0) *flag = (cnt < 480) ? 1 : 0;
}

// ---------------- constants + fp32 expansion of attention vectors -----------------------
__global__ void k_consts(const void* We1, const void* ae1, const void* We2, const void* ae2,
                         const void* as1, const void* ad1, const void* as2, const void* ad2,
                         const int* __restrict__ flag, float* __restrict__ consts) {
    int f = *flag;
    int t = threadIdx.x;
    if (t < 4) {
        float s = 0.f;
        for (int c = 0; c < 32; c++) s += load1(We1, t * 32 + c, f) * load1(ae1, t * 32 + c, f);
        consts[t] = s;
    } else if (t == 4) {
        float s = 0.f;
        for (int c = 0; c < 64; c++) s += load1(We2, c, f) * load1(ae2, c, f);
        consts[4] = s;
    }
    if (t < 128) {
        consts[8 + t] = load1(as1, t, f);
        consts[136 + t] = load1(ad1, t, f);
    }
    if (t < 64) {
        consts[264 + t] = load1(as2, t, f);
        consts[328 + t] = load1(ad2, t, f);
    }
}

// ---------------- GEMM: Y[nrows,NC] = X[nrows,128] @ W[128,NC] --------------------------
template <int NC>
__global__ __launch_bounds__(256, 4) void k_gemm5(
    const void* __restrict__ X, const void* __restrict__ Wg,
    const int* __restrict__ flag, int fXovr, u16* __restrict__ Y, int nrows) {
    constexpr int K = 128;
    constexpr int ROWS = 32;
    __shared__ float Ws[K * NC];
    __shared__ float Xs[ROWS * K];

    const int f = *flag;
    const bool fX = (fXovr < 0) ? (f != 0) : (fXovr != 0);
    const bool fW = (f != 0);
    const int tid = threadIdx.x, wid = tid >> 6, lane = tid & 63;

    for (int i = tid * 4; i < K * NC; i += 256 * 4) {
        int j = i / NC;
        int col = i & (NC - 1);
        int srow = (NC == 64) ? ((j & 1) * 64 + (j >> 1)) : j;
        int g = srow * NC + col;
        if (fW) {
            float4 v = *(const float4*)((const float*)Wg + g);
            Ws[i] = v.x; Ws[i + 1] = v.y; Ws[i + 2] = v.z; Ws[i + 3] = v.w;
        } else {
            ushort4 r = *(const ushort4*)((const u16*)Wg + g);
            Ws[i] = bf2f(r.x); Ws[i + 1] = bf2f(r.y);
            Ws[i + 2] = bf2f(r.z); Ws[i + 3] = bf2f(r.w);
        }
    }

    const int sr = tid >> 3;
    const int sc = (tid & 7) * 16;

    for (int base = blockIdx.x * ROWS; base < nrows; base += gridDim.x * ROWS) {
        __syncthreads();
        {
            int row = base + sr;
            float* xs = &Xs[sr * K + sc];
            if (row < nrows) {
                if (fX) {
                    const float* xp = (const float*)X + (size_t)row * K + sc;
                    float4 a = *(const float4*)xp;
                    float4 b = *(const float4*)(xp + 4);
                    float4 c = *(const float4*)(xp + 8);
                    float4 d = *(const float4*)(xp + 12);
                    xs[0] = a.x; xs[1] = a.y; xs[2] = a.z; xs[3] = a.w;
                    xs[4] = b.x; xs[5] = b.y; xs[6] = b.z; xs[7] = b.w;
                    xs[8] = c.x; xs[9] = c.y; xs[10] = c.z; xs[11] = c.w;
                    xs[12] = d.x; xs[13] = d.y; xs[14] = d.z; xs[15] = d.w;
                } else {
                    const u16* xp = (const u16*)X + (size_t)row * K + sc;
                    uint4 a = *(const uint4*)xp;
                    uint4 b = *(const uint4*)(xp + 8);
                    xs[0] = bl(a.x); xs[1] = bh(a.x); xs[2] = bl(a.y); xs[3] = bh(a.y);
                    xs[4] = bl(a.z); xs[5] = bh(a.z); xs[6] = bl(a.w); xs[7] = bh(a.w);
                    xs[8] = bl(b.x); xs[9] = bh(b.x); xs[10] = bl(b.y); xs[11] = bh(b.y);
                    xs[12] = bl(b.z); xs[13] = bh(b.z); xs[14] = bl(b.w); xs[15] = bh(b.w);
                }
            } else {
                #pragma unroll
                for (int j = 0; j < 16; j++) xs[j] = 0.f;
            }
        }
        __syncthreads();

        float acc0[8] = {0.f, 0.f, 0.f, 0.f, 0.f, 0.f, 0.f, 0.f};
        float acc1[8] = {0.f, 0.f, 0.f, 0.f, 0.f, 0.f, 0.f, 0.f};
        #pragma unroll 2
        for (int k = 0; k < K; k += 4) {
            float wa0 = Ws[(k + 0) * NC + lane];
            float wa1 = Ws[(k + 1) * NC + lane];
            float wa2 = Ws[(k + 2) * NC + lane];
            float wa3 = Ws[(k + 3) * NC + lane];
            float wb0 = 0.f, wb1 = 0.f, wb2 = 0.f, wb3 = 0.f;
            if constexpr (NC == 128) {
                wb0 = Ws[(k + 0) * NC + lane + 64];
                wb1 = Ws[(k + 1) * NC + lane + 64];
                wb2 = Ws[(k + 2) * NC + lane + 64];
                wb3 = Ws[(k + 3) * NC + lane + 64];
            }
            #pragma unroll
            for (int rr = 0; rr < 8; rr++) {
                float4 xv = *(const float4*)&Xs[(wid * 8 + rr) * K + k];
                acc0[rr] += xv.x * wa0 + xv.y * wa1 + xv.z * wa2 + xv.w * wa3;
                if constexpr (NC == 128)
                    acc1[rr] += xv.x * wb0 + xv.y * wb1 + xv.z * wb2 + xv.w * wb3;
            }
        }

        #pragma unroll
        for (int rr = 0; rr < 8; rr++) {
            int row = base + wid * 8 + rr;
            if (row < nrows) {
                if constexpr (NC == 128) {
                    u32 w = (u32)f2bf(acc0[rr]) | ((u32)f2bf(acc1[rr]) << 16);
                    ((u32*)Y)[(size_t)row * 64 + lane] = w;
                } else {
                    Y[(size_t)row * 64 + lane] = f2bf(acc0[rr]);
                }
            }
        }
    }
}

// ---------------- coef1: paired h1 -> asrc1/adst1 [N][4] --------------------------------
__global__ void k_coef1(const u32* __restrict__ hp, const float* __restrict__ consts,
                        float* __restrict__ asrc, float* __restrict__ adst, int n) {
    int i = blockIdx.x * 256 + threadIdx.x;
    if (i >= n * 2) return;
    int node = i >> 1, g = i & 1;
    const u32* w = hp + (size_t)node * 64 + g * 32;
    const float* asA = consts + 8 + g * 32;
    const float* adA = consts + 136 + g * 32;
    const float* asB = consts + 8 + (g + 2) * 32;
    const float* adB = consts + 136 + (g + 2) * 32;
    float sA1 = 0.f, sA2 = 0.f, sB1 = 0.f, sB2 = 0.f;
    #pragma unroll
    for (int c = 0; c < 32; c += 4) {
        uint4 q = *(const uint4*)&w[c];
        float l0 = bl(q.x), h0 = bh(q.x), l1 = bl(q.y), h1 = bh(q.y);
        float l2 = bl(q.z), h2 = bh(q.z), l3 = bl(q.w), h3 = bh(q.w);
        sA1 += l0 * asA[c] + l1 * asA[c + 1] + l2 * asA[c + 2] + l3 * asA[c + 3];
        sA2 += l0 * adA[c] + l1 * adA[c + 1] + l2 * adA[c + 2] + l3 * adA[c + 3];
        sB1 += h0 * asB[c] + h1 * asB[c + 1] + h2 * asB[c + 2] + h3 * asB[c + 3];
        sB2 += h0 * adB[c] + h1 * adB[c + 1] + h2 * adB[c + 2] + h3 * adB[c + 3];
    }
    asrc[node * 4 + g] = sA1;     adst[node * 4 + g] = sA2;
    asrc[node * 4 + g + 2] = sB1; adst[node * 4 + g + 2] = sB2;
}

// ---------------- coef2: natural h2 -> asrc2/adst2 [N] ----------------------------------
__global__ void k_coef2(const u32* __restrict__ hp, const float* __restrict__ consts,
                        float* __restrict__ asrc, float* __restrict__ adst, int n) {
    int i = blockIdx.x * 256 + threadIdx.x;
    if (i >= n) return;
    const u32* w = hp + (size_t)i * 32;
    const float* as_ = consts + 264;
    const float* ad_ = consts + 328;
    float s1 = 0.f, s2 = 0.f;
    #pragma unroll
    for (int c = 0; c < 32; c += 4) {
        uint4 q = *(const uint4*)&w[c];
        float l0 = bl(q.x), h0 = bh(q.x), l1 = bl(q.y), h1 = bh(q.y);
        float l2 = bl(q.z), h2 = bh(q.z), l3 = bl(q.w), h3 = bh(q.w);
        s1 += l0 * as_[2*c] + h0 * as_[2*c+1] + l1 * as_[2*c+2] + h1 * as_[2*c+3]
            + l2 * as_[2*c+4] + h2 * as_[2*c+5] + l3 * as_[2*c+6] + h3 * as_[2*c+7];
        s2 += l0 * ad_[2*c] + h0 * ad_[2*c+1] + l1 * ad_[2*c+2] + h1 * ad_[2*c+3]
            + l2 * ad_[2*c+4] + h2 * ad_[2*c+5] + l3 * ad_[2*c+6] + h3 * ad_[2*c+7];
    }
    asrc[i] = s1; adst[i] = s2;
}

// ---------------- CSR build -------------------------------------------------------------
__global__ __launch_bounds__(256) void k_bhist(const int* __restrict__ dst,
                                               int* __restrict__ cnt, int* __restrict__ bcnt,
                                               int E, int n, int B) {
    __shared__ int lh[MAXB];
    for (int i = threadIdx.x; i < B; i += 256) lh[i] = 0;
    __syncthreads();
    int stride = gridDim.x * 256;
    for (int e = blockIdx.x * 256 + threadIdx.x; e < E; e += stride) {
        int d = clampi(dst[e], 0, n - 1);
        atomicAdd(&cnt[d], 1);
        atomicAdd(&lh[d >> 8], 1);
    }
    __syncthreads();
    for (int i = threadIdx.x; i < B; i += 256)
        if (lh[i]) atomicAdd(&bcnt[i], lh[i]);
}
__global__ void k_scan1(const int* __restrict__ cnt, int* __restrict__ part,
                        int* __restrict__ bsum, int n) {
    __shared__ int buf[256];
    int i = blockIdx.x * 256 + threadIdx.x;
    int v = (i < n) ? cnt[i] : 0;
    buf[threadIdx.x] = v;
    __syncthreads();
    for (int off = 1; off < 256; off <<= 1) {
        int t = (threadIdx.x >= off) ? buf[threadIdx.x - off] : 0;
        __syncthreads();
        buf[threadIdx.x] += t;
        __syncthreads();
    }
    if (i < n) part[i] = buf[threadIdx.x];
    if (threadIdx.x == 255) bsum[blockIdx.x] = buf[255];
}
__global__ void k_scan2(int* __restrict__ bsum, int nb) {
    __shared__ int buf[256];
    int t = threadIdx.x;
    int v = (t < nb) ? bsum[t] : 0;
    buf[t] = v;
    __syncthreads();
    for (int off = 1; off < 256; off <<= 1) {
        int tt = (t >= off) ? buf[t - off] : 0;
        __syncthreads();
        buf[t] += tt;
        __syncthreads();
    }
    if (t < nb) bsum[t] = buf[t] - v;   // exclusive
}
__global__ void k_scan3(int* __restrict__ roff, const int* __restrict__ bsum,
                        int* __restrict__ rpos, int n) {
    int i = blockIdx.x * 256 + threadIdx.x;
    if (i > n) return;
    int v;
    if (i == 0) { v = 0; roff[0] = 0; }
    else { v = roff[i] + bsum[(i - 1) >> 8]; roff[i] = v; }
    if (i < n) rpos[i] = v;
}
__global__ void k_bscan(const int* __restrict__ bcnt, int* __restrict__ bbase,
                        int* __restrict__ bfront, int B) {
    if (threadIdx.x == 0) {
        int acc = 0;
        for (int i = 0; i < B; i++) { bbase[i] = acc; bfront[i] = acc; acc += bcnt[i]; }
        bbase[B] = acc;
    }
}
// binA: tile-ranked bucket scatter -> staged int4 {src, dst, ea_bits, 0}
__global__ __launch_bounds__(256) void k_binA(
    const int* __restrict__ dst, const int* __restrict__ src, const void* eattr,
    const int* __restrict__ flag, int* __restrict__ bfront, int4* __restrict__ staged,
    int E, int n, int B) {
    __shared__ int lhist[MAXB];
    __shared__ int lbase[MAXB];
    int f = *flag;
    constexpr int T = 2048;
    for (int tile = blockIdx.x; (long long)tile * T < E; tile += gridDim.x) {
        int base = tile * T;
        for (int i = threadIdx.x; i < B; i += 256) lhist[i] = 0;
        __syncthreads();
        int sj0, sj1, sj2, sj3, sj4, sj5, sj6, sj7;
        int dj0, dj1, dj2, dj3, dj4, dj5, dj6, dj7;
        int rj0, rj1, rj2, rj3, rj4, rj5, rj6, rj7;
        int ej0, ej1, ej2, ej3, ej4, ej5, ej6, ej7;
        #define BINA_LOAD(J, SJ, DJ, RJ, EJ)                                   \
        {                                                                      \
            int idx = base + (J) * 256 + threadIdx.x;                          \
            bool v = idx < E;                                                  \
            int d = v ? clampi(dst[idx], 0, n - 1) : 0;                        \
            SJ = v ? clampi(src[idx], 0, n - 1) : 0;                           \
            EJ = v ? __float_as_int(load1(eattr, idx, f)) : 0;                 \
            DJ = d;                                                            \
            RJ = v ? atomicAdd(&lhist[d >> 8], 1) : -1;                        \
        }
        BINA_LOAD(0, sj0, dj0, rj0, ej0)
        BINA_LOAD(1, sj1, dj1, rj1, ej1)
        BINA_LOAD(2, sj2, dj2, rj2, ej2)
        BINA_LOAD(3, sj3, dj3, rj3, ej3)
        BINA_LOAD(4, sj4, dj4, rj4, ej4)
        BINA_LOAD(5, sj5, dj5, rj5, ej5)
        BINA_LOAD(6, sj6, dj6, rj6, ej6)
        BINA_LOAD(7, sj7, dj7, rj7, ej7)
        #undef BINA_LOAD
        __syncthreads();
        for (int i = threadIdx.x; i < B; i += 256) {
            int c = lhist[i];
            lbase[i] = c ? atomicAdd(&bfront[i], c) : 0;
        }
        __syncthreads();
        #define BINA_STORE(SJ, DJ, RJ, EJ)                                     \
        if (RJ >= 0) {                                                         \
            long long q = (long long)lbase[DJ >> 8] + RJ;                      \
            if (q >= 0 && q < E) {                                             \
                int4 v; v.x = SJ; v.y = DJ; v.z = EJ; v.w = 0;                 \
                staged[q] = v;                                                 \
            }                                                                  \
        }
        BINA_STORE(sj0, dj0, rj0, ej0)
        BINA_STORE(sj1, dj1, rj1, ej1)
        BINA_STORE(sj2, dj2, rj2, ej2)
        BINA_STORE(sj3, dj3, rj3, ej3)
        BINA_STORE(sj4, dj4, rj4, ej4)
        BINA_STORE(sj5, dj5, rj5, ej5)
        BINA_STORE(sj6, dj6, rj6, ej6)
        BINA_STORE(sj7, dj7, rj7, ej7)
        #undef BINA_STORE
        __syncthreads();
    }
}
// binB: one workgroup per bucket; writes confined to the bucket's edata window
__global__ __launch_bounds__(256) void k_binB(
    const int4* __restrict__ staged, const int* __restrict__ bbase,
    const int* __restrict__ roff, int2* __restrict__ edata, int N, int E, int B) {
    __shared__ int lpos[256];
    int k = blockIdx.x;
    int dlo = k << 8;
    int t = threadIdx.x;
    int dn = dlo + t;
    lpos[t] = (dn < N) ? roff[dn] : 0;
    __syncthreads();
    int lo = clampi(bbase[k], 0, E);
    int hi = clampi(bbase[k + 1], lo, E);
    for (int i = lo + t; i < hi; i += 256) {
        int4 v = staged[i];
        int p = atomicAdd(&lpos[v.y & 255], 1);
        if (p >= 0 && p < E) edata[p] = make_int2(v.x, v.z);
    }
}
// fallback single-pass scatter
__global__ void k_scatter(const int* __restrict__ dst, const int* __restrict__ src,
                          const void* eattr, const int* __restrict__ flag,
                          int* __restrict__ rpos, int2* __restrict__ edata, int E, int n) {
    int f = *flag;
    int e = blockIdx.x * 256 + threadIdx.x;
    if (e < E) {
        int d = clampi(dst[e], 0, n - 1);
        int s = clampi(src[e], 0, n - 1);
        float ea = load1(eattr, e, f);
        int p = atomicAdd(&rpos[d], 1);
        if (p >= 0 && p < E) {
            int2 v; v.x = s; v.y = __float_as_int(ea);
            edata[p] = v;
        }
    }
}

// ---------------- gat1, CACHED: fused passes for deg<=64, LDS weights, 4x MLP -----------
__global__ __launch_bounds__(256) void k_gat1c(
    const u32* __restrict__ hp, const float* __restrict__ asrc, const float* __restrict__ adst,
    const int2* __restrict__ edata, const int* __restrict__ roff,
    const int* __restrict__ flag, const float* __restrict__ consts, const void* bias,
    float* __restrict__ al, u32* __restrict__ out, int n, int E) {
    __shared__ float4 wls[4][64];
    int f = *flag;
    int gtid = blockIdx.x * 256 + threadIdx.x;
    int wv = gtid >> 6, lane = gtid & 63;
    int wid = (threadIdx.x >> 6);
    int nw = (gridDim.x * 256) >> 6;
    const float c0 = consts[0], c1 = consts[1], c2 = consts[2], c3 = consts[3];
    const int hsel = lane >> 5;
    const float biasA = load1(bias, lane, f);
    const float biasB = load1(bias, 64 + lane, f);

    for (int d = wv; d < n; d += nw) {
        int s0 = clampi(roff[d], 0, E);
        int s1 = clampi(roff[d + 1], s0, E);
        int deg = s1 - s0;
        float4 adv = *(const float4*)&adst[d * 4];
        float accA = 0.f, accB = 0.f;

        if (deg <= 64) {
            bool v = lane < deg;
            int s = 0; float ea = 0.f;
            float a0 = -1e30f, a1 = -1e30f, a2 = -1e30f, a3 = -1e30f;
            if (v) {
                int2 ed = edata[s0 + lane];
                s = ed.x; ea = __int_as_float(ed.y);
                float4 av = *(const float4*)&asrc[(size_t)s * 4];
                a0 = lrelu(av.x + adv.x + ea * c0);
                a1 = lrelu(av.y + adv.y + ea * c1);
                a2 = lrelu(av.z + adv.z + ea * c2);
                a3 = lrelu(av.w + adv.w + ea * c3);
            }
            float m0 = a0, m1 = a1, m2 = a2, m3 = a3;
            #pragma unroll
            for (int off = 32; off > 0; off >>= 1) {
                m0 = fmaxf(m0, __shfl_xor(m0, off));
                m1 = fmaxf(m1, __shfl_xor(m1, off));
                m2 = fmaxf(m2, __shfl_xor(m2, off));
                m3 = fmaxf(m3, __shfl_xor(m3, off));
            }
            float e0 = v ? expf(a0 - m0) : 0.f;
            float e1 = v ? expf(a1 - m1) : 0.f;
            float e2 = v ? expf(a2 - m2) : 0.f;
            float e3 = v ? expf(a3 - m3) : 0.f;
            float d0 = e0, d1 = e1, d2 = e2, d3 = e3;
            #pragma unroll
            for (int off = 32; off > 0; off >>= 1) {
                d0 += __shfl_xor(d0, off); d1 += __shfl_xor(d1, off);
                d2 += __shfl_xor(d2, off); d3 += __shfl_xor(d3, off);
            }
            float i0 = 1.f / (d0 + 1e-16f), i1 = 1.f / (d1 + 1e-16f);
            float i2 = 1.f / (d2 + 1e-16f), i3 = 1.f / (d3 + 1e-16f);
            if (v) wls[wid][lane] = make_float4(e0 * i0, e1 * i1, e2 * i2, e3 * i3);

            int j = 0;
            for (; j + 4 <= deg; j += 4) {
                int sa = __shfl(s, j), sb = __shfl(s, j + 1);
                int sc_ = __shfl(s, j + 2), sd = __shfl(s, j + 3);
                u32 ha = hp[(size_t)sa * 64 + lane];
                u32 hb = hp[(size_t)sb * 64 + lane];
                u32 hc = hp[(size_t)sc_ * 64 + lane];
                u32 hd = hp[(size_t)sd * 64 + lane];
                float4 wa = wls[wid][j], wb = wls[wid][j + 1];
                float4 wc = wls[wid][j + 2], wd = wls[wid][j + 3];
                accA += (hsel ? wa.y : wa.x) * bl(ha); accB += (hsel ? wa.w : wa.z) * bh(ha);
                accA += (hsel ? wb.y : wb.x) * bl(hb); accB += (hsel ? wb.w : wb.z) * bh(hb);
                accA += (hsel ? wc.y : wc.x) * bl(hc); accB += (hsel ? wc.w : wc.z) * bh(hc);
                accA += (hsel ? wd.y : wd.x) * bl(hd); accB += (hsel ? wd.w : wd.z) * bh(hd);
            }
            for (; j < deg; j++) {
                int sj = __shfl(s, j);
                u32 hw = hp[(size_t)sj * 64 + lane];
                float4 w = wls[wid][j];
                accA += (hsel ? w.y : w.x) * bl(hw);
                accB += (hsel ? w.w : w.z) * bh(hw);
            }
        } else {
            float m0 = -1e30f, m1 = -1e30f, m2 = -1e30f, m3 = -1e30f;
            for (int idx = s0 + lane; idx < s1; idx += 64) {
                int2 ed = edata[idx];
                int s = ed.x;
                float ea = __int_as_float(ed.y);
                float4 av = *(const float4*)&asrc[(size_t)s * 4];
                float a0 = lrelu(av.x + adv.x + ea * c0);
                float a1 = lrelu(av.y + adv.y + ea * c1);
                float a2 = lrelu(av.z + adv.z + ea * c2);
                float a3 = lrelu(av.w + adv.w + ea * c3);
                *(float4*)&al[(size_t)idx * 4] = make_float4(a0, a1, a2, a3);
                m0 = fmaxf(m0, a0); m1 = fmaxf(m1, a1);
                m2 = fmaxf(m2, a2); m3 = fmaxf(m3, a3);
            }
            #pragma unroll
            for (int off = 32; off > 0; off >>= 1) {
                m0 = fmaxf(m0, __shfl_xor(m0, off));
                m1 = fmaxf(m1, __shfl_xor(m1, off));
                m2 = fmaxf(m2, __shfl_xor(m2, off));
                m3 = fmaxf(m3, __shfl_xor(m3, off));
            }
            float d0 = 0.f, d1 = 0.f, d2 = 0.f, d3 = 0.f;
            for (int idx = s0 + lane; idx < s1; idx += 64) {
                float4 a = *(const float4*)&al[(size_t)idx * 4];
                float e0 = expf(a.x - m0), e1 = expf(a.y - m1);
                float e2 = expf(a.z - m2), e3 = expf(a.w - m3);
                d0 += e0; d1 += e1; d2 += e2; d3 += e3;
                *(float4*)&al[(size_t)idx * 4] = make_float4(e0, e1, e2, e3);
            }
            #pragma unroll
            for (int off = 32; off > 0; off >>= 1) {
                d0 += __shfl_xor(d0, off); d1 += __shfl_xor(d1, off);
                d2 += __shfl_xor(d2, off); d3 += __shfl_xor(d3, off);
            }
            float i0 = 1.f / (d0 + 1e-16f), i1 = 1.f / (d1 + 1e-16f);
            float i2 = 1.f / (d2 + 1e-16f), i3 = 1.f / (d3 + 1e-16f);
            float iA = hsel ? i1 : i0, iB = hsel ? i3 : i2;
            for (int idx = s0; idx < s1; idx++) {
                int s = edata[idx].x;
                float4 ex = *(const float4*)&al[(size_t)idx * 4];
                float wA = (hsel ? ex.y : ex.x) * iA;
                float wB = (hsel ? ex.w : ex.z) * iB;
                u32 hw = hp[(size_t)s * 64 + lane];
                accA += wA * bl(hw);
                accB += wB * bh(hw);
            }
        }
        float rA = fmaxf(accA + biasA, 0.f);
        float rB = fmaxf(accB + biasB, 0.f);
        out[(size_t)d * 64 + lane] = (u32)f2bf(rA) | ((u32)f2bf(rB) << 16);
    }
}

// ---------------- gat2, CACHED: fused passes for deg<=64, LDS weights, 4x MLP -----------
__global__ __launch_bounds__(256) void k_gat2c(
    const u16* __restrict__ h, const float* __restrict__ asrc, const float* __restrict__ adst,
    const int2* __restrict__ edata, const int* __restrict__ roff,
    const int* __restrict__ flag, const float* __restrict__ consts, const void* bias,
    float* __restrict__ al, u16* __restrict__ out, int n, int E) {
    __shared__ float wls[4][64];
    int f = *flag;
    int gtid = blockIdx.x * 256 + threadIdx.x;
    int wv = gtid >> 6, lane = gtid & 63;
    int wid = (threadIdx.x >> 6);
    int nw = (gridDim.x * 256) >> 6;
    const float C = consts[4];
    const float biasL = load1(bias, lane, f);

    for (int d = wv; d < n; d += nw) {
        int s0 = clampi(roff[d], 0, E);
        int s1 = clampi(roff[d + 1], s0, E);
        int deg = s1 - s0;
        float ad = adst[d];
        float acc = 0.f;

        if (deg <= 64) {
            bool v = lane < deg;
            int s = 0;
            float a = -1e30f;
            if (v) {
                int2 ed = edata[s0 + lane];
                s = ed.x;
                a = lrelu(asrc[s] + ad + __int_as_float(ed.y) * C);
            }
            float m = a;
            #pragma unroll
            for (int off = 32; off > 0; off >>= 1) m = fmaxf(m, __shfl_xor(m, off));
            float e = v ? expf(a - m) : 0.f;
            float den = e;
            #pragma unroll
            for (int off = 32; off > 0; off >>= 1) den += __shfl_xor(den, off);
            float inv = 1.f / (den + 1e-16f);
            if (v) wls[wid][lane] = e * inv;

            int j = 0;
            for (; j + 4 <= deg; j += 4) {
                int sa = __shfl(s, j), sb = __shfl(s, j + 1);
                int sc_ = __shfl(s, j + 2), sd = __shfl(s, j + 3);
                float ha = bf2f(h[(size_t)sa * 64 + lane]);
                float hb = bf2f(h[(size_t)sb * 64 + lane]);
                float hc = bf2f(h[(size_t)sc_ * 64 + lane]);
                float hd = bf2f(h[(size_t)sd * 64 + lane]);
                acc += wls[wid][j] * ha + wls[wid][j + 1] * hb
                     + wls[wid][j + 2] * hc + wls[wid][j + 3] * hd;
            }
            for (; j < deg; j++) {
                int sj = __shfl(s, j);
                acc += wls[wid][j] * bf2f(h[(size_t)sj * 64 + lane]);
            }
        } else {
            float m = -1e30f;
            for (int idx = s0 + lane; idx < s1; idx += 64) {
                int2 ed = edata[idx];
                float a = lrelu(asrc[ed.x] + ad + __int_as_float(ed.y) * C);
                al[idx] = a;
                m = fmaxf(m, a);
            }
            #pragma unroll
            for (int off = 32; off > 0; off >>= 1) m = fmaxf(m, __shfl_xor(m, off));
            float den = 0.f;
            for (int idx = s0 + lane; idx < s1; idx += 64) {
                float e = expf(al[idx] - m);
                den += e;
                al[idx] = e;
            }
            #pragma unroll
            for (int off = 32; off > 0; off >>= 1) den += __shfl_xor(den, off);
            float inv = 1.f / (den + 1e-16f);
            for (int idx = s0; idx < s1; idx++) {
                int s = edata[idx].x;
                acc += al[idx] * inv * bf2f(h[(size_t)s * 64 + lane]);
            }
        }
        out[(size_t)d * 64 + lane] = f2bf(acc + biasL);
    }
}

// ---------------- gat1/gat2 FALLBACK (recompute, no al cache) ---------------------------
__global__ __launch_bounds__(256) void k_gat1f(
    const u32* __restrict__ hp, const float* __restrict__ asrc, const float* __restrict__ adst,
    const int2* __restrict__ edata, const int* __restrict__ roff,
    const int* __restrict__ flag, const float* __restrict__ consts, const void* bias,
    u32* __restrict__ out, int n, int E) {
    int f = *flag;
    int gtid = blockIdx.x * 256 + threadIdx.x;
    int wv = gtid >> 6, lane = gtid & 63;
    int nw = (gridDim.x * 256) >> 6;
    const float c0 = consts[0], c1 = consts[1], c2 = consts[2], c3 = consts[3];
    const int hsel = lane >> 5;
    const float biasA = load1(bias, lane, f);
    const float biasB = load1(bias, 64 + lane, f);

    for (int d = wv; d < n; d += nw) {
        int s0 = clampi(roff[d], 0, E);
        int s1 = clampi(roff[d + 1], s0, E);
        float4 adv = *(const float4*)&adst[d * 4];
        float m0 = -1e30f, m1 = -1e30f, m2 = -1e30f, m3 = -1e30f;
        for (int idx = s0 + lane; idx < s1; idx += 64) {
            int2 ed = edata[idx];
            float ea = __int_as_float(ed.y);
            float4 av = *(const float4*)&asrc[(size_t)ed.x * 4];
            m0 = fmaxf(m0, lrelu(av.x + adv.x + ea * c0));
            m1 = fmaxf(m1, lrelu(av.y + adv.y + ea * c1));
            m2 = fmaxf(m2, lrelu(av.z + adv.z + ea * c2));
            m3 = fmaxf(m3, lrelu(av.w + adv.w + ea * c3));
        }
        #pragma unroll
        for (int off = 32; off > 0; off >>= 1) {
            m0 = fmaxf(m0, __shfl_xor(m0, off));
            m1 = fmaxf(m1, __shfl_xor(m1, off));
            m2 = fmaxf(m2, __shfl_xor(m2, off));
            m3 = fmaxf(m3, __shfl_xor(m3, off));
        }
        float d0 = 0.f, d1 = 0.f, d2 = 0.f, d3 = 0.f;
        for (int idx = s0 + lane; idx < s1; idx += 64) {
            int2 ed = edata[idx];
            float ea = __int_as_float(ed.y);
            float4 av = *(const float4*)&asrc[(size_t)ed.x * 4];
            d0 += expf(lrelu(av.x + adv.x + ea * c0) - m0);
            d1 += expf(lrelu(av.y + adv.y + ea * c1) - m1);
            d2 += expf(lrelu(av.z + adv.z + ea * c2) - m2);
            d3 += expf(lrelu(av.w + adv.w + ea * c3) - m3);
        }
        #pragma unroll
        for (int off = 32; off > 0; off >>= 1) {
            d0 += __shfl_xor(d0, off); d1 += __shfl_xor(d1, off);
            d2 += __shfl_xor(d2, off); d3 += __shfl_xor(d3, off);
        }
        float i0 = 1.f / (d0 + 1e-16f), i1 = 1.f / (d1 + 1e-16f);
        float i2 = 1.f / (d2 + 1e-16f), i3 = 1.f / (d3 + 1e-16f);
        float mA = hsel ? m1 : m0, mB = hsel ? m3 : m2;
        float iA = hsel ? i1 : i0, iB = hsel ? i3 : i2;
        float cA = hsel ? c1 : c0, cB = hsel ? c3 : c2;
        float aA = hsel ? adv.y : adv.x, aB = hsel ? adv.w : adv.z;

        float accA = 0.f, accB = 0.f;
        for (int idx = s0; idx < s1; idx++) {
            int2 ed = edata[idx];
            float ea = __int_as_float(ed.y);
            float4 av = *(const float4*)&asrc[(size_t)ed.x * 4];
            float alA = lrelu((hsel ? av.y : av.x) + aA + ea * cA);
            float alB = lrelu((hsel ? av.w : av.z) + aB + ea * cB);
            float wA = expf(alA - mA) * iA;
            float wB = expf(alB - mB) * iB;
            u32 hw = hp[(size_t)ed.x * 64 + lane];
            accA += wA * bl(hw);
            accB += wB * bh(hw);
        }
        float rA = fmaxf(accA + biasA, 0.f);
        float rB = fmaxf(accB + biasB, 0.f);
        out[(size_t)d * 64 + lane] = (u32)f2bf(rA) | ((u32)f2bf(rB) << 16);
    }
}

__global__ __launch_bounds__(256) void k_gat2f(
    const u16* __restrict__ h, const float* __restrict__ asrc, const float* __restrict__ adst,
    const int2* __restrict__ edata, const int* __restrict__ roff,
    const int* __restrict__ flag, const float* __restrict__ consts, const void* bias,
    u16* __restrict__ out, int n, int E) {
    int f = *flag;
    int gtid = blockIdx.x * 256 + threadIdx.x;
    int wv = gtid >> 6, lane = gtid & 63;
    int nw = (gridDim.x * 256) >> 6;
    const float C = consts[4];
    const float biasL = load1(bias, lane, f);

    for (int d = wv; d < n; d += nw) {
        int s0 = clampi(roff[d], 0, E);
        int s1 = clampi(roff[d + 1], s0, E);
        float ad = adst[d];
        float m = -1e30f;
        for (int idx = s0 + lane; idx < s1; idx += 64) {
            int2 ed = edata[idx];
            m = fmaxf(m, lrelu(asrc[ed.x] + ad + __int_as_float(ed.y) * C));
        }
        #pragma unroll
        for (int off = 32; off > 0; off >>= 1) m = fmaxf(m, __shfl_xor(m, off));
        float den = 0.f;
        for (int idx = s0 + lane; idx < s1; idx += 64) {
            int2 ed = edata[idx];
            den += expf(lrelu(asrc[ed.x] + ad + __int_as_float(ed.y) * C) - m);
        }
        #pragma unroll
        for (int off = 32; off > 0; off >>= 1) den += __shfl_xor(den, off);
        float inv = 1.f / (den + 1e-16f);

        float acc = 0.f;
        for (int idx = s0; idx < s1; idx++) {
            int2 ed = edata[idx];
            float a = lrelu(asrc[ed.x] + ad + __int_as_float(ed.y) * C);
            acc += expf(a - m) * inv * bf2f(h[(size_t)ed.x * 64 + lane]);
        }
        out[(size_t)d * 64 + lane] = f2bf(acc + biasL);
    }
}

// ---------------- pooling ---------------------------------------------------------------
__global__ void k_pool(const u16* __restrict__ agg2, const int* __restrict__ batch,
                       float* __restrict__ pool, float* __restrict__ cnt, int n, int G) {
    int t = blockIdx.x * 256 + threadIdx.x;
    int nb8 = (n + 7) / 8;
    if (t >= nb8 * 64) return;
    int base = (t >> 6) * 8;
    int c = t & 63;
    int end = min(base + 8, n);
    float acc = 0.f, cacc = 0.f;
    int curg = clampi(batch[base], 0, G - 1);
    for (int j = base; j < end; j++) {
        int g = clampi(batch[j], 0, G - 1);
        if (g != curg) {
            atomicAdd(&pool[curg * 64 + c], acc);
            if (c == 0) atomicAdd(&cnt[curg], cacc);
            acc = 0.f; cacc = 0.f; curg = g;
        }
        acc += bf2f(agg2[(size_t)j * 64 + c]);
        cacc += 1.f;
    }
    atomicAdd(&pool[curg * 64 + c], acc);
    if (c == 0) atomicAdd(&cnt[curg], cacc);
}

__global__ void k_head(const float* __restrict__ pool, const float* __restrict__ cnt,
                       const void* Wp, const void* bp, const int* __restrict__ flag,
                       void* out, int G) {
    int f = *flag;
    int g = threadIdx.x;
    if (g >= G) return;
    float s = 0.f;
    for (int c = 0; c < 64; c++) s += pool[g * 64 + c] * load1(Wp, c, f);
    float cv = cnt[g];
    if (!(cv > 0.f)) cv = 1.f;
    float r = s / cv + load1(bp, 0, f);
    if (f) ((float*)out)[g] = r;
    else   ((u16*)out)[g] = f2bf(r);
}

// ---------------- launch ----------------------------------------------------------------
extern "C" void kernel_launch(void* const* d_in, const int* in_sizes, int n_in,
                              void* d_out, int out_size, void* d_ws, size_t ws_size,
                              hipStream_t stream) {
    const void* x    = d_in[0];
    const int* ei    = (const int*)d_in[1];
    const void* eattr = d_in[2];
    const int* batch = (const int*)d_in[3];
    const void* W1   = d_in[4];
    const void* as1  = d_in[5];
    const void* ad1  = d_in[6];
    const void* We1  = d_in[7];
    const void* ae1  = d_in[8];
    const void* b1   = d_in[9];
    const void* W2   = d_in[10];
    const void* as2  = d_in[11];
    const void* ad2  = d_in[12];
    const void* We2  = d_in[13];
    const void* ae2  = d_in[14];
    const void* b2   = d_in[15];
    const void* Wp   = d_in[16];
    const void* bp   = d_in[17];

    const int N = in_sizes[3];
    const int E = in_sizes[2];
    const int G = out_size;
    const int* src = ei;
    const int* dst = ei + E;
    const int B = (N + 255) >> 8;

    char* p = (char*)d_ws;
    auto alloc = [&](size_t bytes) -> char* {
        char* r = p;
        p += (bytes + 255) & ~(size_t)255;
        return r;
    };
    int* flag    = (int*)alloc(32);
    float* consts = (float*)alloc(2048);
    int* roff    = (int*)alloc((size_t)(N + 1) * 4);
    int* rpos    = (int*)alloc((size_t)N * 4);
    int* bsum    = (int*)alloc(256 * 4);
    int* bcnt    = (int*)alloc((size_t)(MAXB * 3 + 1) * 4);
    int* bbase   = bcnt + MAXB;          // B+1 entries
    int* bfront  = bbase + MAXB + 1;     // B entries
    int2* edata  = (int2*)alloc((size_t)E * 8);
    float* pool  = (float*)alloc((size_t)(G * 64 + G) * 4);
    float* cnt   = pool + (size_t)G * 64;
    float* asrc1 = (float*)alloc((size_t)N * 4 * 4);
    float* adst1 = (float*)alloc((size_t)N * 4 * 4);
    float* asrc2 = asrc1;             // alias: dead after gat1
    float* adst2 = adst1;
    u16* agg1    = (u16*)alloc((size_t)N * 128 * 2);
    u16* h1      = (u16*)alloc((size_t)N * 128 * 2);
    u16* h2      = h1;                // alias: h1 dead after gat1
    u16* agg2    = h1 + (size_t)N * 64;
    // al: gat spill buffer (deg>64 only). staged aliases al (temporally disjoint).
    float* al    = (float*)alloc((size_t)E * 16);
    int4* staged = (int4*)al;
    size_t full_need = (size_t)(p - (char*)d_ws);
    const bool cached = (ws_size >= full_need);
    const bool binned = cached && (B <= MAXB);

    hipMemsetAsync(rpos, 0, (size_t)N * 4, stream);
    hipMemsetAsync(bcnt, 0, (size_t)B * 4, stream);
    hipMemsetAsync(pool, 0, (size_t)(G * 64 + G) * 4, stream);

    k_detect<<<1, 64, 0, stream>>>((const u32*)x, flag);
    k_consts<<<1, 256, 0, stream>>>(We1, ae1, We2, ae2, as1, ad1, as2, ad2, flag, consts);
    k_gemm5<128><<<512, 256, 0, stream>>>(x, W1, flag, -1, h1, N);
    k_coef1<<<(N * 2 + 255) / 256, 256, 0, stream>>>((const u32*)h1, consts, asrc1, adst1, N);

    int NB = (N + 255) / 256;
    k_bhist<<<512, 256, 0, stream>>>(dst, rpos, bcnt, E, N, B);
    k_scan1<<<NB, 256, 0, stream>>>(rpos, roff + 1, bsum, N);
    k_scan2<<<1, 256, 0, stream>>>(bsum, NB);
    k_scan3<<<(N + 256) / 256, 256, 0, stream>>>(roff, bsum, rpos, N);
    if (binned) {
        k_bscan<<<1, 64, 0, stream>>>(bcnt, bbase, bfront, B);
        k_binA<<<(E + 2047) / 2048, 256, 0, stream>>>(dst, src, eattr, flag, bfront,
                                                      staged, E, N, B);
        k_binB<<<B, 256, 0, stream>>>(staged, bbase, roff, edata, N, E, B);
    } else {
        k_scatter<<<(E + 255) / 256, 256, 0, stream>>>(dst, src, eattr, flag, rpos,
                                                       edata, E, N);
    }

    int gatBlocks = (N * 64 + 255) / 256;
    if (cached) {
        k_gat1c<<<gatBlocks, 256, 0, stream>>>((const u32*)h1, asrc1, adst1, edata, roff,
                                               flag, consts, b1, al, (u32*)agg1, N, E);
    } else {
        k_gat1f<<<gatBlocks, 256, 0, stream>>>((const u32*)h1, asrc1, adst1, edata, roff,
                                               flag, consts, b1, (u32*)agg1, N, E);
    }
    k_gemm5<64><<<512, 256, 0, stream>>>(agg1, W2, flag, 0, h2, N);
    k_coef2<<<(N + 255) / 256, 256, 0, stream>>>((const u32*)h2, consts, asrc2, adst2, N);
    if (cached) {
        k_gat2c<<<gatBlocks, 256, 0, stream>>>(h2, asrc2, adst2, edata, roff, flag,
                                               consts, b2, al, agg2, N, E);
    } else {
        k_gat2f<<<gatBlocks, 256, 0, stream>>>(h2, asrc2, adst2, edata, roff, flag,
                                               consts, b2, agg2, N, E);
    }
    k_pool<<<(((N + 7) / 8) * 64 + 255) / 256, 256, 0, stream>>>(agg2, batch, pool, cnt, N, G);
    k_head<<<1, 64, 0, stream>>>(pool, cnt, Wp, bp, flag, d_out, G);
}

// Round 13
// 417.961 us; speedup vs baseline: 4.7185x; 1.0228x over previous
//
#include <hip/hip_runtime.h>
#include <hip/hip_bf16.h>

typedef unsigned short u16;
typedef unsigned int u32;

#define MAXB 2048

__device__ __forceinline__ float bf2f(u16 u) { return __uint_as_float(((u32)u) << 16); }
__device__ __forceinline__ float bl(u32 u) { return __uint_as_float(u << 16); }
__device__ __forceinline__ float bh(u32 u) { return __uint_as_float(u & 0xffff0000u); }
__device__ __forceinline__ u16 f2bf(float f) {
    u32 u = __float_as_uint(f);
    u += 0x7fffu + ((u >> 16) & 1u);   // round-to-nearest-even
    return (u16)(u >> 16);
}
__device__ __forceinline__ float lrelu(float x) { return x > 0.f ? x : 0.2f * x; }
__device__ __forceinline__ int clampi(int v, int lo, int hi) {
    return v < lo ? lo : (v > hi ? hi : v);
}
__device__ __forceinline__ float load1(const void* base, int idx, int f32) {
    return f32 ? ((const float*)base)[idx] : bf2f(((const u16*)base)[idx]);
}
// softmax without max-shift: clamp keeps exp finite; shift-invariance => same ratios
__device__ __forceinline__ float cexpf(float a) { return expf(fminf(a, 30.f)); }

// ---------------- dtype detector ---------------------------------------------------------
__global__ void k_detect(const u32* __restrict__ xw, int* __restrict__ flag) {
    int lane = threadIdx.x & 63;
    int cnt = 0;
    #pragma unroll
    for (int j = 0; j < 4; j++) {
        u32 w = xw[lane * 4 + j];
        int e0 = (int)((w >> 7) & 0xffu);
        int e1 = (int)((w >> 23) & 0xffu);
        cnt += (e0 >= 0x60 && e0 <= 0x8f);
        cnt += (e1 >= 0x60 && e1 <= 0x8f);
    }
    #pragma unroll
    for (int off = 32; off > 0; off >>= 1) cnt += __shfl_xor(cnt, off);
    if (lane == 0) *flag = (cnt < 480) ? 1 : 0;
}

// ---------------- constants + fp32 expansion of attention vectors -----------------------
__global__ void k_consts(const void* We1, const void* ae1, const void* We2, const void* ae2,
                         const void* as1, const void* ad1, const void* as2, const void* ad2,
                         const int* __restrict__ flag, float* __restrict__ consts) {
    int f = *flag;
    int t = threadIdx.x;
    if (t < 4) {
        float s = 0.f;
        for (int c = 0; c < 32; c++) s += load1(We1, t * 32 + c, f) * load1(ae1, t * 32 + c, f);
        consts[t] = s;
    } else if (t == 4) {
        float s = 0.f;
        for (int c = 0; c < 64; c++) s += load1(We2, c, f) * load1(ae2, c, f);
        consts[4] = s;
    }
    if (t < 128) {
        consts[8 + t] = load1(as1, t, f);
        consts[136 + t] = load1(ad1, t, f);
    }
    if (t < 64) {
        consts[264 + t] = load1(as2, t, f);
        consts[328 + t] = load1(ad2, t, f);
    }
}

// ---------------- GEMM: Y[nrows,NC] = X[nrows,128] @ W[128,NC] --------------------------
template <int NC>
__global__ __launch_bounds__(256, 4) void k_gemm5(
    const void* __restrict__ X, const void* __restrict__ Wg,
    const int* __restrict__ flag, int fXovr, u16* __restrict__ Y, int nrows) {
    constexpr int K = 128;
    constexpr int ROWS = 32;
    __shared__ float Ws[K * NC];
    __shared__ float Xs[ROWS * K];

    const int f = *flag;
    const bool fX = (fXovr < 0) ? (f != 0) : (fXovr != 0);
    const bool fW = (f != 0);
    const int tid = threadIdx.x, wid = tid >> 6, lane = tid & 63;

    for (int i = tid * 4; i < K * NC; i += 256 * 4) {
        int j = i / NC;
        int col = i & (NC - 1);
        int srow = (NC == 64) ? ((j & 1) * 64 + (j >> 1)) : j;
        int g = srow * NC + col;
        if (fW) {
            float4 v = *(const float4*)((const float*)Wg + g);
            Ws[i] = v.x; Ws[i + 1] = v.y; Ws[i + 2] = v.z; Ws[i + 3] = v.w;
        } else {
            ushort4 r = *(const ushort4*)((const u16*)Wg + g);
            Ws[i] = bf2f(r.x); Ws[i + 1] = bf2f(r.y);
            Ws[i + 2] = bf2f(r.z); Ws[i + 3] = bf2f(r.w);
        }
    }

    const int sr = tid >> 3;
    const int sc = (tid & 7) * 16;

    for (int base = blockIdx.x * ROWS; base < nrows; base += gridDim.x * ROWS) {
        __syncthreads();
        {
            int row = base + sr;
            float* xs = &Xs[sr * K + sc];
            if (row < nrows) {
                if (fX) {
                    const float* xp = (const float*)X + (size_t)row * K + sc;
                    float4 a = *(const float4*)xp;
                    float4 b = *(const float4*)(xp + 4);
                    float4 c = *(const float4*)(xp + 8);
                    float4 d = *(const float4*)(xp + 12);
                    xs[0] = a.x; xs[1] = a.y; xs[2] = a.z; xs[3] = a.w;
                    xs[4] = b.x; xs[5] = b.y; xs[6] = b.z; xs[7] = b.w;
                    xs[8] = c.x; xs[9] = c.y; xs[10] = c.z; xs[11] = c.w;
                    xs[12] = d.x; xs[13] = d.y; xs[14] = d.z; xs[15] = d.w;
                } else {
                    const u16* xp = (const u16*)X + (size_t)row * K + sc;
                    uint4 a = *(const uint4*)xp;
                    uint4 b = *(const uint4*)(xp + 8);
                    xs[0] = bl(a.x); xs[1] = bh(a.x); xs[2] = bl(a.y); xs[3] = bh(a.y);
                    xs[4] = bl(a.z); xs[5] = bh(a.z); xs[6] = bl(a.w); xs[7] = bh(a.w);
                    xs[8] = bl(b.x); xs[9] = bh(b.x); xs[10] = bl(b.y); xs[11] = bh(b.y);
                    xs[12] = bl(b.z); xs[13] = bh(b.z); xs[14] = bl(b.w); xs[15] = bh(b.w);
                }
            } else {
                #pragma unroll
                for (int j = 0; j < 16; j++) xs[j] = 0.f;
            }
        }
        __syncthreads();

        float acc0[8] = {0.f, 0.f, 0.f, 0.f, 0.f, 0.f, 0.f, 0.f};
        float acc1[8] = {0.f, 0.f, 0.f, 0.f, 0.f, 0.f, 0.f, 0.f};
        #pragma unroll 2
        for (int k = 0; k < K; k += 4) {
            float wa0 = Ws[(k + 0) * NC + lane];
            float wa1 = Ws[(k + 1) * NC + lane];
            float wa2 = Ws[(k + 2) * NC + lane];
            float wa3 = Ws[(k + 3) * NC + lane];
            float wb0 = 0.f, wb1 = 0.f, wb2 = 0.f, wb3 = 0.f;
            if constexpr (NC == 128) {
                wb0 = Ws[(k + 0) * NC + lane + 64];
                wb1 = Ws[(k + 1) * NC + lane + 64];
                wb2 = Ws[(k + 2) * NC + lane + 64];
                wb3 = Ws[(k + 3) * NC + lane + 64];
            }
            #pragma unroll
            for (int rr = 0; rr < 8; rr++) {
                float4 xv = *(const float4*)&Xs[(wid * 8 + rr) * K + k];
                acc0[rr] += xv.x * wa0 + xv.y * wa1 + xv.z * wa2 + xv.w * wa3;
                if constexpr (NC == 128)
                    acc1[rr] += xv.x * wb0 + xv.y * wb1 + xv.z * wb2 + xv.w * wb3;
            }
        }

        #pragma unroll
        for (int rr = 0; rr < 8; rr++) {
            int row = base + wid * 8 + rr;
            if (row < nrows) {
                if constexpr (NC == 128) {
                    u32 w = (u32)f2bf(acc0[rr]) | ((u32)f2bf(acc1[rr]) << 16);
                    ((u32*)Y)[(size_t)row * 64 + lane] = w;
                } else {
                    Y[(size_t)row * 64 + lane] = f2bf(acc0[rr]);
                }
            }
        }
    }
}

// ---------------- coef1: paired h1 -> asrc1/adst1 [N][4] --------------------------------
__global__ void k_coef1(const u32* __restrict__ hp, const float* __restrict__ consts,
                        float* __restrict__ asrc, float* __restrict__ adst, int n) {
    int i = blockIdx.x * 256 + threadIdx.x;
    if (i >= n * 2) return;
    int node = i >> 1, g = i & 1;
    const u32* w = hp + (size_t)node * 64 + g * 32;
    const float* asA = consts + 8 + g * 32;
    const float* adA = consts + 136 + g * 32;
    const float* asB = consts + 8 + (g + 2) * 32;
    const float* adB = consts + 136 + (g + 2) * 32;
    float sA1 = 0.f, sA2 = 0.f, sB1 = 0.f, sB2 = 0.f;
    #pragma unroll
    for (int c = 0; c < 32; c += 4) {
        uint4 q = *(const uint4*)&w[c];
        float l0 = bl(q.x), h0 = bh(q.x), l1 = bl(q.y), h1 = bh(q.y);
        float l2 = bl(q.z), h2 = bh(q.z), l3 = bl(q.w), h3 = bh(q.w);
        sA1 += l0 * asA[c] + l1 * asA[c + 1] + l2 * asA[c + 2] + l3 * asA[c + 3];
        sA2 += l0 * adA[c] + l1 * adA[c + 1] + l2 * adA[c + 2] + l3 * adA[c + 3];
        sB1 += h0 * asB[c] + h1 * asB[c + 1] + h2 * asB[c + 2] + h3 * asB[c + 3];
        sB2 += h0 * adB[c] + h1 * adB[c + 1] + h2 * adB[c + 2] + h3 * adB[c + 3];
    }
    asrc[node * 4 + g] = sA1;     adst[node * 4 + g] = sA2;
    asrc[node * 4 + g + 2] = sB1; adst[node * 4 + g + 2] = sB2;
}

// ---------------- coef2: natural h2 -> asrc2/adst2 [N] ----------------------------------
__global__ void k_coef2(const u32* __restrict__ hp, const float* __restrict__ consts,
                        float* __restrict__ asrc, float* __restrict__ adst, int n) {
    int i = blockIdx.x * 256 + threadIdx.x;
    if (i >= n) return;
    const u32* w = hp + (size_t)i * 32;
    const float* as_ = consts + 264;
    const float* ad_ = consts + 328;
    float s1 = 0.f, s2 = 0.f;
    #pragma unroll
    for (int c = 0; c < 32; c += 4) {
        uint4 q = *(const uint4*)&w[c];
        float l0 = bl(q.x), h0 = bh(q.x), l1 = bl(q.y), h1 = bh(q.y);
        float l2 = bl(q.z), h2 = bh(q.z), l3 = bl(q.w), h3 = bh(q.w);
        s1 += l0 * as_[2*c] + h0 * as_[2*c+1] + l1 * as_[2*c+2] + h1 * as_[2*c+3]
            + l2 * as_[2*c+4] + h2 * as_[2*c+5] + l3 * as_[2*c+6] + h3 * as_[2*c+7];
        s2 += l0 * ad_[2*c] + h0 * ad_[2*c+1] + l1 * ad_[2*c+2] + h1 * ad_[2*c+3]
            + l2 * ad_[2*c+4] + h2 * ad_[2*c+5] + l3 * ad_[2*c+6] + h3 * ad_[2*c+7];
    }
    asrc[i] = s1; adst[i] = s2;
}

// ---------------- CSR build -------------------------------------------------------------
__global__ __launch_bounds__(256) void k_bhist(const int* __restrict__ dst,
                                               int* __restrict__ cnt, int* __restrict__ bcnt,
                                               int E, int n, int B) {
    __shared__ int lh[MAXB];
    for (int i = threadIdx.x; i < B; i += 256) lh[i] = 0;
    __syncthreads();
    int stride = gridDim.x * 256;
    for (int e = blockIdx.x * 256 + threadIdx.x; e < E; e += stride) {
        int d = clampi(dst[e], 0, n - 1);
        atomicAdd(&cnt[d], 1);
        atomicAdd(&lh[d >> 8], 1);
    }
    __syncthreads();
    for (int i = threadIdx.x; i < B; i += 256)
        if (lh[i]) atomicAdd(&bcnt[i], lh[i]);
}
__global__ void k_scan1(const int* __restrict__ cnt, int* __restrict__ part,
                        int* __restrict__ bsum, int n) {
    __shared__ int buf[256];
    int i = blockIdx.x * 256 + threadIdx.x;
    int v = (i < n) ? cnt[i] : 0;
    buf[threadIdx.x] = v;
    __syncthreads();
    for (int off = 1; off < 256; off <<= 1) {
        int t = (threadIdx.x >= off) ? buf[threadIdx.x - off] : 0;
        __syncthreads();
        buf[threadIdx.x] += t;
        __syncthreads();
    }
    if (i < n) part[i] = buf[threadIdx.x];
    if (threadIdx.x == 255) bsum[blockIdx.x] = buf[255];
}
__global__ void k_scan2(int* __restrict__ bsum, int nb) {
    __shared__ int buf[256];
    int t = threadIdx.x;
    int v = (t < nb) ? bsum[t] : 0;
    buf[t] = v;
    __syncthreads();
    for (int off = 1; off < 256; off <<= 1) {
        int tt = (t >= off) ? buf[t - off] : 0;
        __syncthreads();
        buf[t] += tt;
        __syncthreads();
    }
    if (t < nb) bsum[t] = buf[t] - v;   // exclusive
}
__global__ void k_scan3(int* __restrict__ roff, const int* __restrict__ bsum,
                        int* __restrict__ rpos, int n) {
    int i = blockIdx.x * 256 + threadIdx.x;
    if (i > n) return;
    int v;
    if (i == 0) { v = 0; roff[0] = 0; }
    else { v = roff[i] + bsum[(i - 1) >> 8]; roff[i] = v; }
    if (i < n) rpos[i] = v;
}
__global__ void k_bscan(const int* __restrict__ bcnt, int* __restrict__ bbase,
                        int* __restrict__ bfront, int B) {
    if (threadIdx.x == 0) {
        int acc = 0;
        for (int i = 0; i < B; i++) { bbase[i] = acc; bfront[i] = acc; acc += bcnt[i]; }
        bbase[B] = acc;
    }
}
// binA: tile-ranked bucket scatter -> staged int4 {src, dst, ea_bits, 0}
__global__ __launch_bounds__(256) void k_binA(
    const int* __restrict__ dst, const int* __restrict__ src, const void* eattr,
    const int* __restrict__ flag, int* __restrict__ bfront, int4* __restrict__ staged,
    int E, int n, int B) {
    __shared__ int lhist[MAXB];
    __shared__ int lbase[MAXB];
    int f = *flag;
    constexpr int T = 2048;
    for (int tile = blockIdx.x; (long long)tile * T < E; tile += gridDim.x) {
        int base = tile * T;
        for (int i = threadIdx.x; i < B; i += 256) lhist[i] = 0;
        __syncthreads();
        int sj0, sj1, sj2, sj3, sj4, sj5, sj6, sj7;
        int dj0, dj1, dj2, dj3, dj4, dj5, dj6, dj7;
        int rj0, rj1, rj2, rj3, rj4, rj5, rj6, rj7;
        int ej0, ej1, ej2, ej3, ej4, ej5, ej6, ej7;
        #define BINA_LOAD(J, SJ, DJ, RJ, EJ)                                   \
        {                                                                      \
            int idx = base + (J) * 256 + threadIdx.x;                          \
            bool v = idx < E;                                                  \
            int d = v ? clampi(dst[idx], 0, n - 1) : 0;                        \
            SJ = v ? clampi(src[idx], 0, n - 1) : 0;                           \
            EJ = v ? __float_as_int(load1(eattr, idx, f)) : 0;                 \
            DJ = d;                                                            \
            RJ = v ? atomicAdd(&lhist[d >> 8], 1) : -1;                        \
        }
        BINA_LOAD(0, sj0, dj0, rj0, ej0)
        BINA_LOAD(1, sj1, dj1, rj1, ej1)
        BINA_LOAD(2, sj2, dj2, rj2, ej2)
        BINA_LOAD(3, sj3, dj3, rj3, ej3)
        BINA_LOAD(4, sj4, dj4, rj4, ej4)
        BINA_LOAD(5, sj5, dj5, rj5, ej5)
        BINA_LOAD(6, sj6, dj6, rj6, ej6)
        BINA_LOAD(7, sj7, dj7, rj7, ej7)
        #undef BINA_LOAD
        __syncthreads();
        for (int i = threadIdx.x; i < B; i += 256) {
            int c = lhist[i];
            lbase[i] = c ? atomicAdd(&bfront[i], c) : 0;
        }
        __syncthreads();
        #define BINA_STORE(SJ, DJ, RJ, EJ)                                     \
        if (RJ >= 0) {                                                         \
            long long q = (long long)lbase[DJ >> 8] + RJ;                      \
            if (q >= 0 && q < E) {                                             \
                int4 v; v.x = SJ; v.y = DJ; v.z = EJ; v.w = 0;                 \
                staged[q] = v;                                                 \
            }                                                                  \
        }
        BINA_STORE(sj0, dj0, rj0, ej0)
        BINA_STORE(sj1, dj1, rj1, ej1)
        BINA_STORE(sj2, dj2, rj2, ej2)
        BINA_STORE(sj3, dj3, rj3, ej3)
        BINA_STORE(sj4, dj4, rj4, ej4)
        BINA_STORE(sj5, dj5, rj5, ej5)
        BINA_STORE(sj6, dj6, rj6, ej6)
        BINA_STORE(sj7, dj7, rj7, ej7)
        #undef BINA_STORE
        __syncthreads();
    }
}
// binB: one workgroup per bucket; writes confined to the bucket's edata window
__global__ __launch_bounds__(256) void k_binB(
    const int4* __restrict__ staged, const int* __restrict__ bbase,
    const int* __restrict__ roff, int2* __restrict__ edata, int N, int E, int B) {
    __shared__ int lpos[256];
    int k = blockIdx.x;
    int dlo = k << 8;
    int t = threadIdx.x;
    int dn = dlo + t;
    lpos[t] = (dn < N) ? roff[dn] : 0;
    __syncthreads();
    int lo = clampi(bbase[k], 0, E);
    int hi = clampi(bbase[k + 1], lo, E);
    for (int i = lo + t; i < hi; i += 256) {
        int4 v = staged[i];
        int p = atomicAdd(&lpos[v.y & 255], 1);
        if (p >= 0 && p < E) edata[p] = make_int2(v.x, v.z);
    }
}
// fallback single-pass scatter
__global__ void k_scatter(const int* __restrict__ dst, const int* __restrict__ src,
                          const void* eattr, const int* __restrict__ flag,
                          int* __restrict__ rpos, int2* __restrict__ edata, int E, int n) {
    int f = *flag;
    int e = blockIdx.x * 256 + threadIdx.x;
    if (e < E) {
        int d = clampi(dst[e], 0, n - 1);
        int s = clampi(src[e], 0, n - 1);
        float ea = load1(eattr, e, f);
        int p = atomicAdd(&rpos[d], 1);
        if (p >= 0 && p < E) {
            int2 v; v.x = s; v.y = __float_as_int(ea);
            edata[p] = v;
        }
    }
}

// ---------------- gat1, CACHED: fused fast path, no-max softmax, LDS weights, 4x MLP ----
__global__ __launch_bounds__(256) void k_gat1c(
    const u32* __restrict__ hp, const float* __restrict__ asrc, const float* __restrict__ adst,
    const int2* __restrict__ edata, const int* __restrict__ roff,
    const int* __restrict__ flag, const float* __restrict__ consts, const void* bias,
    float* __restrict__ al, u32* __restrict__ out, int n, int E) {
    __shared__ float4 wls[4][64];
    int f = *flag;
    int gtid = blockIdx.x * 256 + threadIdx.x;
    int wv = gtid >> 6, lane = gtid & 63;
    int wid = (threadIdx.x >> 6);
    int nw = (gridDim.x * 256) >> 6;
    const float c0 = consts[0], c1 = consts[1], c2 = consts[2], c3 = consts[3];
    const int hsel = lane >> 5;
    const float biasA = load1(bias, lane, f);
    const float biasB = load1(bias, 64 + lane, f);

    for (int d = wv; d < n; d += nw) {
        int s0 = clampi(roff[d], 0, E);
        int s1 = clampi(roff[d + 1], s0, E);
        int deg = s1 - s0;
        float4 adv = *(const float4*)&adst[d * 4];
        float accA = 0.f, accB = 0.f;

        if (deg <= 64) {
            bool v = lane < deg;
            int s = 0;
            float e0 = 0.f, e1 = 0.f, e2 = 0.f, e3 = 0.f;
            if (v) {
                int2 ed = edata[s0 + lane];
                s = ed.x;
                float ea = __int_as_float(ed.y);
                float4 av = *(const float4*)&asrc[(size_t)s * 4];
                e0 = cexpf(lrelu(av.x + adv.x + ea * c0));
                e1 = cexpf(lrelu(av.y + adv.y + ea * c1));
                e2 = cexpf(lrelu(av.z + adv.z + ea * c2));
                e3 = cexpf(lrelu(av.w + adv.w + ea * c3));
            }
            float d0 = e0, d1 = e1, d2 = e2, d3 = e3;
            #pragma unroll
            for (int off = 32; off > 0; off >>= 1) {
                d0 += __shfl_xor(d0, off); d1 += __shfl_xor(d1, off);
                d2 += __shfl_xor(d2, off); d3 += __shfl_xor(d3, off);
            }
            float i0 = 1.f / (d0 + 1e-16f), i1 = 1.f / (d1 + 1e-16f);
            float i2 = 1.f / (d2 + 1e-16f), i3 = 1.f / (d3 + 1e-16f);
            if (v) wls[wid][lane] = make_float4(e0 * i0, e1 * i1, e2 * i2, e3 * i3);

            int j = 0;
            for (; j + 4 <= deg; j += 4) {
                int sa = __shfl(s, j), sb = __shfl(s, j + 1);
                int sc_ = __shfl(s, j + 2), sd = __shfl(s, j + 3);
                u32 ha = hp[(size_t)sa * 64 + lane];
                u32 hb = hp[(size_t)sb * 64 + lane];
                u32 hc = hp[(size_t)sc_ * 64 + lane];
                u32 hd = hp[(size_t)sd * 64 + lane];
                float4 wa = wls[wid][j], wb = wls[wid][j + 1];
                float4 wc = wls[wid][j + 2], wd = wls[wid][j + 3];
                accA += (hsel ? wa.y : wa.x) * bl(ha); accB += (hsel ? wa.w : wa.z) * bh(ha);
                accA += (hsel ? wb.y : wb.x) * bl(hb); accB += (hsel ? wb.w : wb.z) * bh(hb);
                accA += (hsel ? wc.y : wc.x) * bl(hc); accB += (hsel ? wc.w : wc.z) * bh(hc);
                accA += (hsel ? wd.y : wd.x) * bl(hd); accB += (hsel ? wd.w : wd.z) * bh(hd);
            }
            for (; j < deg; j++) {
                int sj = __shfl(s, j);
                u32 hw = hp[(size_t)sj * 64 + lane];
                float4 w = wls[wid][j];
                accA += (hsel ? w.y : w.x) * bl(hw);
                accB += (hsel ? w.w : w.z) * bh(hw);
            }
        } else {
            // general path (rare): 2 passes (exp+sum, then weighted gather)
            float d0 = 0.f, d1 = 0.f, d2 = 0.f, d3 = 0.f;
            for (int idx = s0 + lane; idx < s1; idx += 64) {
                int2 ed = edata[idx];
                int s = ed.x;
                float ea = __int_as_float(ed.y);
                float4 av = *(const float4*)&asrc[(size_t)s * 4];
                float e0 = cexpf(lrelu(av.x + adv.x + ea * c0));
                float e1 = cexpf(lrelu(av.y + adv.y + ea * c1));
                float e2 = cexpf(lrelu(av.z + adv.z + ea * c2));
                float e3 = cexpf(lrelu(av.w + adv.w + ea * c3));
                *(float4*)&al[(size_t)idx * 4] = make_float4(e0, e1, e2, e3);
                d0 += e0; d1 += e1; d2 += e2; d3 += e3;
            }
            #pragma unroll
            for (int off = 32; off > 0; off >>= 1) {
                d0 += __shfl_xor(d0, off); d1 += __shfl_xor(d1, off);
                d2 += __shfl_xor(d2, off); d3 += __shfl_xor(d3, off);
            }
            float i0 = 1.f / (d0 + 1e-16f), i1 = 1.f / (d1 + 1e-16f);
            float i2 = 1.f / (d2 + 1e-16f), i3 = 1.f / (d3 + 1e-16f);
            float iA = hsel ? i1 : i0, iB = hsel ? i3 : i2;
            for (int idx = s0; idx < s1; idx++) {
                int s = edata[idx].x;
                float4 ex = *(const float4*)&al[(size_t)idx * 4];
                float wA = (hsel ? ex.y : ex.x) * iA;
                float wB = (hsel ? ex.w : ex.z) * iB;
                u32 hw = hp[(size_t)s * 64 + lane];
                accA += wA * bl(hw);
                accB += wB * bh(hw);
            }
        }
        float rA = fmaxf(accA + biasA, 0.f);   // fused ReLU
        float rB = fmaxf(accB + biasB, 0.f);
        out[(size_t)d * 64 + lane] = (u32)f2bf(rA) | ((u32)f2bf(rB) << 16);
    }
}

// ---------------- gat2, CACHED: fused fast path, no-max softmax -------------------------
__global__ __launch_bounds__(256) void k_gat2c(
    const u16* __restrict__ h, const float* __restrict__ asrc, const float* __restrict__ adst,
    const int2* __restrict__ edata, const int* __restrict__ roff,
    const int* __restrict__ flag, const float* __restrict__ consts, const void* bias,
    float* __restrict__ al, u16* __restrict__ out, int n, int E) {
    __shared__ float wls[4][64];
    int f = *flag;
    int gtid = blockIdx.x * 256 + threadIdx.x;
    int wv = gtid >> 6, lane = gtid & 63;
    int wid = (threadIdx.x >> 6);
    int nw = (gridDim.x * 256) >> 6;
    const float C = consts[4];
    const float biasL = load1(bias, lane, f);

    for (int d = wv; d < n; d += nw) {
        int s0 = clampi(roff[d], 0, E);
        int s1 = clampi(roff[d + 1], s0, E);
        int deg = s1 - s0;
        float ad = adst[d];
        float acc = 0.f;

        if (deg <= 64) {
            bool v = lane < deg;
            int s = 0;
            float e = 0.f;
            if (v) {
                int2 ed = edata[s0 + lane];
                s = ed.x;
                e = cexpf(lrelu(asrc[s] + ad + __int_as_float(ed.y) * C));
            }
            float den = e;
            #pragma unroll
            for (int off = 32; off > 0; off >>= 1) den += __shfl_xor(den, off);
            float inv = 1.f / (den + 1e-16f);
            if (v) wls[wid][lane] = e * inv;

            int j = 0;
            for (; j + 4 <= deg; j += 4) {
                int sa = __shfl(s, j), sb = __shfl(s, j + 1);
                int sc_ = __shfl(s, j + 2), sd = __shfl(s, j + 3);
                float ha = bf2f(h[(size_t)sa * 64 + lane]);
                float hb = bf2f(h[(size_t)sb * 64 + lane]);
                float hc = bf2f(h[(size_t)sc_ * 64 + lane]);
                float hd = bf2f(h[(size_t)sd * 64 + lane]);
                acc += wls[wid][j] * ha + wls[wid][j + 1] * hb
                     + wls[wid][j + 2] * hc + wls[wid][j + 3] * hd;
            }
            for (; j < deg; j++) {
                int sj = __shfl(s, j);
                acc += wls[wid][j] * bf2f(h[(size_t)sj * 64 + lane]);
            }
        } else {
            float den = 0.f;
            for (int idx = s0 + lane; idx < s1; idx += 64) {
                int2 ed = edata[idx];
                float e = cexpf(lrelu(asrc[ed.x] + ad + __int_as_float(ed.y) * C));
                al[idx] = e;
                den += e;
            }
            #pragma unroll
            for (int off = 32; off > 0; off >>= 1) den += __shfl_xor(den, off);
            float inv = 1.f / (den + 1e-16f);
            for (int idx = s0; idx < s1; idx++) {
                int s = edata[idx].x;
                acc += al[idx] * inv * bf2f(h[(size_t)s * 64 + lane]);
            }
        }
        out[(size_t)d * 64 + lane] = f2bf(acc + biasL);
    }
}

// ---------------- gat1/gat2 FALLBACK (recompute, no al cache) ---------------------------
__global__ __launch_bounds__(256) void k_gat1f(
    const u32* __restrict__ hp, const float* __restrict__ asrc, const float* __restrict__ adst,
    const int2* __restrict__ edata, const int* __restrict__ roff,
    const int* __restrict__ flag, const float* __restrict__ consts, const void* bias,
    u32* __restrict__ out, int n, int E) {
    int f = *flag;
    int gtid = blockIdx.x * 256 + threadIdx.x;
    int wv = gtid >> 6, lane = gtid & 63;
    int nw = (gridDim.x * 256) >> 6;
    const float c0 = consts[0], c1 = consts[1], c2 = consts[2], c3 = consts[3];
    const int hsel = lane >> 5;
    const float biasA = load1(bias, lane, f);
    const float biasB = load1(bias, 64 + lane, f);

    for (int d = wv; d < n; d += nw) {
        int s0 = clampi(roff[d], 0, E);
        int s1 = clampi(roff[d + 1], s0, E);
        float4 adv = *(const float4*)&adst[d * 4];
        float d0 = 0.f, d1 = 0.f, d2 = 0.f, d3 = 0.f;
        for (int idx = s0 + lane; idx < s1; idx += 64) {
            int2 ed = edata[idx];
            float ea = __int_as_float(ed.y);
            float4 av = *(const float4*)&asrc[(size_t)ed.x * 4];
            d0 += cexpf(lrelu(av.x + adv.x + ea * c0));
            d1 += cexpf(lrelu(av.y + adv.y + ea * c1));
            d2 += cexpf(lrelu(av.z + adv.z + ea * c2));
            d3 += cexpf(lrelu(av.w + adv.w + ea * c3));
        }
        #pragma unroll
        for (int off = 32; off > 0; off >>= 1) {
            d0 += __shfl_xor(d0, off); d1 += __shfl_xor(d1, off);
            d2 += __shfl_xor(d2, off); d3 += __shfl_xor(d3, off);
        }
        float i0 = 1.f / (d0 + 1e-16f), i1 = 1.f / (d1 + 1e-16f);
        float i2 = 1.f / (d2 + 1e-16f), i3 = 1.f / (d3 + 1e-16f);
        float iA = hsel ? i1 : i0, iB = hsel ? i3 : i2;
        float cA = hsel ? c1 : c0, cB = hsel ? c3 : c2;
        float aA = hsel ? adv.y : adv.x, aB = hsel ? adv.w : adv.z;

        float accA = 0.f, accB = 0.f;
        for (int idx = s0; idx < s1; idx++) {
            int2 ed = edata[idx];
            float ea = __int_as_float(ed.y);
            float4 av = *(const float4*)&asrc[(size_t)ed.x * 4];
            float wA = cexpf(lrelu((hsel ? av.y : av.x) + aA + ea * cA)) * iA;
            float wB = cexpf(lrelu((hsel ? av.w : av.z) + aB + ea * cB)) * iB;
            u32 hw = hp[(size_t)ed.x * 64 + lane];
            accA += wA * bl(hw);
            accB += wB * bh(hw);
        }
        float rA = fmaxf(accA + biasA, 0.f);
        float rB = fmaxf(accB + biasB, 0.f);
        out[(size_t)d * 64 + lane] = (u32)f2bf(rA) | ((u32)f2bf(rB) << 16);
    }
}

__global__ __launch_bounds__(256) void k_gat2f(
    const u16* __restrict__ h, const float* __restrict__ asrc, const float* __restrict__ adst,
    const int2* __restrict__ edata, const int* __restrict__ roff,
    const int* __restrict__ flag, const float* __restrict__ consts, const void* bias,
    u16* __restrict__ out, int n, int E) {
    int f = *flag;
    int gtid = blockIdx.x * 256 + threadIdx.x;
    int wv = gtid >> 6, lane = gtid & 63;
    int nw = (gridDim.x * 256) >> 6;
    const float C = consts[4];
    const float biasL = load1(bias, lane, f);

    for (int d = wv; d < n; d += nw) {
        int s0 = clampi(roff[d], 0, E);
        int s1 = clampi(roff[d + 1], s0, E);
        float ad = adst[d];
        float den = 0.f;
        for (int idx = s0 + lane; idx < s1; idx += 64) {
            int2 ed = edata[idx];
            den += cexpf(lrelu(asrc[ed.x] + ad + __int_as_float(ed.y) * C));
        }
        #pragma unroll
        for (int off = 32; off > 0; off >>= 1) den += __shfl_xor(den, off);
        float inv = 1.f / (den + 1e-16f);

        float acc = 0.f;
        for (int idx = s0; idx < s1; idx++) {
            int2 ed = edata[idx];
            float w = cexpf(lrelu(asrc[ed.x] + ad + __int_as_float(ed.y) * C)) * inv;
            acc += w * bf2f(h[(size_t)ed.x * 64 + lane]);
        }
        out[(size_t)d * 64 + lane] = f2bf(acc + biasL);
    }
}

// ---------------- pooling ---------------------------------------------------------------
__global__ void k_pool(const u16* __restrict__ agg2, const int* __restrict__ batch,
                       float* __restrict__ pool, float* __restrict__ cnt, int n, int G) {
    int t = blockIdx.x * 256 + threadIdx.x;
    int nb8 = (n + 7) / 8;
    if (t >= nb8 * 64) return;
    int base = (t >> 6) * 8;
    int c = t & 63;
    int end = min(base + 8, n);
    float acc = 0.f, cacc = 0.f;
    int curg = clampi(batch[base], 0, G - 1);
    for (int j = base; j < end; j++) {
        int g = clampi(batch[j], 0, G - 1);
        if (g != curg) {
            atomicAdd(&pool[curg * 64 + c], acc);
            if (c == 0) atomicAdd(&cnt[curg], cacc);
            acc = 0.f; cacc = 0.f; curg = g;
        }
        acc += bf2f(agg2[(size_t)j * 64 + c]);
        cacc += 1.f;
    }
    atomicAdd(&pool[curg * 64 + c], acc);
    if (c == 0) atomicAdd(&cnt[curg], cacc);
}

__global__ void k_head(const float* __restrict__ pool, const float* __restrict__ cnt,
                       const void* Wp, const void* bp, const int* __restrict__ flag,
                       void* out, int G) {
    int f = *flag;
    int g = threadIdx.x;
    if (g >= G) return;
    float s = 0.f;
    for (int c = 0; c < 64; c++) s += pool[g * 64 + c] * load1(Wp, c, f);
    float cv = cnt[g];
    if (!(cv > 0.f)) cv = 1.f;
    float r = s / cv + load1(bp, 0, f);
    if (f) ((float*)out)[g] = r;
    else   ((u16*)out)[g] = f2bf(r);
}

// ---------------- launch ----------------------------------------------------------------
extern "C" void kernel_launch(void* const* d_in, const int* in_sizes, int n_in,
                              void* d_out, int out_size, void* d_ws, size_t ws_size,
                              hipStream_t stream) {
    const void* x    = d_in[0];
    const int* ei    = (const int*)d_in[1];
    const void* eattr = d_in[2];
    const int* batch = (const int*)d_in[3];
    const void* W1   = d_in[4];
    const void* as1  = d_in[5];
    const void* ad1  = d_in[6];
    const void* We1  = d_in[7];
    const void* ae1  = d_in[8];
    const void* b1   = d_in[9];
    const void* W2   = d_in[10];
    const void* as2  = d_in[11];
    const void* ad2  = d_in[12];
    const void* We2  = d_in[13];
    const void* ae2  = d_in[14];
    const void* b2   = d_in[15];
    const void* Wp   = d_in[16];
    const void* bp   = d_in[17];

    const int N = in_sizes[3];
    const int E = in_sizes[2];
    const int G = out_size;
    const int* src = ei;
    const int* dst = ei + E;
    const int B = (N + 255) >> 8;

    char* p = (char*)d_ws;
    auto alloc = [&](size_t bytes) -> char* {
        char* r = p;
        p += (bytes + 255) & ~(size_t)255;
        return r;
    };
    int* flag    = (int*)alloc(32);
    float* consts = (float*)alloc(2048);
    int* roff    = (int*)alloc((size_t)(N + 1) * 4);
    int* rpos    = (int*)alloc((size_t)N * 4);
    int* bsum    = (int*)alloc(256 * 4);
    int* bcnt    = (int*)alloc((size_t)(MAXB * 3 + 1) * 4);
    int* bbase   = bcnt + MAXB;          // B+1 entries
    int* bfront  = bbase + MAXB + 1;     // B entries
    int2* edata  = (int2*)alloc((size_t)E * 8);
    float* pool  = (float*)alloc((size_t)(G * 64 + G) * 4);
    float* cnt   = pool + (size_t)G * 64;
    float* asrc1 = (float*)alloc((size_t)N * 4 * 4);
    float* adst1 = (float*)alloc((size_t)N * 4 * 4);
    float* asrc2 = asrc1;             // alias: dead after gat1
    float* adst2 = adst1;
    u16* agg1    = (u16*)alloc((size_t)N * 128 * 2);
    u16* h1      = (u16*)alloc((size_t)N * 128 * 2);
    u16* h2      = h1;                // alias: h1 dead after gat1
    u16* agg2    = h1 + (size_t)N * 64;
    // al: gat spill buffer (deg>64 only). staged aliases al (temporally disjoint).
    float* al    = (float*)alloc((size_t)E * 16);
    int4* staged = (int4*)al;
    size_t full_need = (size_t)(p - (char*)d_ws);
    const bool cached = (ws_size >= full_need);
    const bool binned = cached && (B <= MAXB);

    hipMemsetAsync(rpos, 0, (size_t)N * 4, stream);
    hipMemsetAsync(bcnt, 0, (size_t)B * 4, stream);
    hipMemsetAsync(pool, 0, (size_t)(G * 64 + G) * 4, stream);

    k_detect<<<1, 64, 0, stream>>>((const u32*)x, flag);
    k_consts<<<1, 256, 0, stream>>>(We1, ae1, We2, ae2, as1, ad1, as2, ad2, flag, consts);
    k_gemm5<128><<<512, 256, 0, stream>>>(x, W1, flag, -1, h1, N);
    k_coef1<<<(N * 2 + 255) / 256, 256, 0, stream>>>((const u32*)h1, consts, asrc1, adst1, N);

    int NB = (N + 255) / 256;
    k_bhist<<<512, 256, 0, stream>>>(dst, rpos, bcnt, E, N, B);
    k_scan1<<<NB, 256, 0, stream>>>(rpos, roff + 1, bsum, N);
    k_scan2<<<1, 256, 0, stream>>>(bsum, NB);
    k_scan3<<<(N + 256) / 256, 256, 0, stream>>>(roff, bsum, rpos, N);
    if (binned) {
        k_bscan<<<1, 64, 0, stream>>>(bcnt, bbase, bfront, B);
        k_binA<<<(E + 2047) / 2048, 256, 0, stream>>>(dst, src, eattr, flag, bfront,
                                                      staged, E, N, B);
        k_binB<<<B, 256, 0, stream>>>(staged, bbase, roff, edata, N, E, B);
    } else {
        k_scatter<<<(E + 255) / 256, 256, 0, stream>>>(dst, src, eattr, flag, rpos,
                                                       edata, E, N);
    }

    int gatBlocks = (N * 64 + 255) / 256;
    if (cached) {
        k_gat1c<<<gatBlocks, 256, 0, stream>>>((const u32*)h1, asrc1, adst1, edata, roff,
                                               flag, consts, b1, al, (u32*)agg1, N, E);
    } else {
        k_gat1f<<<gatBlocks, 256, 0, stream>>>((const u32*)h1, asrc1, adst1, edata, roff,
                                               flag, consts, b1, (u32*)agg1, N, E);
    }
    k_gemm5<64><<<512, 256, 0, stream>>>(agg1, W2, flag, 0, h2, N);
    k_coef2<<<(N + 255) / 256, 256, 0, stream>>>((const u32*)h2, consts, asrc2, adst2, N);
    if (cached) {
        k_gat2c<<<gatBlocks, 256, 0, stream>>>(h2, asrc2, adst2, edata, roff, flag,
                                               consts, b2, al, agg2, N, E);
    } else {
        k_gat2f<<<gatBlocks, 256, 0, stream>>>(h2, asrc2, adst2, edata, roff, flag,
                                               consts, b2, agg2, N, E);
    }
    k_pool<<<(((N + 7) / 8) * 64 + 255) / 256, 256, 0, stream>>>(agg2, batch, pool, cnt, N, G);
    k_head<<<1, 64, 0, stream>>>(pool, cnt, Wp, bp, flag, d_out, G);
}